// Round 1
// baseline (16726.045 us; speedup 1.0000x reference)
//
#include <hip/hip_runtime.h>
#include <cstdint>
#include <cstddef>

#define N_NODES 32768
#define N_EDGES 131072
#define ET_EDGES (N_EDGES + N_NODES)
#define N_ROOTS 1024
#define EMB_D 256
#define FEAT 128
#define SEQ 16
#define OUT_CH 125

static inline int cdiv(long long a, long long b) { return (int)((a + b - 1) / b); }

// ---------- small utils ----------
__device__ __forceinline__ float warpReduceSum(float v) {
#pragma unroll
    for (int m = 32; m; m >>= 1) v += __shfl_xor(v, m, 64);
    return v;
}
// order-preserving float<->int encoding for atomicMax on signed int
__device__ __forceinline__ int encf(float f) {
    int i = __float_as_int(f);
    return i >= 0 ? i : (i ^ 0x7fffffff);
}
__device__ __forceinline__ float decf(int i) {
    return __int_as_float(i >= 0 ? i : (i ^ 0x7fffffff));
}

__global__ void fill_i32(int* p, int v, int n) {
    int i = blockIdx.x * 256 + threadIdx.x;
    if (i < n) p[i] = v;
}

// repack conv weights [oc][ic][kk] -> [oc][kk][ic]
__global__ void repack_conv(const float* __restrict__ in, float* __restrict__ out, int K, int total) {
    int i = blockIdx.x * 256 + threadIdx.x;
    if (i >= total) return;
    int kk = i % K;
    int t = i / K;
    int ic = t & 255;
    int oc = t >> 8;
    out[((size_t)(oc * K + kk)) * EMB_D + ic] = in[i];
}

// ---------- generic fp32 GEMM: C[M,N] = A[M,K] @ B[K,N] (+bias, +relu) ----------
__global__ __launch_bounds__(256) void gemm64(const float* __restrict__ A, const float* __restrict__ B,
                                              const float* __restrict__ bias, float* __restrict__ C,
                                              int M, int N, int K, int lda, int ldc, int doRelu) {
    __shared__ float As[16][65];
    __shared__ float Bs[16][65];
    const int bm = blockIdx.y * 64, bn = blockIdx.x * 64;
    const int tid = threadIdx.x;
    const int tx = tid & 15, ty = tid >> 4;
    float acc[4][4] = {};
    for (int k0 = 0; k0 < K; k0 += 16) {
#pragma unroll
        for (int j = 0; j < 4; j++) {
            int i = tid + j * 256;
            int kk = i & 15, m = i >> 4;
            int gr = bm + m, gc = k0 + kk;
            As[kk][m] = (gr < M && gc < K) ? A[(size_t)gr * lda + gc] : 0.f;
        }
#pragma unroll
        for (int j = 0; j < 4; j++) {
            int i = tid + j * 256;
            int n = i & 63, kk = i >> 6;
            int gr = k0 + kk, gc = bn + n;
            Bs[kk][n] = (gr < K && gc < N) ? B[(size_t)gr * N + gc] : 0.f;
        }
        __syncthreads();
#pragma unroll
        for (int kk = 0; kk < 16; kk++) {
            float a[4], b[4];
#pragma unroll
            for (int i2 = 0; i2 < 4; i2++) a[i2] = As[kk][ty * 4 + i2];
#pragma unroll
            for (int j2 = 0; j2 < 4; j2++) b[j2] = Bs[kk][tx * 4 + j2];
#pragma unroll
            for (int i2 = 0; i2 < 4; i2++)
#pragma unroll
                for (int j2 = 0; j2 < 4; j2++) acc[i2][j2] = fmaf(a[i2], b[j2], acc[i2][j2]);
        }
        __syncthreads();
    }
#pragma unroll
    for (int i2 = 0; i2 < 4; i2++) {
        int r = bm + ty * 4 + i2;
        if (r >= M) continue;
#pragma unroll
        for (int j2 = 0; j2 < 4; j2++) {
            int c = bn + tx * 4 + j2;
            if (c >= N) continue;
            float v = acc[i2][j2];
            if (bias) v += bias[c];
            if (doRelu) v = fmaxf(v, 0.f);
            C[(size_t)r * ldc + c] = v;
        }
    }
}

// ---------- node alpha: al_s = h @ a_src, al_d = h @ a_dst (one wave per node) ----------
__global__ __launch_bounds__(256) void alpha_kernel(const float* __restrict__ h, const float* __restrict__ asrc,
                                                    const float* __restrict__ adst, float* __restrict__ als,
                                                    float* __restrict__ ald) {
    int gw = (blockIdx.x * 256 + threadIdx.x) >> 6;
    int lane = threadIdx.x & 63;
    if (gw >= N_NODES) return;
    const float* row = h + (size_t)gw * FEAT;
    float v0 = row[lane], v1 = row[lane + 64];
    float ps = v0 * asrc[lane] + v1 * asrc[lane + 64];
    float pd = v0 * adst[lane] + v1 * adst[lane + 64];
    ps = warpReduceSum(ps);
    pd = warpReduceSum(pd);
    if (lane == 0) {
        als[gw] = ps;
        ald[gw] = pd;
    }
}

// ---------- edge passes (src/dst with implicit self loops appended) ----------
__device__ __forceinline__ void edge_decode(int i, const int* __restrict__ ei, int& s, int& d) {
    if (i < N_EDGES) {
        s = ei[i];
        d = ei[N_EDGES + i];
    } else {
        s = d = i - N_EDGES;
    }
}

__global__ void edge_p1(const int* __restrict__ ei, const float* __restrict__ als, const float* __restrict__ ald,
                        float* __restrict__ elog, int* __restrict__ menc, float* dega) {
    int i = blockIdx.x * 256 + threadIdx.x;
    if (i >= ET_EDGES) return;
    int s, d;
    edge_decode(i, ei, s, d);
    float e = als[s] + ald[d];
    e = (e >= 0.f) ? e : 0.2f * e;  // LeakyReLU(0.2)
    elog[i] = e;
    atomicMax(&menc[d], encf(e));
    if (dega) unsafeAtomicAdd(&dega[d], 1.f);
}

__global__ void edge_p2(const int* __restrict__ ei, float* __restrict__ elog, const int* __restrict__ menc,
                        float* __restrict__ den) {
    int i = blockIdx.x * 256 + threadIdx.x;
    if (i >= ET_EDGES) return;
    int s, d;
    edge_decode(i, ei, s, d);
    float ex = expf(elog[i] - decf(menc[d]));
    elog[i] = ex;
    unsafeAtomicAdd(&den[d], ex);
}

__global__ void edge_p2b(const int* __restrict__ ei, float* __restrict__ elog, const float* __restrict__ den) {
    int i = blockIdx.x * 256 + threadIdx.x;
    if (i >= ET_EDGES) return;
    int s, d;
    edge_decode(i, ei, s, d);
    elog[i] = elog[i] / den[d];
}

__global__ void dinv_kernel(float* deg) {
    int i = blockIdx.x * 256 + threadIdx.x;
    if (i < N_NODES) deg[i] = rsqrtf(fmaxf(deg[i], 1.f));
}

// out[dst] += coef[e] * h[src], 128 feats per edge
__global__ void edge_scatter(const int* __restrict__ ei, const float* __restrict__ coef, const float* __restrict__ h,
                             float* __restrict__ out, int ldo) {
    int i = blockIdx.x * 256 + threadIdx.x;
    if (i >= ET_EDGES * FEAT) return;
    int e = i >> 7, f = i & 127;
    int s, d;
    edge_decode(e, ei, s, d);
    unsafeAtomicAdd(&out[(size_t)d * ldo + f], coef[e] * h[(size_t)s * FEAT + f]);
}

// GCN: out[dst] += dinv[src]*dinv[dst] * h[src]
__global__ void gcn_scatter(const int* __restrict__ ei, const float* __restrict__ dinv, const float* __restrict__ h,
                            float* __restrict__ out, int ldo) {
    int i = blockIdx.x * 256 + threadIdx.x;
    if (i >= ET_EDGES * FEAT) return;
    int e = i >> 7, f = i & 127;
    int s, d;
    edge_decode(e, ei, s, d);
    float coef = dinv[s] * dinv[d];
    unsafeAtomicAdd(&out[(size_t)d * ldo + f], coef * h[(size_t)s * FEAT + f]);
}

__global__ void biasadd_cat(float* __restrict__ cat, const float* __restrict__ b1, const float* __restrict__ b2) {
    int i = blockIdx.x * 256 + threadIdx.x;  // over N*256
    int n = i >> 8, c = i & 255;
    float b = (c < 128) ? b1[c] : b2[c - 128];
    cat[(size_t)n * 512 + c] += b;
}

__global__ void root_gather(const float* __restrict__ g2, const int* __restrict__ rooti, const float* __restrict__ gb,
                            float* __restrict__ fin) {
    int i = blockIdx.x * 256 + threadIdx.x;
    if (i >= N_ROOTS * FEAT) return;
    int r = i >> 7, c = i & 127;
    fin[(size_t)r * 1128 + c] = g2[(size_t)rooti[r] * FEAT + c] + gb[c];
}

__global__ void fc2_kernel(const float* __restrict__ fch, const float* __restrict__ W, const float* __restrict__ b,
                           float* __restrict__ out) {
    int i = blockIdx.x * 256 + threadIdx.x;
    if (i >= N_ROOTS * 3) return;
    int r = i / 3, c = i - r * 3;
    float acc = b[c];
    for (int k = 0; k < 300; k++) acc = fmaf(fch[(size_t)r * 300 + k], W[k * 3 + c], acc);
    out[i] = acc;
}

// ---------- per-node transformer block (256 threads, LDS exactly 64 KB) ----------
struct TSmem {
    float t0[SEQ][EMB_D];  // input t, later: residual+LN output
    float qb[SEQ][EMB_D];  // q; re-used as attention output (per-thread-exclusive region, safe alias)
    float kb[SEQ][EMB_D];
    float vb[SEQ][EMB_D];
};

__device__ __forceinline__ void transformer_node(TSmem& sm, int node, const float* __restrict__ emb,
                                                 const int* __restrict__ text2, const float* __restrict__ Wq,
                                                 const float* __restrict__ Wk, const float* __restrict__ Wv,
                                                 const float* __restrict__ Wo, const float* __restrict__ bq,
                                                 const float* __restrict__ bk, const float* __restrict__ bv,
                                                 const float* __restrict__ bo, const float* __restrict__ lng,
                                                 const float* __restrict__ lnb) {
    const int tid = threadIdx.x;
    // 1) gather embeddings
#pragma unroll
    for (int s = 0; s < SEQ; s++) {
        int tok = text2[node * SEQ + s];
        sm.t0[s][tid] = emb[(size_t)tok * EMB_D + tid];
    }
    __syncthreads();
    // 2) fused q/k/v projection; thread = output column; t reads shared 3-way
    {
        float aq[SEQ], ak[SEQ], av[SEQ];
#pragma unroll
        for (int s = 0; s < SEQ; s++) {
            aq[s] = 0.f;
            ak[s] = 0.f;
            av[s] = 0.f;
        }
        for (int k0 = 0; k0 < EMB_D; k0 += 4) {
            float wq0 = Wq[(k0 + 0) * EMB_D + tid], wq1 = Wq[(k0 + 1) * EMB_D + tid];
            float wq2 = Wq[(k0 + 2) * EMB_D + tid], wq3 = Wq[(k0 + 3) * EMB_D + tid];
            float wk0 = Wk[(k0 + 0) * EMB_D + tid], wk1 = Wk[(k0 + 1) * EMB_D + tid];
            float wk2 = Wk[(k0 + 2) * EMB_D + tid], wk3 = Wk[(k0 + 3) * EMB_D + tid];
            float wv0 = Wv[(k0 + 0) * EMB_D + tid], wv1 = Wv[(k0 + 1) * EMB_D + tid];
            float wv2 = Wv[(k0 + 2) * EMB_D + tid], wv3 = Wv[(k0 + 3) * EMB_D + tid];
#pragma unroll
            for (int s = 0; s < SEQ; s++) {
                const float4 t4 = *(const float4*)&sm.t0[s][k0];
                aq[s] = fmaf(t4.x, wq0, fmaf(t4.y, wq1, fmaf(t4.z, wq2, fmaf(t4.w, wq3, aq[s]))));
                ak[s] = fmaf(t4.x, wk0, fmaf(t4.y, wk1, fmaf(t4.z, wk2, fmaf(t4.w, wk3, ak[s]))));
                av[s] = fmaf(t4.x, wv0, fmaf(t4.y, wv1, fmaf(t4.z, wv2, fmaf(t4.w, wv3, av[s]))));
            }
        }
        float bq_ = bq[tid], bk_ = bk[tid], bv_ = bv[tid];
#pragma unroll
        for (int s = 0; s < SEQ; s++) {
            sm.qb[s][tid] = aq[s] + bq_;
            sm.kb[s][tid] = ak[s] + bk_;
            sm.vb[s][tid] = av[s] + bv_;
        }
    }
    __syncthreads();
    // 3) attention: thread = (head, query-row); q hoisted to regs (kills stride-256 bank conflicts)
    {
        const int h = tid >> 4, qi = tid & 15, base = h * 16;
        float qv[16];
#pragma unroll
        for (int d = 0; d < 16; d += 4) {
            float4 q4 = *(const float4*)&sm.qb[qi][base + d];
            qv[d] = q4.x;
            qv[d + 1] = q4.y;
            qv[d + 2] = q4.z;
            qv[d + 3] = q4.w;
        }
        float sc[SEQ];
#pragma unroll
        for (int kj = 0; kj < SEQ; kj++) {
            float a = 0.f;
#pragma unroll
            for (int d = 0; d < 16; d += 4) {
                float4 k4 = *(const float4*)&sm.kb[kj][base + d];
                a = fmaf(qv[d], k4.x, fmaf(qv[d + 1], k4.y, fmaf(qv[d + 2], k4.z, fmaf(qv[d + 3], k4.w, a))));
            }
            sc[kj] = a * 0.25f;  // 1/sqrt(dh=16)
        }
        float mx = sc[0];
#pragma unroll
        for (int kj = 1; kj < SEQ; kj++) mx = fmaxf(mx, sc[kj]);
        float sum = 0.f;
#pragma unroll
        for (int kj = 0; kj < SEQ; kj++) {
            sc[kj] = expf(sc[kj] - mx);
            sum += sc[kj];
        }
        float inv = 1.f / sum;
        float ov[16];
#pragma unroll
        for (int d = 0; d < 16; d++) ov[d] = 0.f;
#pragma unroll
        for (int kj = 0; kj < SEQ; kj++) {
            float p = sc[kj];
#pragma unroll
            for (int d = 0; d < 16; d += 4) {
                float4 v4 = *(const float4*)&sm.vb[kj][base + d];
                ov[d] = fmaf(p, v4.x, ov[d]);
                ov[d + 1] = fmaf(p, v4.y, ov[d + 1]);
                ov[d + 2] = fmaf(p, v4.z, ov[d + 2]);
                ov[d + 3] = fmaf(p, v4.w, ov[d + 3]);
            }
        }
        // write attention-out into qb (this thread's exclusive region; its q reads are done)
#pragma unroll
        for (int d = 0; d < 16; d += 4) {
            float4 o4 = make_float4(ov[d] * inv, ov[d + 1] * inv, ov[d + 2] * inv, ov[d + 3] * inv);
            *(float4*)&sm.qb[qi][base + d] = o4;
        }
    }
    __syncthreads();
    // 4) output projection + residual (into t0, own column only)
    {
        float ao[SEQ];
#pragma unroll
        for (int s = 0; s < SEQ; s++) ao[s] = 0.f;
        for (int k0 = 0; k0 < EMB_D; k0 += 4) {
            float w0 = Wo[(k0 + 0) * EMB_D + tid], w1 = Wo[(k0 + 1) * EMB_D + tid];
            float w2 = Wo[(k0 + 2) * EMB_D + tid], w3 = Wo[(k0 + 3) * EMB_D + tid];
#pragma unroll
            for (int s = 0; s < SEQ; s++) {
                const float4 t4 = *(const float4*)&sm.qb[s][k0];
                ao[s] = fmaf(t4.x, w0, fmaf(t4.y, w1, fmaf(t4.z, w2, fmaf(t4.w, w3, ao[s]))));
            }
        }
        float bo_ = bo[tid];
#pragma unroll
        for (int s = 0; s < SEQ; s++) sm.t0[s][tid] = sm.t0[s][tid] + ao[s] + bo_;
    }
    __syncthreads();
    // 5) LayerNorm rows (wave per 4 rows)
    {
        const int wid = tid >> 6, lane = tid & 63;
#pragma unroll
        for (int r = 0; r < 4; r++) {
            const int s = wid * 4 + r;
            float v[4];
            float sum = 0.f, sq = 0.f;
#pragma unroll
            for (int j = 0; j < 4; j++) {
                int c = lane + j * 64;
                v[j] = sm.t0[s][c];
                sum += v[j];
                sq = fmaf(v[j], v[j], sq);
            }
            sum = warpReduceSum(sum);
            sq = warpReduceSum(sq);
            float mu = sum * (1.f / 256.f);
            float var = sq * (1.f / 256.f) - mu * mu;
            float rstd = rsqrtf(var + 1e-5f);
#pragma unroll
            for (int j = 0; j < 4; j++) {
                int c = lane + j * 64;
                sm.t0[s][c] = (v[j] - mu) * rstd * lng[c] + lnb[c];
            }
        }
    }
    __syncthreads();
}

__global__ __launch_bounds__(256) void t1_kernel(const float* __restrict__ emb, const int* __restrict__ text2,
                                                 const float* __restrict__ Wq, const float* __restrict__ Wk,
                                                 const float* __restrict__ Wv, const float* __restrict__ Wo,
                                                 const float* __restrict__ bq, const float* __restrict__ bk,
                                                 const float* __restrict__ bv, const float* __restrict__ bo,
                                                 const float* __restrict__ lng, const float* __restrict__ lnb,
                                                 float* __restrict__ cat) {
    __shared__ TSmem sm;
    const int node = blockIdx.x;
    transformer_node(sm, node, emb, text2, Wq, Wk, Wv, Wo, bq, bk, bv, bo, lng, lnb);
    const int tid = threadIdx.x;
    float s = 0.f;
#pragma unroll
    for (int r = 0; r < SEQ; r++) s += sm.t0[r][tid];
    cat[(size_t)node * 512 + 256 + tid] = s * (1.f / 16.f);
}

// conv over one output channel: register-blocked over positions, t reads are uniform LDS broadcasts
template <int K>
__device__ __forceinline__ float conv_max(const float (&t0)[SEQ][EMB_D], const float* __restrict__ w, float bias) {
    constexpr int L = SEQ - K + 1;
    float acc[L];
#pragma unroll
    for (int p = 0; p < L; p++) acc[p] = bias;
#pragma unroll
    for (int r = 0; r < SEQ; r++) {
        for (int ic = 0; ic < EMB_D; ic += 4) {
            const float4 t4 = *(const float4*)&t0[r][ic];
#pragma unroll
            for (int p = 0; p < L; p++) {
                const int kk = r - p;
                if (kk >= 0 && kk < K) {
                    const float4 w4 = *(const float4*)&w[(size_t)kk * EMB_D + ic];
                    acc[p] = fmaf(t4.x, w4.x, fmaf(t4.y, w4.y, fmaf(t4.z, w4.z, fmaf(t4.w, w4.w, acc[p]))));
                }
            }
        }
    }
    float m = acc[0];
#pragma unroll
    for (int p = 1; p < L; p++) m = fmaxf(m, acc[p]);
    return fmaxf(m, 0.f);  // relu then max == max then relu (monotone)
}

__global__ __launch_bounds__(256) void t2_kernel(const float* __restrict__ emb, const int* __restrict__ text2,
                                                 const float* __restrict__ Wq, const float* __restrict__ Wk,
                                                 const float* __restrict__ Wv, const float* __restrict__ Wo,
                                                 const float* __restrict__ bq, const float* __restrict__ bk,
                                                 const float* __restrict__ bv, const float* __restrict__ bo,
                                                 const float* __restrict__ lng, const float* __restrict__ lnb,
                                                 const int* __restrict__ rooti, const int* __restrict__ rpi,
                                                 const float* __restrict__ wre, const float* __restrict__ cb0,
                                                 const float* __restrict__ cb1, const float* __restrict__ cb2,
                                                 const float* __restrict__ cb3, float* __restrict__ fin) {
    __shared__ TSmem sm;
    const int slot = blockIdx.x;
    const int idx = (slot < N_ROOTS) ? slot : slot - N_ROOTS;
    const int node = (slot < N_ROOTS) ? rooti[idx] : rpi[idx];
    const int colbase = (slot < N_ROOTS) ? 128 : 628;
    transformer_node(sm, node, emb, text2, Wq, Wk, Wv, Wo, bq, bk, bv, bo, lng, lnb);
    const int tid = threadIdx.x;
    if (tid < OUT_CH) {
        // repacked weight offsets: [oc][kk][ic]
        const float* w5 = wre + 0 + (size_t)tid * 5 * EMB_D;
        const float* w6 = wre + 160000 + (size_t)tid * 6 * EMB_D;
        const float* w7 = wre + 352000 + (size_t)tid * 7 * EMB_D;
        const float* w8 = wre + 576000 + (size_t)tid * 8 * EMB_D;
        float r0 = conv_max<5>(sm.t0, w5, cb0[tid]);
        float r1 = conv_max<6>(sm.t0, w6, cb1[tid]);
        float r2 = conv_max<7>(sm.t0, w7, cb2[tid]);
        float r3 = conv_max<8>(sm.t0, w8, cb3[tid]);
        float* dst = fin + (size_t)idx * 1128 + colbase;
        dst[0 * 125 + tid] = r0;
        dst[1 * 125 + tid] = r1;
        dst[2 * 125 + tid] = r2;
        dst[3 * 125 + tid] = r3;
    }
}

// ---------- host launch ----------
extern "C" void kernel_launch(void* const* d_in, const int* in_sizes, int n_in, void* d_out, int out_size, void* d_ws,
                              size_t ws_size, hipStream_t stream) {
    const float* x2 = (const float*)d_in[0];
    const float* emb = (const float*)d_in[1];
    const float* Wq = (const float*)d_in[2];
    const float* Wk = (const float*)d_in[3];
    const float* Wv = (const float*)d_in[4];
    const float* Wo = (const float*)d_in[5];
    const float* bq = (const float*)d_in[6];
    const float* bk = (const float*)d_in[7];
    const float* bv = (const float*)d_in[8];
    const float* bo = (const float*)d_in[9];
    const float* lng = (const float*)d_in[10];
    const float* lnb = (const float*)d_in[11];
    const float* gat1_W = (const float*)d_in[12];
    const float* gat1_as = (const float*)d_in[13];
    const float* gat1_ad = (const float*)d_in[14];
    const float* gat1_b = (const float*)d_in[15];
    const float* gcn1_W = (const float*)d_in[16];
    const float* gcn1_b = (const float*)d_in[17];
    const float* gat2_W = (const float*)d_in[18];
    const float* gat2_as = (const float*)d_in[19];
    const float* gat2_ad = (const float*)d_in[20];
    const float* gat2_b = (const float*)d_in[21];
    // d_in[22]=gcn2_W, d_in[23]=gcn2_b : dead code in the reference forward — skipped
    const float* cw0 = (const float*)d_in[24];
    const float* cb0 = (const float*)d_in[25];
    const float* cw1 = (const float*)d_in[26];
    const float* cb1 = (const float*)d_in[27];
    const float* cw2 = (const float*)d_in[28];
    const float* cb2 = (const float*)d_in[29];
    const float* cw3 = (const float*)d_in[30];
    const float* cb3 = (const float*)d_in[31];
    const float* fc1_W = (const float*)d_in[32];
    const float* fc1_b = (const float*)d_in[33];
    const float* fc2_W = (const float*)d_in[34];
    const float* fc2_b = (const float*)d_in[35];
    const int* text2 = (const int*)d_in[36];
    const int* ei = (const int*)d_in[37];
    const int* rooti = (const int*)d_in[38];
    const int* rpi = (const int*)d_in[39];

    float* ws = (float*)d_ws;
    size_t off = 0;
    auto alloc = [&](size_t n) {
        float* p = ws + off;
        off += n;
        return p;
    };
    // zero block (one memset): cat | gat2_out | den1 | den2 | deg
    float* cat = alloc((size_t)N_NODES * 512);
    float* g2o = alloc((size_t)N_NODES * FEAT);
    float* den1 = alloc(N_NODES);
    float* den2 = alloc(N_NODES);
    float* deg = alloc(N_NODES);
    size_t zero_floats = off;
    float* h1 = alloc((size_t)N_NODES * FEAT);
    float* h2 = alloc((size_t)N_NODES * FEAT);
    float* hg2 = alloc((size_t)N_NODES * FEAT);
    float* als1 = alloc(N_NODES);
    float* ald1 = alloc(N_NODES);
    float* als2 = alloc(N_NODES);
    float* ald2 = alloc(N_NODES);
    int* m1 = (int*)alloc(N_NODES);
    int* m2 = (int*)alloc(N_NODES);  // contiguous after m1
    float* el1 = alloc(ET_EDGES);
    float* el2 = alloc(ET_EDGES);
    float* fin = alloc((size_t)N_ROOTS * 1128);
    float* fch = alloc((size_t)N_ROOTS * 300);
    float* wre = alloc(832000);
    (void)ws_size;
    (void)in_sizes;
    (void)n_in;
    (void)out_size;

    hipMemsetAsync(d_ws, 0, zero_floats * sizeof(float), stream);
    fill_i32<<<cdiv(2 * N_NODES, 256), 256, 0, stream>>>(m1, (int)0x80000000, 2 * N_NODES);
    repack_conv<<<cdiv(160000, 256), 256, 0, stream>>>(cw0, wre + 0, 5, 160000);
    repack_conv<<<cdiv(192000, 256), 256, 0, stream>>>(cw1, wre + 160000, 6, 192000);
    repack_conv<<<cdiv(224000, 256), 256, 0, stream>>>(cw2, wre + 352000, 7, 224000);
    repack_conv<<<cdiv(256000, 256), 256, 0, stream>>>(cw3, wre + 576000, 8, 256000);

    // GAT1 / GCN1 node transforms
    gemm64<<<dim3(2, 512), 256, 0, stream>>>(x2, gat1_W, nullptr, h1, N_NODES, FEAT, FEAT, FEAT, FEAT, 0);
    gemm64<<<dim3(2, 512), 256, 0, stream>>>(x2, gcn1_W, nullptr, h2, N_NODES, FEAT, FEAT, FEAT, FEAT, 0);
    alpha_kernel<<<cdiv((long long)N_NODES * 64, 256), 256, 0, stream>>>(h1, gat1_as, gat1_ad, als1, ald1);
    // GAT1 edge softmax (+degree count for GCN)
    edge_p1<<<cdiv(ET_EDGES, 256), 256, 0, stream>>>(ei, als1, ald1, el1, m1, deg);
    edge_p2<<<cdiv(ET_EDGES, 256), 256, 0, stream>>>(ei, el1, m1, den1);
    edge_p2b<<<cdiv(ET_EDGES, 256), 256, 0, stream>>>(ei, el1, den1);
    dinv_kernel<<<cdiv(N_NODES, 256), 256, 0, stream>>>(deg);
    const int sc_blocks = cdiv((long long)ET_EDGES * FEAT, 256);
    edge_scatter<<<sc_blocks, 256, 0, stream>>>(ei, el1, h1, cat + 0, 512);
    gcn_scatter<<<sc_blocks, 256, 0, stream>>>(ei, deg, h2, cat + 128, 512);
    // transformer -> t_avg into cat[:,256:512]
    t1_kernel<<<N_NODES, 256, 0, stream>>>(emb, text2, Wq, Wk, Wv, Wo, bq, bk, bv, bo, lng, lnb, cat);
    biasadd_cat<<<cdiv((long long)N_NODES * 256, 256), 256, 0, stream>>>(cat, gat1_b, gcn1_b);
    // GAT2
    gemm64<<<dim3(2, 512), 256, 0, stream>>>(cat, gat2_W, nullptr, hg2, N_NODES, FEAT, 512, 512, FEAT, 0);
    alpha_kernel<<<cdiv((long long)N_NODES * 64, 256), 256, 0, stream>>>(hg2, gat2_as, gat2_ad, als2, ald2);
    edge_p1<<<cdiv(ET_EDGES, 256), 256, 0, stream>>>(ei, als2, ald2, el2, m2, nullptr);
    edge_p2<<<cdiv(ET_EDGES, 256), 256, 0, stream>>>(ei, el2, m2, den2);
    edge_p2b<<<cdiv(ET_EDGES, 256), 256, 0, stream>>>(ei, el2, den2);
    edge_scatter<<<sc_blocks, 256, 0, stream>>>(ei, el2, hg2, g2o, FEAT);
    // head
    root_gather<<<cdiv(N_ROOTS * FEAT, 256), 256, 0, stream>>>(g2o, rooti, gat2_b, fin);
    t2_kernel<<<2 * N_ROOTS, 256, 0, stream>>>(emb, text2, Wq, Wk, Wv, Wo, bq, bk, bv, bo, lng, lnb, rooti, rpi, wre,
                                               cb0, cb1, cb2, cb3, fin);
    gemm64<<<dim3(cdiv(300, 64), cdiv(N_ROOTS, 64)), 256, 0, stream>>>(fin, fc1_W, fc1_b, fch, N_ROOTS, 300, 1128,
                                                                       1128, 300, 1);
    fc2_kernel<<<cdiv(N_ROOTS * 3, 256), 256, 0, stream>>>(fch, fc2_W, fc2_b, (float*)d_out);
}

// Round 2
// 7050.212 us; speedup vs baseline: 2.3724x; 2.3724x over previous
//
#include <hip/hip_runtime.h>
#include <hip/hip_bf16.h>
#include <cstdint>
#include <cstddef>

#define N_NODES 32768
#define N_EDGES 131072
#define ET_EDGES (N_EDGES + N_NODES)
#define N_ROOTS 1024
#define EMB_D 256
#define FEAT 128
#define SEQ 16
#define OUT_CH 125

static inline int cdiv(long long a, long long b) { return (int)((a + b - 1) / b); }

typedef short short8 __attribute__((ext_vector_type(8)));
typedef float f32x4 __attribute__((ext_vector_type(4)));

// ---------- small utils ----------
__device__ __forceinline__ float warpReduceSum(float v) {
#pragma unroll
    for (int m = 32; m; m >>= 1) v += __shfl_xor(v, m, 64);
    return v;
}
// order-preserving float<->int encoding for atomicMax on signed int
__device__ __forceinline__ int encf(float f) {
    int i = __float_as_int(f);
    return i >= 0 ? i : (i ^ 0x7fffffff);
}
__device__ __forceinline__ float decf(int i) {
    return __int_as_float(i >= 0 ? i : (i ^ 0x7fffffff));
}

__global__ void fill_i32(int* p, int v, int n) {
    int i = blockIdx.x * 256 + threadIdx.x;
    if (i < n) p[i] = v;
}

// pack all 4 conv kernels into W_all[512][2048] bf16; row r=(Kidx*125+oc), col c=k*256+ic,
// zero beyond K, zero rows 500..511. Source layout [oc][ic][k].
__global__ void repack_wall(const float* __restrict__ cw0, const float* __restrict__ cw1,
                            const float* __restrict__ cw2, const float* __restrict__ cw3,
                            __hip_bfloat16* __restrict__ wall) {
    int i = blockIdx.x * 256 + threadIdx.x;
    if (i >= 512 * 2048) return;
    int r = i >> 11, c = i & 2047;
    int k = c >> 8, ic = c & 255;
    float v = 0.f;
    if (r < 500) {
        int Kidx = r / 125, oc = r - Kidx * 125;
        int K = 5 + Kidx;
        if (k < K) {
            const float* cw = Kidx == 0 ? cw0 : Kidx == 1 ? cw1 : Kidx == 2 ? cw2 : cw3;
            v = cw[((size_t)oc * 256 + ic) * K + k];
        }
    }
    wall[i] = __float2bfloat16(v);
}

// ---------- generic fp32 GEMM: C[M,N] = A[M,K] @ B[K,N] (+bias, +relu) ----------
__global__ __launch_bounds__(256) void gemm64(const float* __restrict__ A, const float* __restrict__ B,
                                              const float* __restrict__ bias, float* __restrict__ C,
                                              int M, int N, int K, int lda, int ldc, int doRelu) {
    __shared__ float As[16][65];
    __shared__ float Bs[16][65];
    const int bm = blockIdx.y * 64, bn = blockIdx.x * 64;
    const int tid = threadIdx.x;
    const int tx = tid & 15, ty = tid >> 4;
    float acc[4][4] = {};
    for (int k0 = 0; k0 < K; k0 += 16) {
#pragma unroll
        for (int j = 0; j < 4; j++) {
            int i = tid + j * 256;
            int kk = i & 15, m = i >> 4;
            int gr = bm + m, gc = k0 + kk;
            As[kk][m] = (gr < M && gc < K) ? A[(size_t)gr * lda + gc] : 0.f;
        }
#pragma unroll
        for (int j = 0; j < 4; j++) {
            int i = tid + j * 256;
            int n = i & 63, kk = i >> 6;
            int gr = k0 + kk, gc = bn + n;
            Bs[kk][n] = (gr < K && gc < N) ? B[(size_t)gr * N + gc] : 0.f;
        }
        __syncthreads();
#pragma unroll
        for (int kk = 0; kk < 16; kk++) {
            float a[4], b[4];
#pragma unroll
            for (int i2 = 0; i2 < 4; i2++) a[i2] = As[kk][ty * 4 + i2];
#pragma unroll
            for (int j2 = 0; j2 < 4; j2++) b[j2] = Bs[kk][tx * 4 + j2];
#pragma unroll
            for (int i2 = 0; i2 < 4; i2++)
#pragma unroll
                for (int j2 = 0; j2 < 4; j2++) acc[i2][j2] = fmaf(a[i2], b[j2], acc[i2][j2]);
        }
        __syncthreads();
    }
#pragma unroll
    for (int i2 = 0; i2 < 4; i2++) {
        int r = bm + ty * 4 + i2;
        if (r >= M) continue;
#pragma unroll
        for (int j2 = 0; j2 < 4; j2++) {
            int c = bn + tx * 4 + j2;
            if (c >= N) continue;
            float v = acc[i2][j2];
            if (bias) v += bias[c];
            if (doRelu) v = fmaxf(v, 0.f);
            C[(size_t)r * ldc + c] = v;
        }
    }
}

// ---------- node alpha: al_s = h @ a_src, al_d = h @ a_dst (one wave per node) ----------
__global__ __launch_bounds__(256) void alpha_kernel(const float* __restrict__ h, const float* __restrict__ asrc,
                                                    const float* __restrict__ adst, float* __restrict__ als,
                                                    float* __restrict__ ald) {
    int gw = (blockIdx.x * 256 + threadIdx.x) >> 6;
    int lane = threadIdx.x & 63;
    if (gw >= N_NODES) return;
    const float* row = h + (size_t)gw * FEAT;
    float v0 = row[lane], v1 = row[lane + 64];
    float ps = v0 * asrc[lane] + v1 * asrc[lane + 64];
    float pd = v0 * adst[lane] + v1 * adst[lane + 64];
    ps = warpReduceSum(ps);
    pd = warpReduceSum(pd);
    if (lane == 0) {
        als[gw] = ps;
        ald[gw] = pd;
    }
}

// ---------- edge passes (src/dst with implicit self loops appended) ----------
__device__ __forceinline__ void edge_decode(int i, const int* __restrict__ ei, int& s, int& d) {
    if (i < N_EDGES) {
        s = ei[i];
        d = ei[N_EDGES + i];
    } else {
        s = d = i - N_EDGES;
    }
}

__global__ void edge_p1(const int* __restrict__ ei, const float* __restrict__ als, const float* __restrict__ ald,
                        float* __restrict__ elog, int* __restrict__ menc, float* dega) {
    int i = blockIdx.x * 256 + threadIdx.x;
    if (i >= ET_EDGES) return;
    int s, d;
    edge_decode(i, ei, s, d);
    float e = als[s] + ald[d];
    e = (e >= 0.f) ? e : 0.2f * e;  // LeakyReLU(0.2)
    elog[i] = e;
    atomicMax(&menc[d], encf(e));
    if (dega) unsafeAtomicAdd(&dega[d], 1.f);
}

__global__ void edge_p2(const int* __restrict__ ei, float* __restrict__ elog, const int* __restrict__ menc,
                        float* __restrict__ den) {
    int i = blockIdx.x * 256 + threadIdx.x;
    if (i >= ET_EDGES) return;
    int s, d;
    edge_decode(i, ei, s, d);
    float ex = expf(elog[i] - decf(menc[d]));
    elog[i] = ex;
    unsafeAtomicAdd(&den[d], ex);
}

__global__ void edge_p2b(const int* __restrict__ ei, float* __restrict__ elog, const float* __restrict__ den) {
    int i = blockIdx.x * 256 + threadIdx.x;
    if (i >= ET_EDGES) return;
    int s, d;
    edge_decode(i, ei, s, d);
    elog[i] = elog[i] / den[d];
}

__global__ void dinv_kernel(float* deg) {
    int i = blockIdx.x * 256 + threadIdx.x;
    if (i < N_NODES) deg[i] = rsqrtf(fmaxf(deg[i], 1.f));
}

// out[dst] += coef[e] * h[src], 128 feats per edge
__global__ void edge_scatter(const int* __restrict__ ei, const float* __restrict__ coef, const float* __restrict__ h,
                             float* __restrict__ out, int ldo) {
    int i = blockIdx.x * 256 + threadIdx.x;
    if (i >= ET_EDGES * FEAT) return;
    int e = i >> 7, f = i & 127;
    int s, d;
    edge_decode(e, ei, s, d);
    unsafeAtomicAdd(&out[(size_t)d * ldo + f], coef[e] * h[(size_t)s * FEAT + f]);
}

// GCN: out[dst] += dinv[src]*dinv[dst] * h[src]
__global__ void gcn_scatter(const int* __restrict__ ei, const float* __restrict__ dinv, const float* __restrict__ h,
                            float* __restrict__ out, int ldo) {
    int i = blockIdx.x * 256 + threadIdx.x;
    if (i >= ET_EDGES * FEAT) return;
    int e = i >> 7, f = i & 127;
    int s, d;
    edge_decode(e, ei, s, d);
    float coef = dinv[s] * dinv[d];
    unsafeAtomicAdd(&out[(size_t)d * ldo + f], coef * h[(size_t)s * FEAT + f]);
}

__global__ void biasadd_cat(float* __restrict__ cat, const float* __restrict__ b1, const float* __restrict__ b2) {
    int i = blockIdx.x * 256 + threadIdx.x;  // over N*256
    int n = i >> 8, c = i & 255;
    float b = (c < 128) ? b1[c] : b2[c - 128];
    cat[(size_t)n * 512 + c] += b;
}

__global__ void root_gather(const float* __restrict__ g2, const int* __restrict__ rooti, const float* __restrict__ gb,
                            float* __restrict__ fin) {
    int i = blockIdx.x * 256 + threadIdx.x;
    if (i >= N_ROOTS * FEAT) return;
    int r = i >> 7, c = i & 127;
    fin[(size_t)r * 1128 + c] = g2[(size_t)rooti[r] * FEAT + c] + gb[c];
}

__global__ void fc2_kernel(const float* __restrict__ fch, const float* __restrict__ W, const float* __restrict__ b,
                           float* __restrict__ out) {
    int i = blockIdx.x * 256 + threadIdx.x;
    if (i >= N_ROOTS * 3) return;
    int r = i / 3, c = i - r * 3;
    float acc = b[c];
    for (int k = 0; k < 300; k++) acc = fmaf(fch[(size_t)r * 300 + k], W[k * 3 + c], acc);
    out[i] = acc;
}

// ---------- per-node transformer block (256 threads, LDS exactly 64 KB) ----------
struct TSmem {
    float t0[SEQ][EMB_D];  // input t, later: residual+LN output
    float qb[SEQ][EMB_D];  // q; re-used as attention output (per-thread-exclusive region, safe alias)
    float kb[SEQ][EMB_D];
    float vb[SEQ][EMB_D];
};

__device__ __forceinline__ void transformer_node(TSmem& sm, int node, const float* __restrict__ emb,
                                                 const int* __restrict__ text2, const float* __restrict__ Wq,
                                                 const float* __restrict__ Wk, const float* __restrict__ Wv,
                                                 const float* __restrict__ Wo, const float* __restrict__ bq,
                                                 const float* __restrict__ bk, const float* __restrict__ bv,
                                                 const float* __restrict__ bo, const float* __restrict__ lng,
                                                 const float* __restrict__ lnb) {
    const int tid = threadIdx.x;
#pragma unroll
    for (int s = 0; s < SEQ; s++) {
        int tok = text2[node * SEQ + s];
        sm.t0[s][tid] = emb[(size_t)tok * EMB_D + tid];
    }
    __syncthreads();
    // fused q/k/v projection; thread = output column
    {
        float aq[SEQ], ak[SEQ], av[SEQ];
#pragma unroll
        for (int s = 0; s < SEQ; s++) {
            aq[s] = 0.f;
            ak[s] = 0.f;
            av[s] = 0.f;
        }
        for (int k0 = 0; k0 < EMB_D; k0 += 4) {
            float wq0 = Wq[(k0 + 0) * EMB_D + tid], wq1 = Wq[(k0 + 1) * EMB_D + tid];
            float wq2 = Wq[(k0 + 2) * EMB_D + tid], wq3 = Wq[(k0 + 3) * EMB_D + tid];
            float wk0 = Wk[(k0 + 0) * EMB_D + tid], wk1 = Wk[(k0 + 1) * EMB_D + tid];
            float wk2 = Wk[(k0 + 2) * EMB_D + tid], wk3 = Wk[(k0 + 3) * EMB_D + tid];
            float wv0 = Wv[(k0 + 0) * EMB_D + tid], wv1 = Wv[(k0 + 1) * EMB_D + tid];
            float wv2 = Wv[(k0 + 2) * EMB_D + tid], wv3 = Wv[(k0 + 3) * EMB_D + tid];
#pragma unroll
            for (int s = 0; s < SEQ; s++) {
                const float4 t4 = *(const float4*)&sm.t0[s][k0];
                aq[s] = fmaf(t4.x, wq0, fmaf(t4.y, wq1, fmaf(t4.z, wq2, fmaf(t4.w, wq3, aq[s]))));
                ak[s] = fmaf(t4.x, wk0, fmaf(t4.y, wk1, fmaf(t4.z, wk2, fmaf(t4.w, wk3, ak[s]))));
                av[s] = fmaf(t4.x, wv0, fmaf(t4.y, wv1, fmaf(t4.z, wv2, fmaf(t4.w, wv3, av[s]))));
            }
        }
        float bq_ = bq[tid], bk_ = bk[tid], bv_ = bv[tid];
#pragma unroll
        for (int s = 0; s < SEQ; s++) {
            sm.qb[s][tid] = aq[s] + bq_;
            sm.kb[s][tid] = ak[s] + bk_;
            sm.vb[s][tid] = av[s] + bv_;
        }
    }
    __syncthreads();
    // attention: thread = (head, query-row)
    {
        const int h = tid >> 4, qi = tid & 15, base = h * 16;
        float qv[16];
#pragma unroll
        for (int d = 0; d < 16; d += 4) {
            float4 q4 = *(const float4*)&sm.qb[qi][base + d];
            qv[d] = q4.x;
            qv[d + 1] = q4.y;
            qv[d + 2] = q4.z;
            qv[d + 3] = q4.w;
        }
        float sc[SEQ];
#pragma unroll
        for (int kj = 0; kj < SEQ; kj++) {
            float a = 0.f;
#pragma unroll
            for (int d = 0; d < 16; d += 4) {
                float4 k4 = *(const float4*)&sm.kb[kj][base + d];
                a = fmaf(qv[d], k4.x, fmaf(qv[d + 1], k4.y, fmaf(qv[d + 2], k4.z, fmaf(qv[d + 3], k4.w, a))));
            }
            sc[kj] = a * 0.25f;
        }
        float mx = sc[0];
#pragma unroll
        for (int kj = 1; kj < SEQ; kj++) mx = fmaxf(mx, sc[kj]);
        float sum = 0.f;
#pragma unroll
        for (int kj = 0; kj < SEQ; kj++) {
            sc[kj] = expf(sc[kj] - mx);
            sum += sc[kj];
        }
        float inv = 1.f / sum;
        float ov[16];
#pragma unroll
        for (int d = 0; d < 16; d++) ov[d] = 0.f;
#pragma unroll
        for (int kj = 0; kj < SEQ; kj++) {
            float p = sc[kj];
#pragma unroll
            for (int d = 0; d < 16; d += 4) {
                float4 v4 = *(const float4*)&sm.vb[kj][base + d];
                ov[d] = fmaf(p, v4.x, ov[d]);
                ov[d + 1] = fmaf(p, v4.y, ov[d + 1]);
                ov[d + 2] = fmaf(p, v4.z, ov[d + 2]);
                ov[d + 3] = fmaf(p, v4.w, ov[d + 3]);
            }
        }
#pragma unroll
        for (int d = 0; d < 16; d += 4) {
            float4 o4 = make_float4(ov[d] * inv, ov[d + 1] * inv, ov[d + 2] * inv, ov[d + 3] * inv);
            *(float4*)&sm.qb[qi][base + d] = o4;
        }
    }
    __syncthreads();
    // output projection + residual
    {
        float ao[SEQ];
#pragma unroll
        for (int s = 0; s < SEQ; s++) ao[s] = 0.f;
        for (int k0 = 0; k0 < EMB_D; k0 += 4) {
            float w0 = Wo[(k0 + 0) * EMB_D + tid], w1 = Wo[(k0 + 1) * EMB_D + tid];
            float w2 = Wo[(k0 + 2) * EMB_D + tid], w3 = Wo[(k0 + 3) * EMB_D + tid];
#pragma unroll
            for (int s = 0; s < SEQ; s++) {
                const float4 t4 = *(const float4*)&sm.qb[s][k0];
                ao[s] = fmaf(t4.x, w0, fmaf(t4.y, w1, fmaf(t4.z, w2, fmaf(t4.w, w3, ao[s]))));
            }
        }
        float bo_ = bo[tid];
#pragma unroll
        for (int s = 0; s < SEQ; s++) sm.t0[s][tid] = sm.t0[s][tid] + ao[s] + bo_;
    }
    __syncthreads();
    // LayerNorm rows (wave per 4 rows)
    {
        const int wid = tid >> 6, lane = tid & 63;
#pragma unroll
        for (int r = 0; r < 4; r++) {
            const int s = wid * 4 + r;
            float v[4];
            float sum = 0.f, sq = 0.f;
#pragma unroll
            for (int j = 0; j < 4; j++) {
                int c = lane + j * 64;
                v[j] = sm.t0[s][c];
                sum += v[j];
                sq = fmaf(v[j], v[j], sq);
            }
            sum = warpReduceSum(sum);
            sq = warpReduceSum(sq);
            float mu = sum * (1.f / 256.f);
            float var = sq * (1.f / 256.f) - mu * mu;
            float rstd = rsqrtf(var + 1e-5f);
#pragma unroll
            for (int j = 0; j < 4; j++) {
                int c = lane + j * 64;
                sm.t0[s][c] = (v[j] - mu) * rstd * lng[c] + lnb[c];
            }
        }
    }
    __syncthreads();
}

__global__ __launch_bounds__(256) void t1_kernel(const float* __restrict__ emb, const int* __restrict__ text2,
                                                 const float* __restrict__ Wq, const float* __restrict__ Wk,
                                                 const float* __restrict__ Wv, const float* __restrict__ Wo,
                                                 const float* __restrict__ bq, const float* __restrict__ bk,
                                                 const float* __restrict__ bv, const float* __restrict__ bo,
                                                 const float* __restrict__ lng, const float* __restrict__ lnb,
                                                 float* __restrict__ cat) {
    __shared__ TSmem sm;
    const int node = blockIdx.x;
    transformer_node(sm, node, emb, text2, Wq, Wk, Wv, Wo, bq, bk, bv, bo, lng, lnb);
    const int tid = threadIdx.x;
    float s = 0.f;
#pragma unroll
    for (int r = 0; r < SEQ; r++) s += sm.t0[r][tid];
    cat[(size_t)node * 512 + 256 + tid] = s * (1.f / 16.f);
}

// transformer for the 2048 root/rootpost slots -> tbuf[slot][24][256] bf16 (rows 16..23 zero pad)
__global__ __launch_bounds__(256) void t2a_kernel(const float* __restrict__ emb, const int* __restrict__ text2,
                                                  const float* __restrict__ Wq, const float* __restrict__ Wk,
                                                  const float* __restrict__ Wv, const float* __restrict__ Wo,
                                                  const float* __restrict__ bq, const float* __restrict__ bk,
                                                  const float* __restrict__ bv, const float* __restrict__ bo,
                                                  const float* __restrict__ lng, const float* __restrict__ lnb,
                                                  const int* __restrict__ rooti, const int* __restrict__ rpi,
                                                  __hip_bfloat16* __restrict__ tbuf) {
    __shared__ TSmem sm;
    const int slot = blockIdx.x;
    const int node = (slot < N_ROOTS) ? rooti[slot] : rpi[slot - N_ROOTS];
    transformer_node(sm, node, emb, text2, Wq, Wk, Wv, Wo, bq, bk, bv, bo, lng, lnb);
    const int tid = threadIdx.x;
    __hip_bfloat16* dst = tbuf + (size_t)slot * 24 * 256 + tid;
#pragma unroll
    for (int r = 0; r < SEQ; r++) dst[r * 256] = __float2bfloat16(sm.t0[r][tid]);
#pragma unroll
    for (int r = SEQ; r < 24; r++) dst[r * 256] = __float2bfloat16(0.f);
}

// C[24576,512] = A[24576,2048] @ W_all^T ; A row m=slot*12+p is tbuf+(slot*24+p)*256 (implicit im2col)
// 128x128 tile, BK=32, bf16 MFMA 16x16x32, stride-40 padded LDS (conflict-free b128 reads)
__global__ __launch_bounds__(256) void conv_gemm(const short* __restrict__ tb, const short* __restrict__ wall,
                                                 float* __restrict__ C) {
    __shared__ short As[128 * 40];
    __shared__ short Bs[128 * 40];
    const int bid = blockIdx.x;
    const int m0 = (bid >> 2) * 128;
    const int n0 = (bid & 3) * 128;
    const int tid = threadIdx.x;
    const int lane = tid & 63;
    const int wave = tid >> 6;
    const int wm = (wave >> 1) * 64, wn = (wave & 1) * 64;
    const int quad = lane >> 4, l16 = lane & 15;

    // staging: 512 16B-chunks per tile; thread covers chunk tid (rows 0..63) and tid+256 (rows 64..127)
    const int r0 = tid >> 2, kc = (tid & 3) * 8;
    const int r1 = r0 + 64;
    const int am0 = m0 + r0, am1 = m0 + r1;
    const int s0 = am0 / 12, p0_ = am0 - s0 * 12;
    const int s1 = am1 / 12, p1_ = am1 - s1 * 12;
    const size_t ga0 = (size_t)(s0 * 24 + p0_) * 256 + kc;
    const size_t ga1 = (size_t)(s1 * 24 + p1_) * 256 + kc;
    const size_t gb0 = (size_t)(n0 + r0) * 2048 + kc;
    const size_t gb1 = (size_t)(n0 + r1) * 2048 + kc;
    short* sa0 = As + r0 * 40 + kc;
    short* sa1 = As + r1 * 40 + kc;
    short* sb0 = Bs + r0 * 40 + kc;
    short* sb1 = Bs + r1 * 40 + kc;

    f32x4 acc[4][4];
#pragma unroll
    for (int i = 0; i < 4; i++)
#pragma unroll
        for (int j = 0; j < 4; j++) acc[i][j] = (f32x4){0.f, 0.f, 0.f, 0.f};

    for (int k0 = 0; k0 < 2048; k0 += 32) {
        short8 a0 = *(const short8*)(tb + ga0 + k0);
        short8 a1 = *(const short8*)(tb + ga1 + k0);
        short8 b0 = *(const short8*)(wall + gb0 + k0);
        short8 b1 = *(const short8*)(wall + gb1 + k0);
        *(short8*)sa0 = a0;
        *(short8*)sa1 = a1;
        *(short8*)sb0 = b0;
        *(short8*)sb1 = b1;
        __syncthreads();
        short8 af[4], bfr[4];
#pragma unroll
        for (int i = 0; i < 4; i++) af[i] = *(const short8*)(As + (wm + i * 16 + l16) * 40 + quad * 8);
#pragma unroll
        for (int j = 0; j < 4; j++) bfr[j] = *(const short8*)(Bs + (wn + j * 16 + l16) * 40 + quad * 8);
#pragma unroll
        for (int i = 0; i < 4; i++)
#pragma unroll
            for (int j = 0; j < 4; j++)
                acc[i][j] = __builtin_amdgcn_mfma_f32_16x16x32_bf16(af[i], bfr[j], acc[i][j], 0, 0, 0);
        __syncthreads();
    }
#pragma unroll
    for (int i = 0; i < 4; i++) {
#pragma unroll
        for (int j = 0; j < 4; j++) {
            const int col = n0 + wn + j * 16 + l16;
            const size_t base = (size_t)(m0 + wm + i * 16 + quad * 4) * 512 + col;
#pragma unroll
            for (int r = 0; r < 4; r++) C[base + (size_t)r * 512] = acc[i][j][r];
        }
    }
}

// max over valid positions + bias + relu -> fin columns
__global__ void conv_maxpool(const float* __restrict__ C, const float* __restrict__ cb0, const float* __restrict__ cb1,
                             const float* __restrict__ cb2, const float* __restrict__ cb3, float* __restrict__ fin) {
    int i = blockIdx.x * 256 + threadIdx.x;
    if (i >= 2048 * 500) return;
    int slot = i / 500, q = i - slot * 500;
    int Kidx = q / 125, oc = q - Kidx * 125;
    int L = 12 - Kidx;  // 17-(5+Kidx) valid positions
    const float* base = C + (size_t)(slot * 12) * 512 + q;
    float m = base[0];
    for (int p = 1; p < L; p++) m = fmaxf(m, base[(size_t)p * 512]);
    float b = (Kidx == 0 ? cb0 : Kidx == 1 ? cb1 : Kidx == 2 ? cb2 : cb3)[oc];
    float v = fmaxf(m + b, 0.f);
    int idx = slot < N_ROOTS ? slot : slot - N_ROOTS;
    int colbase = slot < N_ROOTS ? 128 : 628;
    fin[(size_t)idx * 1128 + colbase + q] = v;
}

// ---------- host launch ----------
extern "C" void kernel_launch(void* const* d_in, const int* in_sizes, int n_in, void* d_out, int out_size, void* d_ws,
                              size_t ws_size, hipStream_t stream) {
    const float* x2 = (const float*)d_in[0];
    const float* emb = (const float*)d_in[1];
    const float* Wq = (const float*)d_in[2];
    const float* Wk = (const float*)d_in[3];
    const float* Wv = (const float*)d_in[4];
    const float* Wo = (const float*)d_in[5];
    const float* bq = (const float*)d_in[6];
    const float* bk = (const float*)d_in[7];
    const float* bv = (const float*)d_in[8];
    const float* bo = (const float*)d_in[9];
    const float* lng = (const float*)d_in[10];
    const float* lnb = (const float*)d_in[11];
    const float* gat1_W = (const float*)d_in[12];
    const float* gat1_as = (const float*)d_in[13];
    const float* gat1_ad = (const float*)d_in[14];
    const float* gat1_b = (const float*)d_in[15];
    const float* gcn1_W = (const float*)d_in[16];
    const float* gcn1_b = (const float*)d_in[17];
    const float* gat2_W = (const float*)d_in[18];
    const float* gat2_as = (const float*)d_in[19];
    const float* gat2_ad = (const float*)d_in[20];
    const float* gat2_b = (const float*)d_in[21];
    // d_in[22]=gcn2_W, d_in[23]=gcn2_b : dead code in the reference forward — skipped
    const float* cw0 = (const float*)d_in[24];
    const float* cb0 = (const float*)d_in[25];
    const float* cw1 = (const float*)d_in[26];
    const float* cb1 = (const float*)d_in[27];
    const float* cw2 = (const float*)d_in[28];
    const float* cb2 = (const float*)d_in[29];
    const float* cw3 = (const float*)d_in[30];
    const float* cb3 = (const float*)d_in[31];
    const float* fc1_W = (const float*)d_in[32];
    const float* fc1_b = (const float*)d_in[33];
    const float* fc2_W = (const float*)d_in[34];
    const float* fc2_b = (const float*)d_in[35];
    const int* text2 = (const int*)d_in[36];
    const int* ei = (const int*)d_in[37];
    const int* rooti = (const int*)d_in[38];
    const int* rpi = (const int*)d_in[39];

    float* ws = (float*)d_ws;
    size_t off = 0;
    auto alloc = [&](size_t n) {
        float* p = ws + off;
        off += n;
        return p;
    };
    // zero block (one memset): cat | gat2_out | den1 | den2 | deg
    float* cat = alloc((size_t)N_NODES * 512);   // later reused as conv C buffer (dead after gat2 gemm)
    float* g2o = alloc((size_t)N_NODES * FEAT);
    float* den1 = alloc(N_NODES);
    float* den2 = alloc(N_NODES);
    float* deg = alloc(N_NODES);
    size_t zero_floats = off;
    float* h1 = alloc((size_t)N_NODES * FEAT);   // h1+h2 later reused as tbuf (dead after scatters)
    float* h2 = alloc((size_t)N_NODES * FEAT);
    float* hg2 = alloc((size_t)N_NODES * FEAT);
    float* als1 = alloc(N_NODES);
    float* ald1 = alloc(N_NODES);
    float* als2 = alloc(N_NODES);
    float* ald2 = alloc(N_NODES);
    int* m1 = (int*)alloc(N_NODES);
    int* m2 = (int*)alloc(N_NODES);  // contiguous after m1
    float* el1 = alloc(ET_EDGES);
    float* el2 = alloc(ET_EDGES);
    float* fin = alloc((size_t)N_ROOTS * 1128);
    float* fch = alloc((size_t)N_ROOTS * 300);
    float* wallf = alloc(512 * 2048 / 2);  // 512x2048 bf16 = 2 MB
    (void)ws_size;
    (void)in_sizes;
    (void)n_in;
    (void)out_size;

    __hip_bfloat16* tbuf = (__hip_bfloat16*)h1;  // 2048*24*256 bf16 = 12.58M bf16, fits in h1+h2
    __hip_bfloat16* wall = (__hip_bfloat16*)wallf;
    float* Cbuf = cat;  // 24576*512 fp32 = 12.58M floats <= 16.78M

    hipMemsetAsync(d_ws, 0, zero_floats * sizeof(float), stream);
    fill_i32<<<cdiv(2 * N_NODES, 256), 256, 0, stream>>>(m1, (int)0x80000000, 2 * N_NODES);
    repack_wall<<<cdiv(512 * 2048, 256), 256, 0, stream>>>(cw0, cw1, cw2, cw3, wall);

    // GAT1 / GCN1 node transforms
    gemm64<<<dim3(2, 512), 256, 0, stream>>>(x2, gat1_W, nullptr, h1, N_NODES, FEAT, FEAT, FEAT, FEAT, 0);
    gemm64<<<dim3(2, 512), 256, 0, stream>>>(x2, gcn1_W, nullptr, h2, N_NODES, FEAT, FEAT, FEAT, FEAT, 0);
    alpha_kernel<<<cdiv((long long)N_NODES * 64, 256), 256, 0, stream>>>(h1, gat1_as, gat1_ad, als1, ald1);
    edge_p1<<<cdiv(ET_EDGES, 256), 256, 0, stream>>>(ei, als1, ald1, el1, m1, deg);
    edge_p2<<<cdiv(ET_EDGES, 256), 256, 0, stream>>>(ei, el1, m1, den1);
    edge_p2b<<<cdiv(ET_EDGES, 256), 256, 0, stream>>>(ei, el1, den1);
    dinv_kernel<<<cdiv(N_NODES, 256), 256, 0, stream>>>(deg);
    const int sc_blocks = cdiv((long long)ET_EDGES * FEAT, 256);
    edge_scatter<<<sc_blocks, 256, 0, stream>>>(ei, el1, h1, cat + 0, 512);
    gcn_scatter<<<sc_blocks, 256, 0, stream>>>(ei, deg, h2, cat + 128, 512);
    // transformer -> t_avg into cat[:,256:512]
    t1_kernel<<<N_NODES, 256, 0, stream>>>(emb, text2, Wq, Wk, Wv, Wo, bq, bk, bv, bo, lng, lnb, cat);
    // transformer for conv slots -> tbuf (h1/h2 now dead)
    t2a_kernel<<<2 * N_ROOTS, 256, 0, stream>>>(emb, text2, Wq, Wk, Wv, Wo, bq, bk, bv, bo, lng, lnb, rooti, rpi,
                                                tbuf);
    biasadd_cat<<<cdiv((long long)N_NODES * 256, 256), 256, 0, stream>>>(cat, gat1_b, gcn1_b);
    // GAT2
    gemm64<<<dim3(2, 512), 256, 0, stream>>>(cat, gat2_W, nullptr, hg2, N_NODES, FEAT, 512, 512, FEAT, 0);
    alpha_kernel<<<cdiv((long long)N_NODES * 64, 256), 256, 0, stream>>>(hg2, gat2_as, gat2_ad, als2, ald2);
    edge_p1<<<cdiv(ET_EDGES, 256), 256, 0, stream>>>(ei, als2, ald2, el2, m2, nullptr);
    edge_p2<<<cdiv(ET_EDGES, 256), 256, 0, stream>>>(ei, el2, m2, den2);
    edge_p2b<<<cdiv(ET_EDGES, 256), 256, 0, stream>>>(ei, el2, den2);
    edge_scatter<<<sc_blocks, 256, 0, stream>>>(ei, el2, hg2, g2o, FEAT);
    // conv branch: MFMA GEMM into Cbuf (cat memory now dead), then maxpool
    conv_gemm<<<192 * 4, 256, 0, stream>>>((const short*)tbuf, (const short*)wall, Cbuf);
    root_gather<<<cdiv(N_ROOTS * FEAT, 256), 256, 0, stream>>>(g2o, rooti, gat2_b, fin);
    conv_maxpool<<<cdiv(2048 * 500, 256), 256, 0, stream>>>(Cbuf, cb0, cb1, cb2, cb3, fin);
    // head
    gemm64<<<dim3(cdiv(300, 64), cdiv(N_ROOTS, 64)), 256, 0, stream>>>(fin, fc1_W, fc1_b, fch, N_ROOTS, 300, 1128,
                                                                       1128, 300, 1);
    fc2_kernel<<<cdiv(N_ROOTS * 3, 256), 256, 0, stream>>>(fch, fc2_W, fc2_b, (float*)d_out);
}

// Round 3
// 2990.886 us; speedup vs baseline: 5.5923x; 2.3572x over previous
//
#include <hip/hip_runtime.h>
#include <hip/hip_bf16.h>
#include <cstdint>
#include <cstddef>

#define N_NODES 32768
#define N_EDGES 131072
#define ET_EDGES (N_EDGES + N_NODES)
#define N_ROOTS 1024
#define EMB_D 256
#define FEAT 128
#define SEQ 16
#define OUT_CH 125

static inline int cdiv(long long a, long long b) { return (int)((a + b - 1) / b); }

typedef short short8 __attribute__((ext_vector_type(8)));
typedef float f32x4 __attribute__((ext_vector_type(4)));

// ---------- small utils ----------
__device__ __forceinline__ float warpReduceSum(float v) {
#pragma unroll
    for (int m = 32; m; m >>= 1) v += __shfl_xor(v, m, 64);
    return v;
}
__device__ __forceinline__ int encf(float f) {
    int i = __float_as_int(f);
    return i >= 0 ? i : (i ^ 0x7fffffff);
}
__device__ __forceinline__ float decf(int i) {
    return __int_as_float(i >= 0 ? i : (i ^ 0x7fffffff));
}
// fp32 -> bf16 (RNE) as raw short
__device__ __forceinline__ short f2bs(float x) {
    unsigned u = __float_as_uint(x);
    u += 0x7fffu + ((u >> 16) & 1u);
    return (short)(u >> 16);
}
__device__ __forceinline__ float bs2f(short s) {
    return __uint_as_float(((unsigned)(unsigned short)s) << 16);
}

__global__ void fill_i32(int* p, int v, int n) {
    int i = blockIdx.x * 256 + threadIdx.x;
    if (i < n) p[i] = v;
}

// pack all 4 conv kernels into W_all[512][2048] bf16 (row=(Kidx*125+oc), col=k*256+ic)
__global__ void repack_wall(const float* __restrict__ cw0, const float* __restrict__ cw1,
                            const float* __restrict__ cw2, const float* __restrict__ cw3,
                            __hip_bfloat16* __restrict__ wall) {
    int i = blockIdx.x * 256 + threadIdx.x;
    if (i >= 512 * 2048) return;
    int r = i >> 11, c = i & 2047;
    int k = c >> 8, ic = c & 255;
    float v = 0.f;
    if (r < 500) {
        int Kidx = r / 125, oc = r - Kidx * 125;
        int K = 5 + Kidx;
        if (k < K) {
            const float* cw = Kidx == 0 ? cw0 : Kidx == 1 ? cw1 : Kidx == 2 ? cw2 : cw3;
            v = cw[((size_t)oc * 256 + ic) * K + k];
        }
    }
    wall[i] = __float2bfloat16(v);
}

// transformer weights: wqkvT[768][256] bf16 (row n = output col of q|k|v, col k), woT[256][256], bqkv[768]
__global__ void repack_xf(const float* __restrict__ Wq, const float* __restrict__ Wk, const float* __restrict__ Wv,
                          const float* __restrict__ Wo, const float* __restrict__ bq, const float* __restrict__ bk,
                          const float* __restrict__ bv, short* __restrict__ wqkvT, short* __restrict__ woT,
                          float* __restrict__ bqkv) {
    int i = blockIdx.x * 256 + threadIdx.x;
    if (i < 768 * 256) {
        int n = i >> 8, k = i & 255;
        const float* W = n < 256 ? Wq : n < 512 ? Wk : Wv;
        wqkvT[i] = f2bs(W[k * 256 + (n & 255)]);
    }
    if (i < 256 * 256) {
        int n = i >> 8, k = i & 255;
        woT[i] = f2bs(Wo[k * 256 + n]);
    }
    if (i < 768) bqkv[i] = i < 256 ? bq[i] : i < 512 ? bk[i - 256] : bv[i - 512];
}

// ---------- generic fp32 GEMM (graph convs + head) ----------
__global__ __launch_bounds__(256) void gemm64(const float* __restrict__ A, const float* __restrict__ B,
                                              const float* __restrict__ bias, float* __restrict__ C,
                                              int M, int N, int K, int lda, int ldc, int doRelu) {
    __shared__ float As[16][65];
    __shared__ float Bs[16][65];
    const int bm = blockIdx.y * 64, bn = blockIdx.x * 64;
    const int tid = threadIdx.x;
    const int tx = tid & 15, ty = tid >> 4;
    float acc[4][4] = {};
    for (int k0 = 0; k0 < K; k0 += 16) {
#pragma unroll
        for (int j = 0; j < 4; j++) {
            int i = tid + j * 256;
            int kk = i & 15, m = i >> 4;
            int gr = bm + m, gc = k0 + kk;
            As[kk][m] = (gr < M && gc < K) ? A[(size_t)gr * lda + gc] : 0.f;
        }
#pragma unroll
        for (int j = 0; j < 4; j++) {
            int i = tid + j * 256;
            int n = i & 63, kk = i >> 6;
            int gr = k0 + kk, gc = bn + n;
            Bs[kk][n] = (gr < K && gc < N) ? B[(size_t)gr * N + gc] : 0.f;
        }
        __syncthreads();
#pragma unroll
        for (int kk = 0; kk < 16; kk++) {
            float a[4], b[4];
#pragma unroll
            for (int i2 = 0; i2 < 4; i2++) a[i2] = As[kk][ty * 4 + i2];
#pragma unroll
            for (int j2 = 0; j2 < 4; j2++) b[j2] = Bs[kk][tx * 4 + j2];
#pragma unroll
            for (int i2 = 0; i2 < 4; i2++)
#pragma unroll
                for (int j2 = 0; j2 < 4; j2++) acc[i2][j2] = fmaf(a[i2], b[j2], acc[i2][j2]);
        }
        __syncthreads();
    }
#pragma unroll
    for (int i2 = 0; i2 < 4; i2++) {
        int r = bm + ty * 4 + i2;
        if (r >= M) continue;
#pragma unroll
        for (int j2 = 0; j2 < 4; j2++) {
            int c = bn + tx * 4 + j2;
            if (c >= N) continue;
            float v = acc[i2][j2];
            if (bias) v += bias[c];
            if (doRelu) v = fmaxf(v, 0.f);
            C[(size_t)r * ldc + c] = v;
        }
    }
}

// ---------- GAT alphas ----------
__global__ __launch_bounds__(256) void alpha_kernel(const float* __restrict__ h, const float* __restrict__ asrc,
                                                    const float* __restrict__ adst, float* __restrict__ als,
                                                    float* __restrict__ ald) {
    int gw = (blockIdx.x * 256 + threadIdx.x) >> 6;
    int lane = threadIdx.x & 63;
    if (gw >= N_NODES) return;
    const float* row = h + (size_t)gw * FEAT;
    float v0 = row[lane], v1 = row[lane + 64];
    float ps = v0 * asrc[lane] + v1 * asrc[lane + 64];
    float pd = v0 * adst[lane] + v1 * adst[lane + 64];
    ps = warpReduceSum(ps);
    pd = warpReduceSum(pd);
    if (lane == 0) {
        als[gw] = ps;
        ald[gw] = pd;
    }
}

// ---------- edge passes ----------
__device__ __forceinline__ void edge_decode(int i, const int* __restrict__ ei, int& s, int& d) {
    if (i < N_EDGES) {
        s = ei[i];
        d = ei[N_EDGES + i];
    } else {
        s = d = i - N_EDGES;
    }
}

__global__ void edge_p1(const int* __restrict__ ei, const float* __restrict__ als, const float* __restrict__ ald,
                        float* __restrict__ elog, int* __restrict__ menc, float* dega) {
    int i = blockIdx.x * 256 + threadIdx.x;
    if (i >= ET_EDGES) return;
    int s, d;
    edge_decode(i, ei, s, d);
    float e = als[s] + ald[d];
    e = (e >= 0.f) ? e : 0.2f * e;
    elog[i] = e;
    atomicMax(&menc[d], encf(e));
    if (dega) unsafeAtomicAdd(&dega[d], 1.f);
}

__global__ void edge_p2(const int* __restrict__ ei, float* __restrict__ elog, const int* __restrict__ menc,
                        float* __restrict__ den) {
    int i = blockIdx.x * 256 + threadIdx.x;
    if (i >= ET_EDGES) return;
    int s, d;
    edge_decode(i, ei, s, d);
    float ex = expf(elog[i] - decf(menc[d]));
    elog[i] = ex;
    unsafeAtomicAdd(&den[d], ex);
}

__global__ void edge_p2b(const int* __restrict__ ei, float* __restrict__ elog, const float* __restrict__ den) {
    int i = blockIdx.x * 256 + threadIdx.x;
    if (i >= ET_EDGES) return;
    int s, d;
    edge_decode(i, ei, s, d);
    elog[i] = elog[i] / den[d];
}

__global__ void dinv_kernel(float* deg) {
    int i = blockIdx.x * 256 + threadIdx.x;
    if (i < N_NODES) deg[i] = rsqrtf(fmaxf(deg[i], 1.f));
}

__global__ void edge_scatter(const int* __restrict__ ei, const float* __restrict__ coef, const float* __restrict__ h,
                             float* __restrict__ out, int ldo) {
    int i = blockIdx.x * 256 + threadIdx.x;
    if (i >= ET_EDGES * FEAT) return;
    int e = i >> 7, f = i & 127;
    int s, d;
    edge_decode(e, ei, s, d);
    unsafeAtomicAdd(&out[(size_t)d * ldo + f], coef[e] * h[(size_t)s * FEAT + f]);
}

__global__ void gcn_scatter(const int* __restrict__ ei, const float* __restrict__ dinv, const float* __restrict__ h,
                            float* __restrict__ out, int ldo) {
    int i = blockIdx.x * 256 + threadIdx.x;
    if (i >= ET_EDGES * FEAT) return;
    int e = i >> 7, f = i & 127;
    int s, d;
    edge_decode(e, ei, s, d);
    float coef = dinv[s] * dinv[d];
    unsafeAtomicAdd(&out[(size_t)d * ldo + f], coef * h[(size_t)s * FEAT + f]);
}

__global__ void biasadd_cat(float* __restrict__ cat, const float* __restrict__ b1, const float* __restrict__ b2) {
    int i = blockIdx.x * 256 + threadIdx.x;
    int n = i >> 8, c = i & 255;
    float b = (c < 128) ? b1[c] : b2[c - 128];
    cat[(size_t)n * 512 + c] += b;
}

__global__ void root_gather(const float* __restrict__ g2, const int* __restrict__ rooti, const float* __restrict__ gb,
                            float* __restrict__ fin) {
    int i = blockIdx.x * 256 + threadIdx.x;
    if (i >= N_ROOTS * FEAT) return;
    int r = i >> 7, c = i & 127;
    fin[(size_t)r * 1128 + c] = g2[(size_t)rooti[r] * FEAT + c] + gb[c];
}

__global__ void fc2_kernel(const float* __restrict__ fch, const float* __restrict__ W, const float* __restrict__ b,
                           float* __restrict__ out) {
    int i = blockIdx.x * 256 + threadIdx.x;
    if (i >= N_ROOTS * 3) return;
    int r = i / 3, c = i - r * 3;
    float acc = b[c];
    for (int k = 0; k < 300; k++) acc = fmaf(fch[(size_t)r * 300 + k], W[k * 3 + c], acc);
    out[i] = acc;
}

// ================= MFMA transformer: 2 nodes/block, 256 threads =================
// MODE 0: all nodes -> t_avg into cat[:,256:512].  MODE 1: root/rootpost slots -> tbuf bf16 rows.
#define QA_STRIDE 264  // shorts; 132 dwords == 4 mod 32 -> 2-way on A-frag reads (free)
#define KV_STRIDE 520  // shorts; k cols 0-255, v cols 256-511; later y (cols 0-255)

template <int MODE>
__global__ __launch_bounds__(256) void xformer_kernel(
    const float* __restrict__ emb, const int* __restrict__ text2, const short* __restrict__ wqkvT,
    const float* __restrict__ bqkv, const short* __restrict__ woT, const float* __restrict__ bo,
    const float* __restrict__ lng, const float* __restrict__ lnb, const int* __restrict__ rooti,
    const int* __restrict__ rpi, float* __restrict__ cat, unsigned short* __restrict__ tbuf) {
    __shared__ short qa[32 * QA_STRIDE];
    __shared__ short kv[32 * KV_STRIDE];

    const int tid = threadIdx.x;
    const int wave = tid >> 6, lane = tid & 63;
    const int quad = lane >> 4, l16 = lane & 15;

    int gnode[2];
#pragma unroll
    for (int m = 0; m < 2; m++) {
        int slot = blockIdx.x * 2 + m;
        gnode[m] = (MODE == 0) ? slot : ((slot < N_ROOTS) ? rooti[slot] : rpi[slot - N_ROOTS]);
    }
    const int tokA0 = text2[gnode[0] * SEQ + l16];
    const int tokA1 = text2[gnode[1] * SEQ + l16];

    // ---- Phase 1: QKV. wave w owns n-tiles {q:w*4+i, k:16+w*4+i, v:32+w*4+i} ----
    f32x4 acc[12][2];
#pragma unroll
    for (int i = 0; i < 12; i++) {
        acc[i][0] = (f32x4){0.f, 0.f, 0.f, 0.f};
        acc[i][1] = (f32x4){0.f, 0.f, 0.f, 0.f};
    }
    for (int k0 = 0; k0 < 8; k0++) {
        const float* pa0 = emb + (size_t)tokA0 * 256 + k0 * 32 + quad * 8;
        const float* pa1 = emb + (size_t)tokA1 * 256 + k0 * 32 + quad * 8;
        float4 a0l = ((const float4*)pa0)[0], a0h = ((const float4*)pa0)[1];
        float4 a1l = ((const float4*)pa1)[0], a1h = ((const float4*)pa1)[1];
        short8 A0 = {f2bs(a0l.x), f2bs(a0l.y), f2bs(a0l.z), f2bs(a0l.w),
                     f2bs(a0h.x), f2bs(a0h.y), f2bs(a0h.z), f2bs(a0h.w)};
        short8 A1 = {f2bs(a1l.x), f2bs(a1l.y), f2bs(a1l.z), f2bs(a1l.w),
                     f2bs(a1h.x), f2bs(a1h.y), f2bs(a1h.z), f2bs(a1h.w)};
#pragma unroll
        for (int i = 0; i < 12; i++) {
            const int g = wave * 4 + i + (i < 4 ? 0 : (i < 8 ? 12 : 24));
            short8 B = *(const short8*)(wqkvT + (size_t)(g * 16 + l16) * 256 + k0 * 32 + quad * 8);
            acc[i][0] = __builtin_amdgcn_mfma_f32_16x16x32_bf16(A0, B, acc[i][0], 0, 0, 0);
            acc[i][1] = __builtin_amdgcn_mfma_f32_16x16x32_bf16(A1, B, acc[i][1], 0, 0, 0);
        }
    }
#pragma unroll
    for (int i = 0; i < 12; i++) {
        const int g = wave * 4 + i + (i < 4 ? 0 : (i < 8 ? 12 : 24));
        const int col = g * 16 + l16;
        const float b = bqkv[col];
#pragma unroll
        for (int m = 0; m < 2; m++) {
            const int rbase = m * 16 + quad * 4;
#pragma unroll
            for (int r = 0; r < 4; r++) {
                short s = f2bs(acc[i][m][r] + b);
                if (i < 4) qa[(rbase + r) * QA_STRIDE + col] = s;
                else kv[(rbase + r) * KV_STRIDE + (col - 256)] = s;
            }
        }
    }
    // q/k/v for heads wave*4..wave*4+3 are wave-local: no barrier needed before attention.

    // ---- Phase 2: attention (pass p = node p); thread = (head=wave*4+quad, qi=l16) ----
#pragma unroll
    for (int p = 0; p < 2; p++) {
        const int h = wave * 4 + quad, qi = l16;
        const int rq = p * 16 + qi;
        float qv[16];
        {
            short8 q0 = *(const short8*)(qa + rq * QA_STRIDE + h * 16);
            short8 q1 = *(const short8*)(qa + rq * QA_STRIDE + h * 16 + 8);
#pragma unroll
            for (int d = 0; d < 8; d++) {
                qv[d] = bs2f(q0[d]);
                qv[d + 8] = bs2f(q1[d]);
            }
        }
        float sc[16];
#pragma unroll
        for (int kj = 0; kj < 16; kj++) {
            short8 k0v = *(const short8*)(kv + (p * 16 + kj) * KV_STRIDE + h * 16);
            short8 k1v = *(const short8*)(kv + (p * 16 + kj) * KV_STRIDE + h * 16 + 8);
            float a = 0.f;
#pragma unroll
            for (int d = 0; d < 8; d++) {
                a = fmaf(qv[d], bs2f(k0v[d]), a);
                a = fmaf(qv[d + 8], bs2f(k1v[d]), a);
            }
            sc[kj] = a * 0.25f;
        }
        float mx = sc[0];
#pragma unroll
        for (int kj = 1; kj < 16; kj++) mx = fmaxf(mx, sc[kj]);
        float sum = 0.f;
#pragma unroll
        for (int kj = 0; kj < 16; kj++) {
            sc[kj] = expf(sc[kj] - mx);
            sum += sc[kj];
        }
        const float inv = 1.f / sum;
        float ov[16];
#pragma unroll
        for (int d = 0; d < 16; d++) ov[d] = 0.f;
#pragma unroll
        for (int kj = 0; kj < 16; kj++) {
            const float pw = sc[kj];
            short8 v0 = *(const short8*)(kv + (p * 16 + kj) * KV_STRIDE + 256 + h * 16);
            short8 v1 = *(const short8*)(kv + (p * 16 + kj) * KV_STRIDE + 256 + h * 16 + 8);
#pragma unroll
            for (int d = 0; d < 8; d++) {
                ov[d] = fmaf(pw, bs2f(v0[d]), ov[d]);
                ov[d + 8] = fmaf(pw, bs2f(v1[d]), ov[d + 8]);
            }
        }
        short8 o0, o1;
#pragma unroll
        for (int d = 0; d < 8; d++) {
            o0[d] = f2bs(ov[d] * inv);
            o1[d] = f2bs(ov[d + 8] * inv);
        }
        *(short8*)(qa + rq * QA_STRIDE + h * 16) = o0;       // own exclusive region
        *(short8*)(qa + rq * QA_STRIDE + h * 16 + 8) = o1;
    }
    __syncthreads();  // attn-out needed cross-wave for O-proj A-frags

    // ---- Phase 3: O-proj + residual -> y (bf16) into kv cols 0..255 ----
    {
        short8 Afr[2][8];
#pragma unroll
        for (int m = 0; m < 2; m++)
#pragma unroll
            for (int k0 = 0; k0 < 8; k0++)
                Afr[m][k0] = *(const short8*)(qa + (m * 16 + l16) * QA_STRIDE + k0 * 32 + quad * 8);
        int tokR[2][4];
#pragma unroll
        for (int m = 0; m < 2; m++)
#pragma unroll
            for (int r = 0; r < 4; r++) tokR[m][r] = text2[gnode[m] * SEQ + quad * 4 + r];
#pragma unroll
        for (int i = 0; i < 4; i++) {
            const int g = wave * 4 + i;
            f32x4 oa0 = (f32x4){0.f, 0.f, 0.f, 0.f}, oa1 = (f32x4){0.f, 0.f, 0.f, 0.f};
            for (int k0 = 0; k0 < 8; k0++) {
                short8 B = *(const short8*)(woT + (size_t)(g * 16 + l16) * 256 + k0 * 32 + quad * 8);
                oa0 = __builtin_amdgcn_mfma_f32_16x16x32_bf16(Afr[0][k0], B, oa0, 0, 0, 0);
                oa1 = __builtin_amdgcn_mfma_f32_16x16x32_bf16(Afr[1][k0], B, oa1, 0, 0, 0);
            }
            const int col = g * 16 + l16;
            const float bocol = bo[col];
#pragma unroll
            for (int r = 0; r < 4; r++) {
                float y0 = oa0[r] + bocol + emb[(size_t)tokR[0][r] * 256 + col];
                float y1 = oa1[r] + bocol + emb[(size_t)tokR[1][r] * 256 + col];
                kv[(quad * 4 + r) * KV_STRIDE + col] = f2bs(y0);
                kv[(16 + quad * 4 + r) * KV_STRIDE + col] = f2bs(y1);
            }
        }
    }
    __syncthreads();

    // ---- Phase 4: LayerNorm (wave handles 8 rows), then t_avg or tbuf write ----
    {
        float csum[4] = {0.f, 0.f, 0.f, 0.f};
#pragma unroll
        for (int rr = 0; rr < 8; rr++) {
            const int srow = wave * 8 + rr;
            float v[4];
            float sum = 0.f, sq = 0.f;
#pragma unroll
            for (int j = 0; j < 4; j++) {
                const int c = lane + j * 64;
                v[j] = bs2f(kv[srow * KV_STRIDE + c]);
                sum += v[j];
                sq = fmaf(v[j], v[j], sq);
            }
            sum = warpReduceSum(sum);
            sq = warpReduceSum(sq);
            const float mu = sum * (1.f / 256.f);
            const float var = sq * (1.f / 256.f) - mu * mu;
            const float rstd = rsqrtf(var + 1e-5f);
#pragma unroll
            for (int j = 0; j < 4; j++) {
                const int c = lane + j * 64;
                const float o = (v[j] - mu) * rstd * lng[c] + lnb[c];
                if (MODE == 0) {
                    csum[j] += o;
                } else {
                    const int m = srow >> 4;
                    tbuf[((size_t)(blockIdx.x * 2 + m) * 24 + (srow & 15)) * 256 + c] =
                        (unsigned short)f2bs(o);
                }
            }
        }
        if (MODE == 0) {
            float* cs = (float*)qa;  // qa dead
#pragma unroll
            for (int j = 0; j < 4; j++) cs[wave * 256 + lane + j * 64] = csum[j];
            __syncthreads();
            float a0 = (cs[0 * 256 + tid] + cs[1 * 256 + tid]) * (1.f / 16.f);
            float a1 = (cs[2 * 256 + tid] + cs[3 * 256 + tid]) * (1.f / 16.f);
            cat[(size_t)gnode[0] * 512 + 256 + tid] = a0;
            cat[(size_t)gnode[1] * 512 + 256 + tid] = a1;
        } else {
            // zero pad rows 16..23 of both slots
            for (int z = tid; z < 2 * 8 * 256; z += 256) {
                const int m = z >> 11, rem = z & 2047;
                tbuf[((size_t)(blockIdx.x * 2 + m) * 24 + 16 + (rem >> 8)) * 256 + (rem & 255)] = 0;
            }
        }
    }
}

// conv GEMM (unchanged, proven): C[24576,512] = im2col(tbuf) @ W_all^T
__global__ __launch_bounds__(256) void conv_gemm(const short* __restrict__ tb, const short* __restrict__ wall,
                                                 float* __restrict__ C) {
    __shared__ short As[128 * 40];
    __shared__ short Bs[128 * 40];
    const int bid = blockIdx.x;
    const int m0 = (bid >> 2) * 128;
    const int n0 = (bid & 3) * 128;
    const int tid = threadIdx.x;
    const int lane = tid & 63;
    const int wave = tid >> 6;
    const int wm = (wave >> 1) * 64, wn = (wave & 1) * 64;
    const int quad = lane >> 4, l16 = lane & 15;

    const int r0 = tid >> 2, kc = (tid & 3) * 8;
    const int r1 = r0 + 64;
    const int am0 = m0 + r0, am1 = m0 + r1;
    const int s0 = am0 / 12, p0_ = am0 - s0 * 12;
    const int s1 = am1 / 12, p1_ = am1 - s1 * 12;
    const size_t ga0 = (size_t)(s0 * 24 + p0_) * 256 + kc;
    const size_t ga1 = (size_t)(s1 * 24 + p1_) * 256 + kc;
    const size_t gb0 = (size_t)(n0 + r0) * 2048 + kc;
    const size_t gb1 = (size_t)(n0 + r1) * 2048 + kc;
    short* sa0 = As + r0 * 40 + kc;
    short* sa1 = As + r1 * 40 + kc;
    short* sb0 = Bs + r0 * 40 + kc;
    short* sb1 = Bs + r1 * 40 + kc;

    f32x4 acc[4][4];
#pragma unroll
    for (int i = 0; i < 4; i++)
#pragma unroll
        for (int j = 0; j < 4; j++) acc[i][j] = (f32x4){0.f, 0.f, 0.f, 0.f};

    for (int k0 = 0; k0 < 2048; k0 += 32) {
        short8 a0 = *(const short8*)(tb + ga0 + k0);
        short8 a1 = *(const short8*)(tb + ga1 + k0);
        short8 b0 = *(const short8*)(wall + gb0 + k0);
        short8 b1 = *(const short8*)(wall + gb1 + k0);
        *(short8*)sa0 = a0;
        *(short8*)sa1 = a1;
        *(short8*)sb0 = b0;
        *(short8*)sb1 = b1;
        __syncthreads();
        short8 af[4], bfr[4];
#pragma unroll
        for (int i = 0; i < 4; i++) af[i] = *(const short8*)(As + (wm + i * 16 + l16) * 40 + quad * 8);
#pragma unroll
        for (int j = 0; j < 4; j++) bfr[j] = *(const short8*)(Bs + (wn + j * 16 + l16) * 40 + quad * 8);
#pragma unroll
        for (int i = 0; i < 4; i++)
#pragma unroll
            for (int j = 0; j < 4; j++)
                acc[i][j] = __builtin_amdgcn_mfma_f32_16x16x32_bf16(af[i], bfr[j], acc[i][j], 0, 0, 0);
        __syncthreads();
    }
#pragma unroll
    for (int i = 0; i < 4; i++) {
#pragma unroll
        for (int j = 0; j < 4; j++) {
            const int col = n0 + wn + j * 16 + l16;
            const size_t base = (size_t)(m0 + wm + i * 16 + quad * 4) * 512 + col;
#pragma unroll
            for (int r = 0; r < 4; r++) C[base + (size_t)r * 512] = acc[i][j][r];
        }
    }
}

__global__ void conv_maxpool(const float* __restrict__ C, const float* __restrict__ cb0, const float* __restrict__ cb1,
                             const float* __restrict__ cb2, const float* __restrict__ cb3, float* __restrict__ fin) {
    int i = blockIdx.x * 256 + threadIdx.x;
    if (i >= 2048 * 500) return;
    int slot = i / 500, q = i - slot * 500;
    int Kidx = q / 125, oc = q - Kidx * 125;
    int L = 12 - Kidx;
    const float* base = C + (size_t)(slot * 12) * 512 + q;
    float m = base[0];
    for (int p = 1; p < L; p++) m = fmaxf(m, base[(size_t)p * 512]);
    float b = (Kidx == 0 ? cb0 : Kidx == 1 ? cb1 : Kidx == 2 ? cb2 : cb3)[oc];
    float v = fmaxf(m + b, 0.f);
    int idx = slot < N_ROOTS ? slot : slot - N_ROOTS;
    int colbase = slot < N_ROOTS ? 128 : 628;
    fin[(size_t)idx * 1128 + colbase + q] = v;
}

// ---------- host launch ----------
extern "C" void kernel_launch(void* const* d_in, const int* in_sizes, int n_in, void* d_out, int out_size, void* d_ws,
                              size_t ws_size, hipStream_t stream) {
    const float* x2 = (const float*)d_in[0];
    const float* emb = (const float*)d_in[1];
    const float* Wq = (const float*)d_in[2];
    const float* Wk = (const float*)d_in[3];
    const float* Wv = (const float*)d_in[4];
    const float* Wo = (const float*)d_in[5];
    const float* bq = (const float*)d_in[6];
    const float* bk = (const float*)d_in[7];
    const float* bv = (const float*)d_in[8];
    const float* bo = (const float*)d_in[9];
    const float* lng = (const float*)d_in[10];
    const float* lnb = (const float*)d_in[11];
    const float* gat1_W = (const float*)d_in[12];
    const float* gat1_as = (const float*)d_in[13];
    const float* gat1_ad = (const float*)d_in[14];
    const float* gat1_b = (const float*)d_in[15];
    const float* gcn1_W = (const float*)d_in[16];
    const float* gcn1_b = (const float*)d_in[17];
    const float* gat2_W = (const float*)d_in[18];
    const float* gat2_as = (const float*)d_in[19];
    const float* gat2_ad = (const float*)d_in[20];
    const float* gat2_b = (const float*)d_in[21];
    // d_in[22]/[23] gcn2: dead code in reference forward
    const float* cw0 = (const float*)d_in[24];
    const float* cb0 = (const float*)d_in[25];
    const float* cw1 = (const float*)d_in[26];
    const float* cb1 = (const float*)d_in[27];
    const float* cw2 = (const float*)d_in[28];
    const float* cb2 = (const float*)d_in[29];
    const float* cw3 = (const float*)d_in[30];
    const float* cb3 = (const float*)d_in[31];
    const float* fc1_W = (const float*)d_in[32];
    const float* fc1_b = (const float*)d_in[33];
    const float* fc2_W = (const float*)d_in[34];
    const float* fc2_b = (const float*)d_in[35];
    const int* text2 = (const int*)d_in[36];
    const int* ei = (const int*)d_in[37];
    const int* rooti = (const int*)d_in[38];
    const int* rpi = (const int*)d_in[39];

    float* ws = (float*)d_ws;
    size_t off = 0;
    auto alloc = [&](size_t n) {
        float* p = ws + off;
        off += n;
        return p;
    };
    float* cat = alloc((size_t)N_NODES * 512);  // reused as conv C buffer after gat2 gemm
    float* g2o = alloc((size_t)N_NODES * FEAT);
    float* den1 = alloc(N_NODES);
    float* den2 = alloc(N_NODES);
    float* deg = alloc(N_NODES);
    size_t zero_floats = off;
    float* h1 = alloc((size_t)N_NODES * FEAT);  // h1+h2 reused as tbuf after scatters
    float* h2 = alloc((size_t)N_NODES * FEAT);
    float* hg2 = alloc((size_t)N_NODES * FEAT);
    float* als1 = alloc(N_NODES);
    float* ald1 = alloc(N_NODES);
    float* als2 = alloc(N_NODES);
    float* ald2 = alloc(N_NODES);
    int* m1 = (int*)alloc(N_NODES);
    int* m2 = (int*)alloc(N_NODES);
    float* el1 = alloc(ET_EDGES);
    float* el2 = alloc(ET_EDGES);
    float* fin = alloc((size_t)N_ROOTS * 1128);
    float* fch = alloc((size_t)N_ROOTS * 300);
    float* wallf = alloc(512 * 2048 / 2);
    float* wqkvTf = alloc(768 * 256 / 2);
    float* woTf = alloc(256 * 256 / 2);
    float* bqkv = alloc(768);
    (void)ws_size;
    (void)in_sizes;
    (void)n_in;
    (void)out_size;

    unsigned short* tbuf = (unsigned short*)h1;  // 2048*24*256 bf16 fits in h1+h2
    __hip_bfloat16* wall = (__hip_bfloat16*)wallf;
    short* wqkvT = (short*)wqkvTf;
    short* woT = (short*)woTf;
    float* Cbuf = cat;

    hipMemsetAsync(d_ws, 0, zero_floats * sizeof(float), stream);
    fill_i32<<<cdiv(2 * N_NODES, 256), 256, 0, stream>>>(m1, (int)0x80000000, 2 * N_NODES);
    repack_wall<<<cdiv(512 * 2048, 256), 256, 0, stream>>>(cw0, cw1, cw2, cw3, wall);
    repack_xf<<<cdiv(768 * 256, 256), 256, 0, stream>>>(Wq, Wk, Wv, Wo, bq, bk, bv, wqkvT, woT, bqkv);

    // GAT1 / GCN1 node transforms
    gemm64<<<dim3(2, 512), 256, 0, stream>>>(x2, gat1_W, nullptr, h1, N_NODES, FEAT, FEAT, FEAT, FEAT, 0);
    gemm64<<<dim3(2, 512), 256, 0, stream>>>(x2, gcn1_W, nullptr, h2, N_NODES, FEAT, FEAT, FEAT, FEAT, 0);
    alpha_kernel<<<cdiv((long long)N_NODES * 64, 256), 256, 0, stream>>>(h1, gat1_as, gat1_ad, als1, ald1);
    edge_p1<<<cdiv(ET_EDGES, 256), 256, 0, stream>>>(ei, als1, ald1, el1, m1, deg);
    edge_p2<<<cdiv(ET_EDGES, 256), 256, 0, stream>>>(ei, el1, m1, den1);
    edge_p2b<<<cdiv(ET_EDGES, 256), 256, 0, stream>>>(ei, el1, den1);
    dinv_kernel<<<cdiv(N_NODES, 256), 256, 0, stream>>>(deg);
    const int sc_blocks = cdiv((long long)ET_EDGES * FEAT, 256);
    edge_scatter<<<sc_blocks, 256, 0, stream>>>(ei, el1, h1, cat + 0, 512);
    gcn_scatter<<<sc_blocks, 256, 0, stream>>>(ei, deg, h2, cat + 128, 512);
    // transformer (MFMA): all nodes -> t_avg into cat[:,256:512]
    xformer_kernel<0><<<N_NODES / 2, 256, 0, stream>>>(emb, text2, wqkvT, bqkv, woT, bo, lng, lnb, rooti, rpi, cat,
                                                       nullptr);
    // transformer (MFMA): conv slots -> tbuf (h1/h2 dead after scatters)
    xformer_kernel<1><<<2 * N_ROOTS / 2, 256, 0, stream>>>(emb, text2, wqkvT, bqkv, woT, bo, lng, lnb, rooti, rpi,
                                                           nullptr, tbuf);
    biasadd_cat<<<cdiv((long long)N_NODES * 256, 256), 256, 0, stream>>>(cat, gat1_b, gcn1_b);
    // GAT2
    gemm64<<<dim3(2, 512), 256, 0, stream>>>(cat, gat2_W, nullptr, hg2, N_NODES, FEAT, 512, 512, FEAT, 0);
    alpha_kernel<<<cdiv((long long)N_NODES * 64, 256), 256, 0, stream>>>(hg2, gat2_as, gat2_ad, als2, ald2);
    edge_p1<<<cdiv(ET_EDGES, 256), 256, 0, stream>>>(ei, als2, ald2, el2, m2, nullptr);
    edge_p2<<<cdiv(ET_EDGES, 256), 256, 0, stream>>>(ei, el2, m2, den2);
    edge_p2b<<<cdiv(ET_EDGES, 256), 256, 0, stream>>>(ei, el2, den2);
    edge_scatter<<<sc_blocks, 256, 0, stream>>>(ei, el2, hg2, g2o, FEAT);
    // conv branch
    conv_gemm<<<192 * 4, 256, 0, stream>>>((const short*)tbuf, (const short*)wall, Cbuf);
    root_gather<<<cdiv(N_ROOTS * FEAT, 256), 256, 0, stream>>>(g2o, rooti, gat2_b, fin);
    conv_maxpool<<<cdiv(2048 * 500, 256), 256, 0, stream>>>(Cbuf, cb0, cb1, cb2, cb3, fin);
    // head
    gemm64<<<dim3(cdiv(300, 64), cdiv(N_ROOTS, 64)), 256, 0, stream>>>(fin, fc1_W, fc1_b, fch, N_ROOTS, 300, 1128,
                                                                       1128, 300, 1);
    fc2_kernel<<<cdiv(N_ROOTS * 3, 256), 256, 0, stream>>>(fch, fc2_W, fc2_b, (float*)d_out);
}

// Round 4
// 2551.234 us; speedup vs baseline: 6.5561x; 1.1723x over previous
//
#include <hip/hip_runtime.h>
#include <hip/hip_bf16.h>
#include <cstdint>
#include <cstddef>

#define N_NODES 32768
#define N_EDGES 131072
#define ET_EDGES (N_EDGES + N_NODES)
#define N_ROOTS 1024
#define EMB_D 256
#define FEAT 128
#define SEQ 16
#define OUT_CH 125

static inline int cdiv(long long a, long long b) { return (int)((a + b - 1) / b); }

typedef short short8 __attribute__((ext_vector_type(8)));
typedef float f32x4 __attribute__((ext_vector_type(4)));

// ---------- small utils ----------
__device__ __forceinline__ float warpReduceSum(float v) {
#pragma unroll
    for (int m = 32; m; m >>= 1) v += __shfl_xor(v, m, 64);
    return v;
}
__device__ __forceinline__ int encf(float f) {
    int i = __float_as_int(f);
    return i >= 0 ? i : (i ^ 0x7fffffff);
}
__device__ __forceinline__ float decf(int i) {
    return __int_as_float(i >= 0 ? i : (i ^ 0x7fffffff));
}
// fp32 -> bf16 (RNE) as raw short
__device__ __forceinline__ short f2bs(float x) {
    unsigned u = __float_as_uint(x);
    u += 0x7fffu + ((u >> 16) & 1u);
    return (short)(u >> 16);
}
__device__ __forceinline__ float bs2f(short s) {
    return __uint_as_float(((unsigned)(unsigned short)s) << 16);
}

__global__ void fill_i32(int* p, int v, int n) {
    int i = blockIdx.x * 256 + threadIdx.x;
    if (i < n) p[i] = v;
}

// pack all 4 conv kernels into W_all[512][2048] bf16 (row=(Kidx*125+oc), col=k*256+ic)
__global__ void repack_wall(const float* __restrict__ cw0, const float* __restrict__ cw1,
                            const float* __restrict__ cw2, const float* __restrict__ cw3,
                            __hip_bfloat16* __restrict__ wall) {
    int i = blockIdx.x * 256 + threadIdx.x;
    if (i >= 512 * 2048) return;
    int r = i >> 11, c = i & 2047;
    int k = c >> 8, ic = c & 255;
    float v = 0.f;
    if (r < 500) {
        int Kidx = r / 125, oc = r - Kidx * 125;
        int K = 5 + Kidx;
        if (k < K) {
            const float* cw = Kidx == 0 ? cw0 : Kidx == 1 ? cw1 : Kidx == 2 ? cw2 : cw3;
            v = cw[((size_t)oc * 256 + ic) * K + k];
        }
    }
    wall[i] = __float2bfloat16(v);
}

// transformer weights: wqkvT[768][256] bf16 (row n = output col of q|k|v, col k), woT[256][256], bqkv[768]
__global__ void repack_xf(const float* __restrict__ Wq, const float* __restrict__ Wk, const float* __restrict__ Wv,
                          const float* __restrict__ Wo, const float* __restrict__ bq, const float* __restrict__ bk,
                          const float* __restrict__ bv, short* __restrict__ wqkvT, short* __restrict__ woT,
                          float* __restrict__ bqkv) {
    int i = blockIdx.x * 256 + threadIdx.x;
    if (i < 768 * 256) {
        int n = i >> 8, k = i & 255;
        const float* W = n < 256 ? Wq : n < 512 ? Wk : Wv;
        wqkvT[i] = f2bs(W[k * 256 + (n & 255)]);
    }
    if (i < 256 * 256) {
        int n = i >> 8, k = i & 255;
        woT[i] = f2bs(Wo[k * 256 + n]);
    }
    if (i < 768) bqkv[i] = i < 256 ? bq[i] : i < 512 ? bk[i - 256] : bv[i - 512];
}

// ---------- generic fp32 GEMM (graph convs + head) ----------
__global__ __launch_bounds__(256) void gemm64(const float* __restrict__ A, const float* __restrict__ B,
                                              const float* __restrict__ bias, float* __restrict__ C,
                                              int M, int N, int K, int lda, int ldc, int doRelu) {
    __shared__ float As[16][65];
    __shared__ float Bs[16][65];
    const int bm = blockIdx.y * 64, bn = blockIdx.x * 64;
    const int tid = threadIdx.x;
    const int tx = tid & 15, ty = tid >> 4;
    float acc[4][4] = {};
    for (int k0 = 0; k0 < K; k0 += 16) {
#pragma unroll
        for (int j = 0; j < 4; j++) {
            int i = tid + j * 256;
            int kk = i & 15, m = i >> 4;
            int gr = bm + m, gc = k0 + kk;
            As[kk][m] = (gr < M && gc < K) ? A[(size_t)gr * lda + gc] : 0.f;
        }
#pragma unroll
        for (int j = 0; j < 4; j++) {
            int i = tid + j * 256;
            int n = i & 63, kk = i >> 6;
            int gr = k0 + kk, gc = bn + n;
            Bs[kk][n] = (gr < K && gc < N) ? B[(size_t)gr * N + gc] : 0.f;
        }
        __syncthreads();
#pragma unroll
        for (int kk = 0; kk < 16; kk++) {
            float a[4], b[4];
#pragma unroll
            for (int i2 = 0; i2 < 4; i2++) a[i2] = As[kk][ty * 4 + i2];
#pragma unroll
            for (int j2 = 0; j2 < 4; j2++) b[j2] = Bs[kk][tx * 4 + j2];
#pragma unroll
            for (int i2 = 0; i2 < 4; i2++)
#pragma unroll
                for (int j2 = 0; j2 < 4; j2++) acc[i2][j2] = fmaf(a[i2], b[j2], acc[i2][j2]);
        }
        __syncthreads();
    }
#pragma unroll
    for (int i2 = 0; i2 < 4; i2++) {
        int r = bm + ty * 4 + i2;
        if (r >= M) continue;
#pragma unroll
        for (int j2 = 0; j2 < 4; j2++) {
            int c = bn + tx * 4 + j2;
            if (c >= N) continue;
            float v = acc[i2][j2];
            if (bias) v += bias[c];
            if (doRelu) v = fmaxf(v, 0.f);
            C[(size_t)r * ldc + c] = v;
        }
    }
}

// ---------- GAT alphas ----------
__global__ __launch_bounds__(256) void alpha_kernel(const float* __restrict__ h, const float* __restrict__ asrc,
                                                    const float* __restrict__ adst, float* __restrict__ als,
                                                    float* __restrict__ ald) {
    int gw = (blockIdx.x * 256 + threadIdx.x) >> 6;
    int lane = threadIdx.x & 63;
    if (gw >= N_NODES) return;
    const float* row = h + (size_t)gw * FEAT;
    float v0 = row[lane], v1 = row[lane + 64];
    float ps = v0 * asrc[lane] + v1 * asrc[lane + 64];
    float pd = v0 * adst[lane] + v1 * adst[lane + 64];
    ps = warpReduceSum(ps);
    pd = warpReduceSum(pd);
    if (lane == 0) {
        als[gw] = ps;
        ald[gw] = pd;
    }
}

// ---------- edge passes ----------
__device__ __forceinline__ void edge_decode(int i, const int* __restrict__ ei, int& s, int& d) {
    if (i < N_EDGES) {
        s = ei[i];
        d = ei[N_EDGES + i];
    } else {
        s = d = i - N_EDGES;
    }
}

__global__ void edge_p1(const int* __restrict__ ei, const float* __restrict__ als, const float* __restrict__ ald,
                        float* __restrict__ elog, int* __restrict__ menc, float* dega) {
    int i = blockIdx.x * 256 + threadIdx.x;
    if (i >= ET_EDGES) return;
    int s, d;
    edge_decode(i, ei, s, d);
    float e = als[s] + ald[d];
    e = (e >= 0.f) ? e : 0.2f * e;
    elog[i] = e;
    atomicMax(&menc[d], encf(e));
    if (dega) unsafeAtomicAdd(&dega[d], 1.f);
}

__global__ void edge_p2(const int* __restrict__ ei, float* __restrict__ elog, const int* __restrict__ menc,
                        float* __restrict__ den) {
    int i = blockIdx.x * 256 + threadIdx.x;
    if (i >= ET_EDGES) return;
    int s, d;
    edge_decode(i, ei, s, d);
    float ex = __expf(elog[i] - decf(menc[d]));
    elog[i] = ex;
    unsafeAtomicAdd(&den[d], ex);
}

__global__ void edge_p2b(const int* __restrict__ ei, float* __restrict__ elog, const float* __restrict__ den) {
    int i = blockIdx.x * 256 + threadIdx.x;
    if (i >= ET_EDGES) return;
    int s, d;
    edge_decode(i, ei, s, d);
    elog[i] = elog[i] / den[d];
}

__global__ void dinv_kernel(float* deg) {
    int i = blockIdx.x * 256 + threadIdx.x;
    if (i < N_NODES) deg[i] = rsqrtf(fmaxf(deg[i], 1.f));
}

__global__ void edge_scatter(const int* __restrict__ ei, const float* __restrict__ coef, const float* __restrict__ h,
                             float* __restrict__ out, int ldo) {
    int i = blockIdx.x * 256 + threadIdx.x;
    if (i >= ET_EDGES * FEAT) return;
    int e = i >> 7, f = i & 127;
    int s, d;
    edge_decode(e, ei, s, d);
    unsafeAtomicAdd(&out[(size_t)d * ldo + f], coef[e] * h[(size_t)s * FEAT + f]);
}

__global__ void gcn_scatter(const int* __restrict__ ei, const float* __restrict__ dinv, const float* __restrict__ h,
                            float* __restrict__ out, int ldo) {
    int i = blockIdx.x * 256 + threadIdx.x;
    if (i >= ET_EDGES * FEAT) return;
    int e = i >> 7, f = i & 127;
    int s, d;
    edge_decode(e, ei, s, d);
    float coef = dinv[s] * dinv[d];
    unsafeAtomicAdd(&out[(size_t)d * ldo + f], coef * h[(size_t)s * FEAT + f]);
}

__global__ void biasadd_cat(float* __restrict__ cat, const float* __restrict__ b1, const float* __restrict__ b2) {
    int i = blockIdx.x * 256 + threadIdx.x;
    int n = i >> 8, c = i & 255;
    float b = (c < 128) ? b1[c] : b2[c - 128];
    cat[(size_t)n * 512 + c] += b;
}

__global__ void root_gather(const float* __restrict__ g2, const int* __restrict__ rooti, const float* __restrict__ gb,
                            float* __restrict__ fin) {
    int i = blockIdx.x * 256 + threadIdx.x;
    if (i >= N_ROOTS * FEAT) return;
    int r = i >> 7, c = i & 127;
    fin[(size_t)r * 1128 + c] = g2[(size_t)rooti[r] * FEAT + c] + gb[c];
}

__global__ void fc2_kernel(const float* __restrict__ fch, const float* __restrict__ W, const float* __restrict__ b,
                           float* __restrict__ out) {
    int i = blockIdx.x * 256 + threadIdx.x;
    if (i >= N_ROOTS * 3) return;
    int r = i / 3, c = i - r * 3;
    float acc = b[c];
    for (int k = 0; k < 300; k++) acc = fmaf(fch[(size_t)r * 300 + k], W[k * 3 + c], acc);
    out[i] = acc;
}

// ================= MFMA transformer: 2 nodes/block, 256 threads =================
// MODE 0: all nodes -> t_avg into cat[:,256:512].  MODE 1: root/rootpost slots -> tbuf bf16 rows.
#define QA_STRIDE 264  // shorts; 2-way bank aliasing on A-frag reads (free)
#define KV_STRIDE 520  // shorts; k cols 0-255, v cols 256-511; later y (cols 0-255)

template <int MODE>
__global__ __launch_bounds__(256, 3) void xformer_kernel(
    const float* __restrict__ emb, const int* __restrict__ text2, const short* __restrict__ wqkvT,
    const float* __restrict__ bqkv, const short* __restrict__ woT, const float* __restrict__ bo,
    const float* __restrict__ lng, const float* __restrict__ lnb, const int* __restrict__ rooti,
    const int* __restrict__ rpi, float* __restrict__ cat, unsigned short* __restrict__ tbuf) {
    __shared__ short qa[32 * QA_STRIDE];
    __shared__ short kv[32 * KV_STRIDE];

    const int tid = threadIdx.x;
    const int wave = tid >> 6, lane = tid & 63;
    const int quad = lane >> 4, l16 = lane & 15;

    int gnode[2];
#pragma unroll
    for (int m = 0; m < 2; m++) {
        int slot = blockIdx.x * 2 + m;
        gnode[m] = (MODE == 0) ? slot : ((slot < N_ROOTS) ? rooti[slot] : rpi[slot - N_ROOTS]);
    }
    const int tokA0 = text2[gnode[0] * SEQ + l16];
    const int tokA1 = text2[gnode[1] * SEQ + l16];

    // ---- Preload A fragments (both nodes, all 8 k-chunks) into registers ----
    short8 Areg[2][8];
#pragma unroll
    for (int k0 = 0; k0 < 8; k0++) {
        const float* pa0 = emb + (size_t)tokA0 * 256 + k0 * 32 + quad * 8;
        const float* pa1 = emb + (size_t)tokA1 * 256 + k0 * 32 + quad * 8;
        float4 a0l = ((const float4*)pa0)[0], a0h = ((const float4*)pa0)[1];
        float4 a1l = ((const float4*)pa1)[0], a1h = ((const float4*)pa1)[1];
        Areg[0][k0] = (short8){f2bs(a0l.x), f2bs(a0l.y), f2bs(a0l.z), f2bs(a0l.w),
                               f2bs(a0h.x), f2bs(a0h.y), f2bs(a0h.z), f2bs(a0h.w)};
        Areg[1][k0] = (short8){f2bs(a1l.x), f2bs(a1l.y), f2bs(a1l.z), f2bs(a1l.w),
                               f2bs(a1h.x), f2bs(a1h.y), f2bs(a1h.z), f2bs(a1h.w)};
    }

    // ---- Phase 1: QKV in 3 passes (q, k, v), 4 n-tiles each; acc stays at 32 VGPRs ----
#pragma unroll
    for (int grp = 0; grp < 3; grp++) {
        f32x4 acc[4][2];
#pragma unroll
        for (int i = 0; i < 4; i++) {
            acc[i][0] = (f32x4){0.f, 0.f, 0.f, 0.f};
            acc[i][1] = (f32x4){0.f, 0.f, 0.f, 0.f};
        }
#pragma unroll
        for (int k0 = 0; k0 < 8; k0++) {
#pragma unroll
            for (int i = 0; i < 4; i++) {
                const int g = grp * 16 + wave * 4 + i;
                short8 B = *(const short8*)(wqkvT + (size_t)(g * 16 + l16) * 256 + k0 * 32 + quad * 8);
                acc[i][0] = __builtin_amdgcn_mfma_f32_16x16x32_bf16(Areg[0][k0], B, acc[i][0], 0, 0, 0);
                acc[i][1] = __builtin_amdgcn_mfma_f32_16x16x32_bf16(Areg[1][k0], B, acc[i][1], 0, 0, 0);
            }
        }
#pragma unroll
        for (int i = 0; i < 4; i++) {
            const int g = grp * 16 + wave * 4 + i;
            const int col = g * 16 + l16;  // global qkv column 0..767
            const float b = bqkv[col];
#pragma unroll
            for (int m = 0; m < 2; m++) {
                const int rbase = m * 16 + quad * 4;
#pragma unroll
                for (int r = 0; r < 4; r++) {
                    short s = f2bs(acc[i][m][r] + b);
                    if (grp == 0) qa[(rbase + r) * QA_STRIDE + col] = s;
                    else kv[(rbase + r) * KV_STRIDE + (col - 256)] = s;
                }
            }
        }
    }
    // q/k/v for heads wave*4..wave*4+3 are wave-local: no barrier before attention.

    // ---- Phase 2: attention; thread = (head=wave*4+quad, qi=l16), pass p = node ----
#pragma unroll
    for (int p = 0; p < 2; p++) {
        const int h = wave * 4 + quad, qi = l16;
        const int rq = p * 16 + qi;
        float qv[16];
        {
            short8 q0 = *(const short8*)(qa + rq * QA_STRIDE + h * 16);
            short8 q1 = *(const short8*)(qa + rq * QA_STRIDE + h * 16 + 8);
#pragma unroll
            for (int d = 0; d < 8; d++) {
                qv[d] = bs2f(q0[d]);
                qv[d + 8] = bs2f(q1[d]);
            }
        }
        float sc[16];
#pragma unroll
        for (int kj = 0; kj < 16; kj++) {
            short8 k0v = *(const short8*)(kv + (p * 16 + kj) * KV_STRIDE + h * 16);
            short8 k1v = *(const short8*)(kv + (p * 16 + kj) * KV_STRIDE + h * 16 + 8);
            float a = 0.f;
#pragma unroll
            for (int d = 0; d < 8; d++) {
                a = fmaf(qv[d], bs2f(k0v[d]), a);
                a = fmaf(qv[d + 8], bs2f(k1v[d]), a);
            }
            sc[kj] = a * 0.25f;
        }
        float mx = sc[0];
#pragma unroll
        for (int kj = 1; kj < 16; kj++) mx = fmaxf(mx, sc[kj]);
        float sum = 0.f;
#pragma unroll
        for (int kj = 0; kj < 16; kj++) {
            sc[kj] = __expf(sc[kj] - mx);
            sum += sc[kj];
        }
        const float inv = 1.f / sum;
        float ov[16];
#pragma unroll
        for (int d = 0; d < 16; d++) ov[d] = 0.f;
#pragma unroll
        for (int kj = 0; kj < 16; kj++) {
            const float pw = sc[kj];
            short8 v0 = *(const short8*)(kv + (p * 16 + kj) * KV_STRIDE + 256 + h * 16);
            short8 v1 = *(const short8*)(kv + (p * 16 + kj) * KV_STRIDE + 256 + h * 16 + 8);
#pragma unroll
            for (int d = 0; d < 8; d++) {
                ov[d] = fmaf(pw, bs2f(v0[d]), ov[d]);
                ov[d + 8] = fmaf(pw, bs2f(v1[d]), ov[d + 8]);
            }
        }
        short8 o0, o1;
#pragma unroll
        for (int d = 0; d < 8; d++) {
            o0[d] = f2bs(ov[d] * inv);
            o1[d] = f2bs(ov[d + 8] * inv);
        }
        *(short8*)(qa + rq * QA_STRIDE + h * 16) = o0;  // own exclusive region
        *(short8*)(qa + rq * QA_STRIDE + h * 16 + 8) = o1;
    }
    __syncthreads();  // attn-out crosses waves for O-proj A-frags

    // ---- Phase 3: O-proj (+bo, no residual) -> kv cols 0..255 ----
    {
        short8 Afr[2][8];
#pragma unroll
        for (int m = 0; m < 2; m++)
#pragma unroll
            for (int k0 = 0; k0 < 8; k0++)
                Afr[m][k0] = *(const short8*)(qa + (m * 16 + l16) * QA_STRIDE + k0 * 32 + quad * 8);
#pragma unroll
        for (int i = 0; i < 4; i++) {
            const int g = wave * 4 + i;
            f32x4 oa0 = (f32x4){0.f, 0.f, 0.f, 0.f}, oa1 = (f32x4){0.f, 0.f, 0.f, 0.f};
#pragma unroll
            for (int k0 = 0; k0 < 8; k0++) {
                short8 B = *(const short8*)(woT + (size_t)(g * 16 + l16) * 256 + k0 * 32 + quad * 8);
                oa0 = __builtin_amdgcn_mfma_f32_16x16x32_bf16(Afr[0][k0], B, oa0, 0, 0, 0);
                oa1 = __builtin_amdgcn_mfma_f32_16x16x32_bf16(Afr[1][k0], B, oa1, 0, 0, 0);
            }
            const int col = g * 16 + l16;
            const float bocol = bo[col];
#pragma unroll
            for (int r = 0; r < 4; r++) {
                kv[(quad * 4 + r) * KV_STRIDE + col] = f2bs(oa0[r] + bocol);
                kv[(16 + quad * 4 + r) * KV_STRIDE + col] = f2bs(oa1[r] + bocol);
            }
        }
    }
    __syncthreads();

    // ---- Phase 4: LayerNorm via segment partials (residual added here from fp32 emb) ----
    float* qs = (float*)qa;  // qa dead
    {
        const int row = tid >> 3, seg = tid & 7;
        const int m = row >> 4, r = row & 15;
        const int tokr = text2[gnode[m] * SEQ + r];
        const float* ep = emb + (size_t)tokr * 256 + seg * 32;
        float sum = 0.f, sq = 0.f;
#pragma unroll
        for (int j = 0; j < 4; j++) {
            short8 y8 = *(const short8*)(kv + row * KV_STRIDE + seg * 32 + j * 8);
            float4 e0 = ((const float4*)(ep + j * 8))[0];
            float4 e1 = ((const float4*)(ep + j * 8))[1];
            float ev[8] = {e0.x, e0.y, e0.z, e0.w, e1.x, e1.y, e1.z, e1.w};
#pragma unroll
            for (int e = 0; e < 8; e++) {
                float yv = bs2f(y8[e]) + ev[e];
                sum += yv;
                sq = fmaf(yv, yv, sq);
            }
        }
        qs[tid] = sum;
        qs[256 + tid] = sq;
    }
    __syncthreads();
    if (tid < 32) {
        float s = 0.f, q2 = 0.f;
#pragma unroll
        for (int j = 0; j < 8; j++) {
            s += qs[tid * 8 + j];
            q2 += qs[256 + tid * 8 + j];
        }
        float mu = s * (1.f / 256.f);
        float var = q2 * (1.f / 256.f) - mu * mu;
        qs[512 + tid * 2] = mu;
        qs[512 + tid * 2 + 1] = rsqrtf(var + 1e-5f);
    }
    __syncthreads();
    {
        const int c = tid;
        const float g = lng[c], bb = lnb[c];
        float csum[2] = {0.f, 0.f};
#pragma unroll
        for (int m = 0; m < 2; m++) {
#pragma unroll
            for (int r = 0; r < 16; r++) {
                const int row = m * 16 + r;
                const int tok = text2[gnode[m] * SEQ + r];  // wave-uniform
                const float yv = bs2f(kv[row * KV_STRIDE + c]) + emb[(size_t)tok * 256 + c];
                const float mu = qs[512 + row * 2], rstd = qs[512 + row * 2 + 1];
                const float o = (yv - mu) * rstd * g + bb;
                if (MODE == 0) {
                    csum[m] += o;
                } else {
                    tbuf[((size_t)(blockIdx.x * 2 + m) * 24 + r) * 256 + c] = (unsigned short)f2bs(o);
                }
            }
        }
        if (MODE == 0) {
            cat[(size_t)gnode[0] * 512 + 256 + c] = csum[0] * (1.f / 16.f);
            cat[(size_t)gnode[1] * 512 + 256 + c] = csum[1] * (1.f / 16.f);
        } else {
            for (int z = tid; z < 2 * 8 * 256; z += 256) {
                const int m = z >> 11, rem = z & 2047;
                tbuf[((size_t)(blockIdx.x * 2 + m) * 24 + 16 + (rem >> 8)) * 256 + (rem & 255)] = 0;
            }
        }
    }
}

// conv GEMM (proven): C[24576,512] = im2col(tbuf) @ W_all^T
__global__ __launch_bounds__(256) void conv_gemm(const short* __restrict__ tb, const short* __restrict__ wall,
                                                 float* __restrict__ C) {
    __shared__ short As[128 * 40];
    __shared__ short Bs[128 * 40];
    const int bid = blockIdx.x;
    const int m0 = (bid >> 2) * 128;
    const int n0 = (bid & 3) * 128;
    const int tid = threadIdx.x;
    const int lane = tid & 63;
    const int wave = tid >> 6;
    const int wm = (wave >> 1) * 64, wn = (wave & 1) * 64;
    const int quad = lane >> 4, l16 = lane & 15;

    const int r0 = tid >> 2, kc = (tid & 3) * 8;
    const int r1 = r0 + 64;
    const int am0 = m0 + r0, am1 = m0 + r1;
    const int s0 = am0 / 12, p0_ = am0 - s0 * 12;
    const int s1 = am1 / 12, p1_ = am1 - s1 * 12;
    const size_t ga0 = (size_t)(s0 * 24 + p0_) * 256 + kc;
    const size_t ga1 = (size_t)(s1 * 24 + p1_) * 256 + kc;
    const size_t gb0 = (size_t)(n0 + r0) * 2048 + kc;
    const size_t gb1 = (size_t)(n0 + r1) * 2048 + kc;
    short* sa0 = As + r0 * 40 + kc;
    short* sa1 = As + r1 * 40 + kc;
    short* sb0 = Bs + r0 * 40 + kc;
    short* sb1 = Bs + r1 * 40 + kc;

    f32x4 acc[4][4];
#pragma unroll
    for (int i = 0; i < 4; i++)
#pragma unroll
        for (int j = 0; j < 4; j++) acc[i][j] = (f32x4){0.f, 0.f, 0.f, 0.f};

    for (int k0 = 0; k0 < 2048; k0 += 32) {
        short8 a0 = *(const short8*)(tb + ga0 + k0);
        short8 a1 = *(const short8*)(tb + ga1 + k0);
        short8 b0 = *(const short8*)(wall + gb0 + k0);
        short8 b1 = *(const short8*)(wall + gb1 + k0);
        *(short8*)sa0 = a0;
        *(short8*)sa1 = a1;
        *(short8*)sb0 = b0;
        *(short8*)sb1 = b1;
        __syncthreads();
        short8 af[4], bfr[4];
#pragma unroll
        for (int i = 0; i < 4; i++) af[i] = *(const short8*)(As + (wm + i * 16 + l16) * 40 + quad * 8);
#pragma unroll
        for (int j = 0; j < 4; j++) bfr[j] = *(const short8*)(Bs + (wn + j * 16 + l16) * 40 + quad * 8);
#pragma unroll
        for (int i = 0; i < 4; i++)
#pragma unroll
            for (int j = 0; j < 4; j++)
                acc[i][j] = __builtin_amdgcn_mfma_f32_16x16x32_bf16(af[i], bfr[j], acc[i][j], 0, 0, 0);
        __syncthreads();
    }
#pragma unroll
    for (int i = 0; i < 4; i++) {
#pragma unroll
        for (int j = 0; j < 4; j++) {
            const int col = n0 + wn + j * 16 + l16;
            const size_t base = (size_t)(m0 + wm + i * 16 + quad * 4) * 512 + col;
#pragma unroll
            for (int r = 0; r < 4; r++) C[base + (size_t)r * 512] = acc[i][j][r];
        }
    }
}

__global__ void conv_maxpool(const float* __restrict__ C, const float* __restrict__ cb0, const float* __restrict__ cb1,
                             const float* __restrict__ cb2, const float* __restrict__ cb3, float* __restrict__ fin) {
    int i = blockIdx.x * 256 + threadIdx.x;
    if (i >= 2048 * 500) return;
    int slot = i / 500, q = i - slot * 500;
    int Kidx = q / 125, oc = q - Kidx * 125;
    int L = 12 - Kidx;
    const float* base = C + (size_t)(slot * 12) * 512 + q;
    float m = base[0];
    for (int p = 1; p < L; p++) m = fmaxf(m, base[(size_t)p * 512]);
    float b = (Kidx == 0 ? cb0 : Kidx == 1 ? cb1 : Kidx == 2 ? cb2 : cb3)[oc];
    float v = fmaxf(m + b, 0.f);
    int idx = slot < N_ROOTS ? slot : slot - N_ROOTS;
    int colbase = slot < N_ROOTS ? 128 : 628;
    fin[(size_t)idx * 1128 + colbase + q] = v;
}

// ---------- host launch ----------
extern "C" void kernel_launch(void* const* d_in, const int* in_sizes, int n_in, void* d_out, int out_size, void* d_ws,
                              size_t ws_size, hipStream_t stream) {
    const float* x2 = (const float*)d_in[0];
    const float* emb = (const float*)d_in[1];
    const float* Wq = (const float*)d_in[2];
    const float* Wk = (const float*)d_in[3];
    const float* Wv = (const float*)d_in[4];
    const float* Wo = (const float*)d_in[5];
    const float* bq = (const float*)d_in[6];
    const float* bk = (const float*)d_in[7];
    const float* bv = (const float*)d_in[8];
    const float* bo = (const float*)d_in[9];
    const float* lng = (const float*)d_in[10];
    const float* lnb = (const float*)d_in[11];
    const float* gat1_W = (const float*)d_in[12];
    const float* gat1_as = (const float*)d_in[13];
    const float* gat1_ad = (const float*)d_in[14];
    const float* gat1_b = (const float*)d_in[15];
    const float* gcn1_W = (const float*)d_in[16];
    const float* gcn1_b = (const float*)d_in[17];
    const float* gat2_W = (const float*)d_in[18];
    const float* gat2_as = (const float*)d_in[19];
    const float* gat2_ad = (const float*)d_in[20];
    const float* gat2_b = (const float*)d_in[21];
    // d_in[22]/[23] gcn2: dead code in reference forward
    const float* cw0 = (const float*)d_in[24];
    const float* cb0 = (const float*)d_in[25];
    const float* cw1 = (const float*)d_in[26];
    const float* cb1 = (const float*)d_in[27];
    const float* cw2 = (const float*)d_in[28];
    const float* cb2 = (const float*)d_in[29];
    const float* cw3 = (const float*)d_in[30];
    const float* cb3 = (const float*)d_in[31];
    const float* fc1_W = (const float*)d_in[32];
    const float* fc1_b = (const float*)d_in[33];
    const float* fc2_W = (const float*)d_in[34];
    const float* fc2_b = (const float*)d_in[35];
    const int* text2 = (const int*)d_in[36];
    const int* ei = (const int*)d_in[37];
    const int* rooti = (const int*)d_in[38];
    const int* rpi = (const int*)d_in[39];

    float* ws = (float*)d_ws;
    size_t off = 0;
    auto alloc = [&](size_t n) {
        float* p = ws + off;
        off += n;
        return p;
    };
    float* cat = alloc((size_t)N_NODES * 512);  // reused as conv C buffer after gat2 gemm
    float* g2o = alloc((size_t)N_NODES * FEAT);
    float* den1 = alloc(N_NODES);
    float* den2 = alloc(N_NODES);
    float* deg = alloc(N_NODES);
    size_t zero_floats = off;
    float* h1 = alloc((size_t)N_NODES * FEAT);  // h1+h2 reused as tbuf after scatters
    float* h2 = alloc((size_t)N_NODES * FEAT);
    float* hg2 = alloc((size_t)N_NODES * FEAT);
    float* als1 = alloc(N_NODES);
    float* ald1 = alloc(N_NODES);
    float* als2 = alloc(N_NODES);
    float* ald2 = alloc(N_NODES);
    int* m1 = (int*)alloc(N_NODES);
    int* m2 = (int*)alloc(N_NODES);
    float* el1 = alloc(ET_EDGES);
    float* el2 = alloc(ET_EDGES);
    float* fin = alloc((size_t)N_ROOTS * 1128);
    float* fch = alloc((size_t)N_ROOTS * 300);
    float* wallf = alloc(512 * 2048 / 2);
    float* wqkvTf = alloc(768 * 256 / 2);
    float* woTf = alloc(256 * 256 / 2);
    float* bqkv = alloc(768);
    (void)ws_size;
    (void)in_sizes;
    (void)n_in;
    (void)out_size;

    unsigned short* tbuf = (unsigned short*)h1;  // 2048*24*256 bf16 fits in h1+h2
    __hip_bfloat16* wall = (__hip_bfloat16*)wallf;
    short* wqkvT = (short*)wqkvTf;
    short* woT = (short*)woTf;
    float* Cbuf = cat;

    hipMemsetAsync(d_ws, 0, zero_floats * sizeof(float), stream);
    fill_i32<<<cdiv(2 * N_NODES, 256), 256, 0, stream>>>(m1, (int)0x80000000, 2 * N_NODES);
    repack_wall<<<cdiv(512 * 2048, 256), 256, 0, stream>>>(cw0, cw1, cw2, cw3, wall);
    repack_xf<<<cdiv(768 * 256, 256), 256, 0, stream>>>(Wq, Wk, Wv, Wo, bq, bk, bv, wqkvT, woT, bqkv);

    // GAT1 / GCN1 node transforms
    gemm64<<<dim3(2, 512), 256, 0, stream>>>(x2, gat1_W, nullptr, h1, N_NODES, FEAT, FEAT, FEAT, FEAT, 0);
    gemm64<<<dim3(2, 512), 256, 0, stream>>>(x2, gcn1_W, nullptr, h2, N_NODES, FEAT, FEAT, FEAT, FEAT, 0);
    alpha_kernel<<<cdiv((long long)N_NODES * 64, 256), 256, 0, stream>>>(h1, gat1_as, gat1_ad, als1, ald1);
    edge_p1<<<cdiv(ET_EDGES, 256), 256, 0, stream>>>(ei, als1, ald1, el1, m1, deg);
    edge_p2<<<cdiv(ET_EDGES, 256), 256, 0, stream>>>(ei, el1, m1, den1);
    edge_p2b<<<cdiv(ET_EDGES, 256), 256, 0, stream>>>(ei, el1, den1);
    dinv_kernel<<<cdiv(N_NODES, 256), 256, 0, stream>>>(deg);
    const int sc_blocks = cdiv((long long)ET_EDGES * FEAT, 256);
    edge_scatter<<<sc_blocks, 256, 0, stream>>>(ei, el1, h1, cat + 0, 512);
    gcn_scatter<<<sc_blocks, 256, 0, stream>>>(ei, deg, h2, cat + 128, 512);
    // transformer (MFMA): all nodes -> t_avg into cat[:,256:512]
    xformer_kernel<0><<<N_NODES / 2, 256, 0, stream>>>(emb, text2, wqkvT, bqkv, woT, bo, lng, lnb, rooti, rpi, cat,
                                                       nullptr);
    // transformer (MFMA): conv slots -> tbuf (h1/h2 dead after scatters)
    xformer_kernel<1><<<2 * N_ROOTS / 2, 256, 0, stream>>>(emb, text2, wqkvT, bqkv, woT, bo, lng, lnb, rooti, rpi,
                                                           nullptr, tbuf);
    biasadd_cat<<<cdiv((long long)N_NODES * 256, 256), 256, 0, stream>>>(cat, gat1_b, gcn1_b);
    // GAT2
    gemm64<<<dim3(2, 512), 256, 0, stream>>>(cat, gat2_W, nullptr, hg2, N_NODES, FEAT, 512, 512, FEAT, 0);
    alpha_kernel<<<cdiv((long long)N_NODES * 64, 256), 256, 0, stream>>>(hg2, gat2_as, gat2_ad, als2, ald2);
    edge_p1<<<cdiv(ET_EDGES, 256), 256, 0, stream>>>(ei, als2, ald2, el2, m2, nullptr);
    edge_p2<<<cdiv(ET_EDGES, 256), 256, 0, stream>>>(ei, el2, m2, den2);
    edge_p2b<<<cdiv(ET_EDGES, 256), 256, 0, stream>>>(ei, el2, den2);
    edge_scatter<<<sc_blocks, 256, 0, stream>>>(ei, el2, hg2, g2o, FEAT);
    // conv branch
    conv_gemm<<<192 * 4, 256, 0, stream>>>((const short*)tbuf, (const short*)wall, Cbuf);
    root_gather<<<cdiv(N_ROOTS * FEAT, 256), 256, 0, stream>>>(g2o, rooti, gat2_b, fin);
    conv_maxpool<<<cdiv(2048 * 500, 256), 256, 0, stream>>>(Cbuf, cb0, cb1, cb2, cb3, fin);
    // head
    gemm64<<<dim3(cdiv(300, 64), cdiv(N_ROOTS, 64)), 256, 0, stream>>>(fin, fc1_W, fc1_b, fch, N_ROOTS, 300, 1128,
                                                                       1128, 300, 1);
    fc2_kernel<<<cdiv(N_ROOTS * 3, 256), 256, 0, stream>>>(fch, fc2_W, fc2_b, (float*)d_out);
}

// Round 5
// 2512.858 us; speedup vs baseline: 6.6562x; 1.0153x over previous
//
#include <hip/hip_runtime.h>
#include <hip/hip_bf16.h>
#include <cstdint>
#include <cstddef>

#define N_NODES 32768
#define N_EDGES 131072
#define ET_EDGES (N_EDGES + N_NODES)
#define N_ROOTS 1024
#define EMB_D 256
#define FEAT 128
#define SEQ 16
#define OUT_CH 125

static inline int cdiv(long long a, long long b) { return (int)((a + b - 1) / b); }

typedef short short8 __attribute__((ext_vector_type(8)));
typedef short short4v __attribute__((ext_vector_type(4)));
typedef float f32x4 __attribute__((ext_vector_type(4)));

// ---------- small utils ----------
__device__ __forceinline__ float warpReduceSum(float v) {
#pragma unroll
    for (int m = 32; m; m >>= 1) v += __shfl_xor(v, m, 64);
    return v;
}
__device__ __forceinline__ int encf(float f) {
    int i = __float_as_int(f);
    return i >= 0 ? i : (i ^ 0x7fffffff);
}
__device__ __forceinline__ float decf(int i) {
    return __int_as_float(i >= 0 ? i : (i ^ 0x7fffffff));
}
// fp32 -> bf16 (RNE) scalar
__device__ __forceinline__ short f2bs(float x) {
    unsigned u = __float_as_uint(x);
    u += 0x7fffu + ((u >> 16) & 1u);
    return (short)(u >> 16);
}
// packed pair (v_cvt_pk_bf16_f32)
__device__ __forceinline__ short2 f2bs2(float a, float b) {
    union {
        __hip_bfloat162 h;
        short2 s;
    } u;
    u.h = __float22bfloat162_rn(make_float2(a, b));
    return u.s;
}
__device__ __forceinline__ float bs2f(short s) {
    return __uint_as_float(((unsigned)(unsigned short)s) << 16);
}

__global__ void fill_i32(int* p, int v, int n) {
    int i = blockIdx.x * 256 + threadIdx.x;
    if (i < n) p[i] = v;
}

// cat cols 0..255 pre-initialized with GAT1/GCN1 biases (scatters accumulate on top)
__global__ void init_cat(float* __restrict__ cat, const float* __restrict__ b1, const float* __restrict__ b2) {
    int i = blockIdx.x * 256 + threadIdx.x;  // over N*256
    int n = i >> 8, c = i & 255;
    cat[(size_t)n * 512 + c] = (c < 128) ? b1[c] : b2[c - 128];
}

// pack all 4 conv kernels into W_all[512][2048] bf16 (row=(Kidx*125+oc), col=k*256+ic)
__global__ void repack_wall(const float* __restrict__ cw0, const float* __restrict__ cw1,
                            const float* __restrict__ cw2, const float* __restrict__ cw3,
                            __hip_bfloat16* __restrict__ wall) {
    int i = blockIdx.x * 256 + threadIdx.x;
    if (i >= 512 * 2048) return;
    int r = i >> 11, c = i & 2047;
    int k = c >> 8, ic = c & 255;
    float v = 0.f;
    if (r < 500) {
        int Kidx = r / 125, oc = r - Kidx * 125;
        int K = 5 + Kidx;
        if (k < K) {
            const float* cw = Kidx == 0 ? cw0 : Kidx == 1 ? cw1 : Kidx == 2 ? cw2 : cw3;
            v = cw[((size_t)oc * 256 + ic) * K + k];
        }
    }
    wall[i] = __float2bfloat16(v);
}

// transformer weights: wqkvT[768][256] bf16, woT[256][256], bqkv[768]
__global__ void repack_xf(const float* __restrict__ Wq, const float* __restrict__ Wk, const float* __restrict__ Wv,
                          const float* __restrict__ Wo, const float* __restrict__ bq, const float* __restrict__ bk,
                          const float* __restrict__ bv, short* __restrict__ wqkvT, short* __restrict__ woT,
                          float* __restrict__ bqkv) {
    int i = blockIdx.x * 256 + threadIdx.x;
    if (i < 768 * 256) {
        int n = i >> 8, k = i & 255;
        const float* W = n < 256 ? Wq : n < 512 ? Wk : Wv;
        wqkvT[i] = f2bs(W[k * 256 + (n & 255)]);
    }
    if (i < 256 * 256) {
        int n = i >> 8, k = i & 255;
        woT[i] = f2bs(Wo[k * 256 + n]);
    }
    if (i < 768) bqkv[i] = i < 256 ? bq[i] : i < 512 ? bk[i - 256] : bv[i - 512];
}

// ---------- generic fp32 GEMM (graph convs + head) ----------
__global__ __launch_bounds__(256) void gemm64(const float* __restrict__ A, const float* __restrict__ B,
                                              const float* __restrict__ bias, float* __restrict__ C,
                                              int M, int N, int K, int lda, int ldc, int doRelu) {
    __shared__ float As[16][65];
    __shared__ float Bs[16][65];
    const int bm = blockIdx.y * 64, bn = blockIdx.x * 64;
    const int tid = threadIdx.x;
    const int tx = tid & 15, ty = tid >> 4;
    float acc[4][4] = {};
    for (int k0 = 0; k0 < K; k0 += 16) {
#pragma unroll
        for (int j = 0; j < 4; j++) {
            int i = tid + j * 256;
            int kk = i & 15, m = i >> 4;
            int gr = bm + m, gc = k0 + kk;
            As[kk][m] = (gr < M && gc < K) ? A[(size_t)gr * lda + gc] : 0.f;
        }
#pragma unroll
        for (int j = 0; j < 4; j++) {
            int i = tid + j * 256;
            int n = i & 63, kk = i >> 6;
            int gr = k0 + kk, gc = bn + n;
            Bs[kk][n] = (gr < K && gc < N) ? B[(size_t)gr * N + gc] : 0.f;
        }
        __syncthreads();
#pragma unroll
        for (int kk = 0; kk < 16; kk++) {
            float a[4], b[4];
#pragma unroll
            for (int i2 = 0; i2 < 4; i2++) a[i2] = As[kk][ty * 4 + i2];
#pragma unroll
            for (int j2 = 0; j2 < 4; j2++) b[j2] = Bs[kk][tx * 4 + j2];
#pragma unroll
            for (int i2 = 0; i2 < 4; i2++)
#pragma unroll
                for (int j2 = 0; j2 < 4; j2++) acc[i2][j2] = fmaf(a[i2], b[j2], acc[i2][j2]);
        }
        __syncthreads();
    }
#pragma unroll
    for (int i2 = 0; i2 < 4; i2++) {
        int r = bm + ty * 4 + i2;
        if (r >= M) continue;
#pragma unroll
        for (int j2 = 0; j2 < 4; j2++) {
            int c = bn + tx * 4 + j2;
            if (c >= N) continue;
            float v = acc[i2][j2];
            if (bias) v += bias[c];
            if (doRelu) v = fmaxf(v, 0.f);
            C[(size_t)r * ldc + c] = v;
        }
    }
}

// ---------- GAT alphas ----------
__global__ __launch_bounds__(256) void alpha_kernel(const float* __restrict__ h, const float* __restrict__ asrc,
                                                    const float* __restrict__ adst, float* __restrict__ als,
                                                    float* __restrict__ ald) {
    int gw = (blockIdx.x * 256 + threadIdx.x) >> 6;
    int lane = threadIdx.x & 63;
    if (gw >= N_NODES) return;
    const float* row = h + (size_t)gw * FEAT;
    float v0 = row[lane], v1 = row[lane + 64];
    float ps = v0 * asrc[lane] + v1 * asrc[lane + 64];
    float pd = v0 * adst[lane] + v1 * adst[lane + 64];
    ps = warpReduceSum(ps);
    pd = warpReduceSum(pd);
    if (lane == 0) {
        als[gw] = ps;
        ald[gw] = pd;
    }
}

// ---------- edge passes ----------
__device__ __forceinline__ void edge_decode(int i, const int* __restrict__ ei, int& s, int& d) {
    if (i < N_EDGES) {
        s = ei[i];
        d = ei[N_EDGES + i];
    } else {
        s = d = i - N_EDGES;
    }
}

__global__ void edge_p1(const int* __restrict__ ei, const float* __restrict__ als, const float* __restrict__ ald,
                        float* __restrict__ elog, int* __restrict__ menc, float* dega) {
    int i = blockIdx.x * 256 + threadIdx.x;
    if (i >= ET_EDGES) return;
    int s, d;
    edge_decode(i, ei, s, d);
    float e = als[s] + ald[d];
    e = (e >= 0.f) ? e : 0.2f * e;
    elog[i] = e;
    atomicMax(&menc[d], encf(e));
    if (dega) unsafeAtomicAdd(&dega[d], 1.f);
}

__global__ void edge_p2(const int* __restrict__ ei, float* __restrict__ elog, const int* __restrict__ menc,
                        float* __restrict__ den) {
    int i = blockIdx.x * 256 + threadIdx.x;
    if (i >= ET_EDGES) return;
    int s, d;
    edge_decode(i, ei, s, d);
    float ex = __expf(elog[i] - decf(menc[d]));
    elog[i] = ex;
    unsafeAtomicAdd(&den[d], ex);
}

__global__ void edge_p2b(const int* __restrict__ ei, float* __restrict__ elog, const float* __restrict__ den) {
    int i = blockIdx.x * 256 + threadIdx.x;
    if (i >= ET_EDGES) return;
    int s, d;
    edge_decode(i, ei, s, d);
    elog[i] = elog[i] / den[d];
}

__global__ void dinv_kernel(float* deg) {
    int i = blockIdx.x * 256 + threadIdx.x;
    if (i < N_NODES) deg[i] = rsqrtf(fmaxf(deg[i], 1.f));
}

__global__ void edge_scatter(const int* __restrict__ ei, const float* __restrict__ coef, const float* __restrict__ h,
                             float* __restrict__ out, int ldo) {
    int i = blockIdx.x * 256 + threadIdx.x;
    if (i >= ET_EDGES * FEAT) return;
    int e = i >> 7, f = i & 127;
    int s, d;
    edge_decode(e, ei, s, d);
    unsafeAtomicAdd(&out[(size_t)d * ldo + f], coef[e] * h[(size_t)s * FEAT + f]);
}

__global__ void gcn_scatter(const int* __restrict__ ei, const float* __restrict__ dinv, const float* __restrict__ h,
                            float* __restrict__ out, int ldo) {
    int i = blockIdx.x * 256 + threadIdx.x;
    if (i >= ET_EDGES * FEAT) return;
    int e = i >> 7, f = i & 127;
    int s, d;
    edge_decode(e, ei, s, d);
    float coef = dinv[s] * dinv[d];
    unsafeAtomicAdd(&out[(size_t)d * ldo + f], coef * h[(size_t)s * FEAT + f]);
}

__global__ void root_gather(const float* __restrict__ g2, const int* __restrict__ rooti, const float* __restrict__ gb,
                            float* __restrict__ fin) {
    int i = blockIdx.x * 256 + threadIdx.x;
    if (i >= N_ROOTS * FEAT) return;
    int r = i >> 7, c = i & 127;
    fin[(size_t)r * 1128 + c] = g2[(size_t)rooti[r] * FEAT + c] + gb[c];
}

__global__ void fc2_kernel(const float* __restrict__ fch, const float* __restrict__ W, const float* __restrict__ b,
                           float* __restrict__ out) {
    int i = blockIdx.x * 256 + threadIdx.x;
    if (i >= N_ROOTS * 3) return;
    int r = i / 3, c = i - r * 3;
    float acc = b[c];
    for (int k = 0; k < 300; k++) acc = fmaf(fch[(size_t)r * 300 + k], W[k * 3 + c], acc);
    out[i] = acc;
}

// ================= MFMA transformer v2: MFMA attention, 2 nodes/block =================
// LDS: qa (Q scaled, then attn-out, then fp32 LN scratch), kreg (K, then y), vT (V transposed).
#define QA_STRIDE 264
#define KR_STRIDE 264
#define VT_STRIDE 40

template <int MODE>
__global__ __launch_bounds__(256, 3) void xformer_kernel(
    const float* __restrict__ emb, const int* __restrict__ text2, const short* __restrict__ wqkvT,
    const float* __restrict__ bqkv, const short* __restrict__ woT, const float* __restrict__ bo,
    const float* __restrict__ lng, const float* __restrict__ lnb, const int* __restrict__ rooti,
    const int* __restrict__ rpi, float* __restrict__ cat, unsigned short* __restrict__ tbuf) {
    __shared__ short qa[32 * QA_STRIDE];    // 16896 B
    __shared__ short kreg[32 * KR_STRIDE];  // 16896 B
    __shared__ short vT[256 * VT_STRIDE];   // 20480 B  (total 54272 B -> 3 blocks/CU)

    const int tid = threadIdx.x;
    const int wave = tid >> 6, lane = tid & 63;
    const int quad = lane >> 4, l16 = lane & 15;

    int gnode[2];
#pragma unroll
    for (int m = 0; m < 2; m++) {
        int slot = blockIdx.x * 2 + m;
        gnode[m] = (MODE == 0) ? slot : ((slot < N_ROOTS) ? rooti[slot] : rpi[slot - N_ROOTS]);
    }
    const int tokA0 = text2[gnode[0] * SEQ + l16];
    const int tokA1 = text2[gnode[1] * SEQ + l16];

    // ---- Preload A fragments (both nodes, 8 k-chunks) ----
    short8 Areg[2][8];
#pragma unroll
    for (int k0 = 0; k0 < 8; k0++) {
        const float* pa0 = emb + (size_t)tokA0 * 256 + k0 * 32 + quad * 8;
        const float* pa1 = emb + (size_t)tokA1 * 256 + k0 * 32 + quad * 8;
        float4 a0l = ((const float4*)pa0)[0], a0h = ((const float4*)pa0)[1];
        float4 a1l = ((const float4*)pa1)[0], a1h = ((const float4*)pa1)[1];
        short2 c0 = f2bs2(a0l.x, a0l.y), c1 = f2bs2(a0l.z, a0l.w), c2 = f2bs2(a0h.x, a0h.y), c3 = f2bs2(a0h.z, a0h.w);
        Areg[0][k0] = (short8){c0.x, c0.y, c1.x, c1.y, c2.x, c2.y, c3.x, c3.y};
        c0 = f2bs2(a1l.x, a1l.y);
        c1 = f2bs2(a1l.z, a1l.w);
        c2 = f2bs2(a1h.x, a1h.y);
        c3 = f2bs2(a1h.z, a1h.w);
        Areg[1][k0] = (short8){c0.x, c0.y, c1.x, c1.y, c2.x, c2.y, c3.x, c3.y};
    }

    // ---- Phase 1: QKV, 3 passes (q scaled by 1/4 | k | v -> vT transposed) ----
#pragma unroll
    for (int grp = 0; grp < 3; grp++) {
        f32x4 acc[4][2];
#pragma unroll
        for (int i = 0; i < 4; i++) {
            acc[i][0] = (f32x4){0.f, 0.f, 0.f, 0.f};
            acc[i][1] = (f32x4){0.f, 0.f, 0.f, 0.f};
        }
#pragma unroll
        for (int k0 = 0; k0 < 8; k0++) {
#pragma unroll
            for (int i = 0; i < 4; i++) {
                const int g = grp * 16 + wave * 4 + i;
                short8 B = *(const short8*)(wqkvT + (size_t)(g * 16 + l16) * 256 + k0 * 32 + quad * 8);
                acc[i][0] = __builtin_amdgcn_mfma_f32_16x16x32_bf16(Areg[0][k0], B, acc[i][0], 0, 0, 0);
                acc[i][1] = __builtin_amdgcn_mfma_f32_16x16x32_bf16(Areg[1][k0], B, acc[i][1], 0, 0, 0);
            }
        }
#pragma unroll
        for (int i = 0; i < 4; i++) {
            const int g = grp * 16 + wave * 4 + i;
            const int col = g * 16 + l16;  // 0..767
            const float b = bqkv[col];
#pragma unroll
            for (int m = 0; m < 2; m++) {
                const int rbase = m * 16 + quad * 4;
                float v0 = acc[i][m][0] + b, v1 = acc[i][m][1] + b;
                float v2 = acc[i][m][2] + b, v3 = acc[i][m][3] + b;
                if (grp == 0) {  // fold 1/sqrt(dh)=0.25 into Q
                    v0 *= 0.25f;
                    v1 *= 0.25f;
                    v2 *= 0.25f;
                    v3 *= 0.25f;
                }
                short2 p01 = f2bs2(v0, v1), p23 = f2bs2(v2, v3);
                if (grp == 0) {
                    qa[(rbase + 0) * QA_STRIDE + col] = p01.x;
                    qa[(rbase + 1) * QA_STRIDE + col] = p01.y;
                    qa[(rbase + 2) * QA_STRIDE + col] = p23.x;
                    qa[(rbase + 3) * QA_STRIDE + col] = p23.y;
                } else if (grp == 1) {
                    const int cl = col - 256;
                    kreg[(rbase + 0) * KR_STRIDE + cl] = p01.x;
                    kreg[(rbase + 1) * KR_STRIDE + cl] = p01.y;
                    kreg[(rbase + 2) * KR_STRIDE + cl] = p23.x;
                    kreg[(rbase + 3) * KR_STRIDE + cl] = p23.y;
                } else {  // V transposed: vT[d][key]
                    const int d = col - 512;
                    *(short4v*)(vT + d * VT_STRIDE + rbase) = (short4v){p01.x, p01.y, p23.x, p23.y};
                }
            }
        }
    }
    // q/k/v for heads wave*4..+3 are wave-local: no barrier before attention.

    // ---- Phase 2: MFMA attention. S^T = K·Q^T (zero-padded K=32), softmax cols, PV via shuffled P ----
#pragma unroll
    for (int p = 0; p < 2; p++) {
#pragma unroll
        for (int i = 0; i < 4; i++) {
            const int h = wave * 4 + i;
            const int arow = p * 16 + l16;
            const int q8 = (quad & 1) * 8;  // quads 2,3 read valid addr, result zeroed
            short8 Af = *(const short8*)(kreg + arow * KR_STRIDE + h * 16 + q8);
            short8 Bf = *(const short8*)(qa + arow * QA_STRIDE + h * 16 + q8);
            if (quad >= 2) {
                Af = (short8){0, 0, 0, 0, 0, 0, 0, 0};
                Bf = (short8){0, 0, 0, 0, 0, 0, 0, 0};
            }
            f32x4 S = __builtin_amdgcn_mfma_f32_16x16x32_bf16(Af, Bf, (f32x4){0.f, 0.f, 0.f, 0.f}, 0, 0, 0);
            // S^T[key=quad*4+r][q=l16]; softmax over keys (rows) per column q
            float mx = fmaxf(fmaxf(S[0], S[1]), fmaxf(S[2], S[3]));
            mx = fmaxf(mx, __shfl_xor(mx, 16));
            mx = fmaxf(mx, __shfl_xor(mx, 32));
            float e0 = __expf(S[0] - mx), e1 = __expf(S[1] - mx);
            float e2 = __expf(S[2] - mx), e3 = __expf(S[3] - mx);
            float sm = (e0 + e1) + (e2 + e3);
            sm += __shfl_xor(sm, 16);
            sm += __shfl_xor(sm, 32);
            const float inv = 1.f / sm;
            e0 *= inv;
            e1 *= inv;
            e2 *= inv;
            e3 *= inv;
            // Build PV B-operand: B[k=key=quad*8+j][n=q=l16] from P^T via lane shuffles
            float pr[4] = {e0, e1, e2, e3};
            float bp[8];
#pragma unroll
            for (int j = 0; j < 8; j++) {
                const int srcq = (2 * quad + (j >> 2)) & 3;
                float v = __shfl(pr[j & 3], l16 + 16 * srcq);
                bp[j] = (quad < 2) ? v : 0.f;
            }
            short2 b01 = f2bs2(bp[0], bp[1]), b23 = f2bs2(bp[2], bp[3]);
            short2 b45 = f2bs2(bp[4], bp[5]), b67 = f2bs2(bp[6], bp[7]);
            short8 BP = (short8){b01.x, b01.y, b23.x, b23.y, b45.x, b45.y, b67.x, b67.y};
            short8 Av = *(const short8*)(vT + (h * 16 + l16) * VT_STRIDE + p * 16 + q8);
            if (quad >= 2) Av = (short8){0, 0, 0, 0, 0, 0, 0, 0};
            f32x4 O = __builtin_amdgcn_mfma_f32_16x16x32_bf16(Av, BP, (f32x4){0.f, 0.f, 0.f, 0.f}, 0, 0, 0);
            // O^T[d=quad*4+r][q=l16] -> attn-out at qa[row=p*16+l16][col=h*16+quad*4+r] (b64)
            short2 o01 = f2bs2(O[0], O[1]), o23 = f2bs2(O[2], O[3]);
            *(short4v*)(qa + arow * QA_STRIDE + h * 16 + quad * 4) = (short4v){o01.x, o01.y, o23.x, o23.y};
        }
    }
    __syncthreads();  // attn-out crosses waves for O-proj A-frags

    // ---- Phase 3: O-proj (+bo) -> y into kreg cols 0..255 (K dead) ----
    {
        short8 Afr[2][8];
#pragma unroll
        for (int m = 0; m < 2; m++)
#pragma unroll
            for (int k0 = 0; k0 < 8; k0++)
                Afr[m][k0] = *(const short8*)(qa + (m * 16 + l16) * QA_STRIDE + k0 * 32 + quad * 8);
#pragma unroll
        for (int i = 0; i < 4; i++) {
            const int g = wave * 4 + i;
            f32x4 oa0 = (f32x4){0.f, 0.f, 0.f, 0.f}, oa1 = (f32x4){0.f, 0.f, 0.f, 0.f};
#pragma unroll
            for (int k0 = 0; k0 < 8; k0++) {
                short8 B = *(const short8*)(woT + (size_t)(g * 16 + l16) * 256 + k0 * 32 + quad * 8);
                oa0 = __builtin_amdgcn_mfma_f32_16x16x32_bf16(Afr[0][k0], B, oa0, 0, 0, 0);
                oa1 = __builtin_amdgcn_mfma_f32_16x16x32_bf16(Afr[1][k0], B, oa1, 0, 0, 0);
            }
            const int col = g * 16 + l16;
            const float bocol = bo[col];
            short2 a01 = f2bs2(oa0[0] + bocol, oa0[1] + bocol), a23 = f2bs2(oa0[2] + bocol, oa0[3] + bocol);
            short2 c01 = f2bs2(oa1[0] + bocol, oa1[1] + bocol), c23 = f2bs2(oa1[2] + bocol, oa1[3] + bocol);
            kreg[(quad * 4 + 0) * KR_STRIDE + col] = a01.x;
            kreg[(quad * 4 + 1) * KR_STRIDE + col] = a01.y;
            kreg[(quad * 4 + 2) * KR_STRIDE + col] = a23.x;
            kreg[(quad * 4 + 3) * KR_STRIDE + col] = a23.y;
            kreg[(16 + quad * 4 + 0) * KR_STRIDE + col] = c01.x;
            kreg[(16 + quad * 4 + 1) * KR_STRIDE + col] = c01.y;
            kreg[(16 + quad * 4 + 2) * KR_STRIDE + col] = c23.x;
            kreg[(16 + quad * 4 + 3) * KR_STRIDE + col] = c23.y;
        }
    }
    __syncthreads();

    // ---- Phase 4: residual + LayerNorm (pass A: partials + writeback y+res; pass B: normalize) ----
    float* qs = (float*)qa;  // qa dead
    {
        const int row = tid >> 3, seg = tid & 7;
        const int m = row >> 4, r = row & 15;
        const int tokr = text2[gnode[m] * SEQ + r];
        const float* ep = emb + (size_t)tokr * 256 + seg * 32;
        float sum = 0.f, sq = 0.f;
#pragma unroll
        for (int j = 0; j < 4; j++) {
            short8 y8 = *(const short8*)(kreg + row * KR_STRIDE + seg * 32 + j * 8);
            float4 ea = ((const float4*)(ep + j * 8))[0];
            float4 eb = ((const float4*)(ep + j * 8))[1];
            float ev[8] = {ea.x, ea.y, ea.z, ea.w, eb.x, eb.y, eb.z, eb.w};
            float yv[8];
#pragma unroll
            for (int e = 0; e < 8; e++) {
                yv[e] = bs2f(y8[e]) + ev[e];
                sum += yv[e];
                sq = fmaf(yv[e], yv[e], sq);
            }
            short2 w0 = f2bs2(yv[0], yv[1]), w1 = f2bs2(yv[2], yv[3]);
            short2 w2 = f2bs2(yv[4], yv[5]), w3 = f2bs2(yv[6], yv[7]);
            *(short4v*)(kreg + row * KR_STRIDE + seg * 32 + j * 8) = (short4v){w0.x, w0.y, w1.x, w1.y};
            *(short4v*)(kreg + row * KR_STRIDE + seg * 32 + j * 8 + 4) = (short4v){w2.x, w2.y, w3.x, w3.y};
        }
        qs[tid] = sum;
        qs[256 + tid] = sq;
    }
    __syncthreads();
    if (tid < 32) {
        float s = 0.f, q2 = 0.f;
#pragma unroll
        for (int j = 0; j < 8; j++) {
            s += qs[tid * 8 + j];
            q2 += qs[256 + tid * 8 + j];
        }
        float mu = s * (1.f / 256.f);
        float var = q2 * (1.f / 256.f) - mu * mu;
        qs[512 + tid * 2] = mu;
        qs[512 + tid * 2 + 1] = rsqrtf(var + 1e-5f);
    }
    __syncthreads();
    {
        const int c = tid;
        const float g = lng[c], bb = lnb[c];
        float csum[2] = {0.f, 0.f};
#pragma unroll
        for (int m = 0; m < 2; m++) {
#pragma unroll
            for (int r = 0; r < 16; r++) {
                const int row = m * 16 + r;
                const float yv = bs2f(kreg[row * KR_STRIDE + c]);  // y+residual already
                const float mu = qs[512 + row * 2], rstd = qs[512 + row * 2 + 1];
                const float o = (yv - mu) * rstd * g + bb;
                if (MODE == 0) {
                    csum[m] += o;
                } else {
                    tbuf[((size_t)(blockIdx.x * 2 + m) * 24 + r) * 256 + c] = (unsigned short)f2bs(o);
                }
            }
        }
        if (MODE == 0) {
            cat[(size_t)gnode[0] * 512 + 256 + c] = csum[0] * (1.f / 16.f);
            cat[(size_t)gnode[1] * 512 + 256 + c] = csum[1] * (1.f / 16.f);
        } else {
            for (int z = tid; z < 2 * 8 * 256; z += 256) {
                const int m = z >> 11, rem = z & 2047;
                tbuf[((size_t)(blockIdx.x * 2 + m) * 24 + 16 + (rem >> 8)) * 256 + (rem & 255)] = 0;
            }
        }
    }
}

// conv GEMM (proven): C[24576,512] = im2col(tbuf) @ W_all^T
__global__ __launch_bounds__(256) void conv_gemm(const short* __restrict__ tb, const short* __restrict__ wall,
                                                 float* __restrict__ C) {
    __shared__ short As[128 * 40];
    __shared__ short Bs[128 * 40];
    const int bid = blockIdx.x;
    const int m0 = (bid >> 2) * 128;
    const int n0 = (bid & 3) * 128;
    const int tid = threadIdx.x;
    const int lane = tid & 63;
    const int wave = tid >> 6;
    const int wm = (wave >> 1) * 64, wn = (wave & 1) * 64;
    const int quad = lane >> 4, l16 = lane & 15;

    const int r0 = tid >> 2, kc = (tid & 3) * 8;
    const int r1 = r0 + 64;
    const int am0 = m0 + r0, am1 = m0 + r1;
    const int s0 = am0 / 12, p0_ = am0 - s0 * 12;
    const int s1 = am1 / 12, p1_ = am1 - s1 * 12;
    const size_t ga0 = (size_t)(s0 * 24 + p0_) * 256 + kc;
    const size_t ga1 = (size_t)(s1 * 24 + p1_) * 256 + kc;
    const size_t gb0 = (size_t)(n0 + r0) * 2048 + kc;
    const size_t gb1 = (size_t)(n0 + r1) * 2048 + kc;
    short* sa0 = As + r0 * 40 + kc;
    short* sa1 = As + r1 * 40 + kc;
    short* sb0 = Bs + r0 * 40 + kc;
    short* sb1 = Bs + r1 * 40 + kc;

    f32x4 acc[4][4];
#pragma unroll
    for (int i = 0; i < 4; i++)
#pragma unroll
        for (int j = 0; j < 4; j++) acc[i][j] = (f32x4){0.f, 0.f, 0.f, 0.f};

    for (int k0 = 0; k0 < 2048; k0 += 32) {
        short8 a0 = *(const short8*)(tb + ga0 + k0);
        short8 a1 = *(const short8*)(tb + ga1 + k0);
        short8 b0 = *(const short8*)(wall + gb0 + k0);
        short8 b1 = *(const short8*)(wall + gb1 + k0);
        *(short8*)sa0 = a0;
        *(short8*)sa1 = a1;
        *(short8*)sb0 = b0;
        *(short8*)sb1 = b1;
        __syncthreads();
        short8 af[4], bfr[4];
#pragma unroll
        for (int i = 0; i < 4; i++) af[i] = *(const short8*)(As + (wm + i * 16 + l16) * 40 + quad * 8);
#pragma unroll
        for (int j = 0; j < 4; j++) bfr[j] = *(const short8*)(Bs + (wn + j * 16 + l16) * 40 + quad * 8);
#pragma unroll
        for (int i = 0; i < 4; i++)
#pragma unroll
            for (int j = 0; j < 4; j++)
                acc[i][j] = __builtin_amdgcn_mfma_f32_16x16x32_bf16(af[i], bfr[j], acc[i][j], 0, 0, 0);
        __syncthreads();
    }
#pragma unroll
    for (int i = 0; i < 4; i++) {
#pragma unroll
        for (int j = 0; j < 4; j++) {
            const int col = n0 + wn + j * 16 + l16;
            const size_t base = (size_t)(m0 + wm + i * 16 + quad * 4) * 512 + col;
#pragma unroll
            for (int r = 0; r < 4; r++) C[base + (size_t)r * 512] = acc[i][j][r];
        }
    }
}

__global__ void conv_maxpool(const float* __restrict__ C, const float* __restrict__ cb0, const float* __restrict__ cb1,
                             const float* __restrict__ cb2, const float* __restrict__ cb3, float* __restrict__ fin) {
    int i = blockIdx.x * 256 + threadIdx.x;
    if (i >= 2048 * 500) return;
    int slot = i / 500, q = i - slot * 500;
    int Kidx = q / 125, oc = q - Kidx * 125;
    int L = 12 - Kidx;
    const float* base = C + (size_t)(slot * 12) * 512 + q;
    float m = base[0];
    for (int p = 1; p < L; p++) m = fmaxf(m, base[(size_t)p * 512]);
    float b = (Kidx == 0 ? cb0 : Kidx == 1 ? cb1 : Kidx == 2 ? cb2 : cb3)[oc];
    float v = fmaxf(m + b, 0.f);
    int idx = slot < N_ROOTS ? slot : slot - N_ROOTS;
    int colbase = slot < N_ROOTS ? 128 : 628;
    fin[(size_t)idx * 1128 + colbase + q] = v;
}

// ---------- host launch ----------
extern "C" void kernel_launch(void* const* d_in, const int* in_sizes, int n_in, void* d_out, int out_size, void* d_ws,
                              size_t ws_size, hipStream_t stream) {
    const float* x2 = (const float*)d_in[0];
    const float* emb = (const float*)d_in[1];
    const float* Wq = (const float*)d_in[2];
    const float* Wk = (const float*)d_in[3];
    const float* Wv = (const float*)d_in[4];
    const float* Wo = (const float*)d_in[5];
    const float* bq = (const float*)d_in[6];
    const float* bk = (const float*)d_in[7];
    const float* bv = (const float*)d_in[8];
    const float* bo = (const float*)d_in[9];
    const float* lng = (const float*)d_in[10];
    const float* lnb = (const float*)d_in[11];
    const float* gat1_W = (const float*)d_in[12];
    const float* gat1_as = (const float*)d_in[13];
    const float* gat1_ad = (const float*)d_in[14];
    const float* gat1_b = (const float*)d_in[15];
    const float* gcn1_W = (const float*)d_in[16];
    const float* gcn1_b = (const float*)d_in[17];
    const float* gat2_W = (const float*)d_in[18];
    const float* gat2_as = (const float*)d_in[19];
    const float* gat2_ad = (const float*)d_in[20];
    const float* gat2_b = (const float*)d_in[21];
    // d_in[22]/[23] gcn2: dead code in reference forward
    const float* cw0 = (const float*)d_in[24];
    const float* cb0 = (const float*)d_in[25];
    const float* cw1 = (const float*)d_in[26];
    const float* cb1 = (const float*)d_in[27];
    const float* cw2 = (const float*)d_in[28];
    const float* cb2 = (const float*)d_in[29];
    const float* cw3 = (const float*)d_in[30];
    const float* cb3 = (const float*)d_in[31];
    const float* fc1_W = (const float*)d_in[32];
    const float* fc1_b = (const float*)d_in[33];
    const float* fc2_W = (const float*)d_in[34];
    const float* fc2_b = (const float*)d_in[35];
    const int* text2 = (const int*)d_in[36];
    const int* ei = (const int*)d_in[37];
    const int* rooti = (const int*)d_in[38];
    const int* rpi = (const int*)d_in[39];

    float* ws = (float*)d_ws;
    size_t off = 0;
    auto alloc = [&](size_t n) {
        float* p = ws + off;
        off += n;
        return p;
    };
    // zero block first (one small memset): g2o | den1 | den2 | deg
    float* g2o = alloc((size_t)N_NODES * FEAT);
    float* den1 = alloc(N_NODES);
    float* den2 = alloc(N_NODES);
    float* deg = alloc(N_NODES);
    size_t zero_floats = off;
    float* cat = alloc((size_t)N_NODES * 512);  // init_cat covers cols 0..255; xformer fills 256..511
    float* h1 = alloc((size_t)N_NODES * FEAT);  // h1+h2 reused as tbuf after scatters
    float* h2 = alloc((size_t)N_NODES * FEAT);
    float* hg2 = alloc((size_t)N_NODES * FEAT);
    float* als1 = alloc(N_NODES);
    float* ald1 = alloc(N_NODES);
    float* als2 = alloc(N_NODES);
    float* ald2 = alloc(N_NODES);
    int* m1 = (int*)alloc(N_NODES);
    int* m2 = (int*)alloc(N_NODES);
    float* el1 = alloc(ET_EDGES);
    float* el2 = alloc(ET_EDGES);
    float* fin = alloc((size_t)N_ROOTS * 1128);
    float* fch = alloc((size_t)N_ROOTS * 300);
    float* wallf = alloc(512 * 2048 / 2);
    float* wqkvTf = alloc(768 * 256 / 2);
    float* woTf = alloc(256 * 256 / 2);
    float* bqkv = alloc(768);
    (void)ws_size;
    (void)in_sizes;
    (void)n_in;
    (void)out_size;

    unsigned short* tbuf = (unsigned short*)h1;  // 2048*24*256 bf16 fits in h1+h2
    __hip_bfloat16* wall = (__hip_bfloat16*)wallf;
    short* wqkvT = (short*)wqkvTf;
    short* woT = (short*)woTf;
    float* Cbuf = cat;

    hipMemsetAsync(g2o, 0, zero_floats * sizeof(float), stream);
    init_cat<<<cdiv((long long)N_NODES * 256, 256), 256, 0, stream>>>(cat, gat1_b, gcn1_b);
    fill_i32<<<cdiv(2 * N_NODES, 256), 256, 0, stream>>>(m1, (int)0x80000000, 2 * N_NODES);
    repack_wall<<<cdiv(512 * 2048, 256), 256, 0, stream>>>(cw0, cw1, cw2, cw3, wall);
    repack_xf<<<cdiv(768 * 256, 256), 256, 0, stream>>>(Wq, Wk, Wv, Wo, bq, bk, bv, wqkvT, woT, bqkv);

    // GAT1 / GCN1 node transforms
    gemm64<<<dim3(2, 512), 256, 0, stream>>>(x2, gat1_W, nullptr, h1, N_NODES, FEAT, FEAT, FEAT, FEAT, 0);
    gemm64<<<dim3(2, 512), 256, 0, stream>>>(x2, gcn1_W, nullptr, h2, N_NODES, FEAT, FEAT, FEAT, FEAT, 0);
    alpha_kernel<<<cdiv((long long)N_NODES * 64, 256), 256, 0, stream>>>(h1, gat1_as, gat1_ad, als1, ald1);
    edge_p1<<<cdiv(ET_EDGES, 256), 256, 0, stream>>>(ei, als1, ald1, el1, m1, deg);
    edge_p2<<<cdiv(ET_EDGES, 256), 256, 0, stream>>>(ei, el1, m1, den1);
    edge_p2b<<<cdiv(ET_EDGES, 256), 256, 0, stream>>>(ei, el1, den1);
    dinv_kernel<<<cdiv(N_NODES, 256), 256, 0, stream>>>(deg);
    const int sc_blocks = cdiv((long long)ET_EDGES * FEAT, 256);
    edge_scatter<<<sc_blocks, 256, 0, stream>>>(ei, el1, h1, cat + 0, 512);
    gcn_scatter<<<sc_blocks, 256, 0, stream>>>(ei, deg, h2, cat + 128, 512);
    // transformer (MFMA): all nodes -> t_avg into cat[:,256:512]
    xformer_kernel<0><<<N_NODES / 2, 256, 0, stream>>>(emb, text2, wqkvT, bqkv, woT, bo, lng, lnb, rooti, rpi, cat,
                                                       nullptr);
    // transformer (MFMA): conv slots -> tbuf (h1/h2 dead after scatters)
    xformer_kernel<1><<<2 * N_ROOTS / 2, 256, 0, stream>>>(emb, text2, wqkvT, bqkv, woT, bo, lng, lnb, rooti, rpi,
                                                           nullptr, tbuf);
    // GAT2
    gemm64<<<dim3(2, 512), 256, 0, stream>>>(cat, gat2_W, nullptr, hg2, N_NODES, FEAT, 512, 512, FEAT, 0);
    alpha_kernel<<<cdiv((long long)N_NODES * 64, 256), 256, 0, stream>>>(hg2, gat2_as, gat2_ad, als2, ald2);
    edge_p1<<<cdiv(ET_EDGES, 256), 256, 0, stream>>>(ei, als2, ald2, el2, m2, nullptr);
    edge_p2<<<cdiv(ET_EDGES, 256), 256, 0, stream>>>(ei, el2, m2, den2);
    edge_p2b<<<cdiv(ET_EDGES, 256), 256, 0, stream>>>(ei, el2, den2);
    edge_scatter<<<sc_blocks, 256, 0, stream>>>(ei, el2, hg2, g2o, FEAT);
    // conv branch
    conv_gemm<<<192 * 4, 256, 0, stream>>>((const short*)tbuf, (const short*)wall, Cbuf);
    root_gather<<<cdiv(N_ROOTS * FEAT, 256), 256, 0, stream>>>(g2o, rooti, gat2_b, fin);
    conv_maxpool<<<cdiv(2048 * 500, 256), 256, 0, stream>>>(Cbuf, cb0, cb1, cb2, cb3, fin);
    // head
    gemm64<<<dim3(cdiv(300, 64), cdiv(N_ROOTS, 64)), 256, 0, stream>>>(fin, fc1_W, fc1_b, fch, N_ROOTS, 300, 1128,
                                                                       1128, 300, 1);
    fc2_kernel<<<cdiv(N_ROOTS * 3, 256), 256, 0, stream>>>(fch, fc2_W, fc2_b, (float*)d_out);
}

// Round 6
// 2326.976 us; speedup vs baseline: 7.1879x; 1.0799x over previous
//
#include <hip/hip_runtime.h>
#include <hip/hip_bf16.h>
#include <cstdint>
#include <cstddef>

#define N_NODES 32768
#define N_EDGES 131072
#define ET_EDGES (N_EDGES + N_NODES)
#define N_ROOTS 1024
#define EMB_D 256
#define FEAT 128
#define SEQ 16
#define OUT_CH 125

static inline int cdiv(long long a, long long b) { return (int)((a + b - 1) / b); }

typedef short short8 __attribute__((ext_vector_type(8)));
typedef short short4v __attribute__((ext_vector_type(4)));
typedef float f32x4 __attribute__((ext_vector_type(4)));

// ---------- small utils ----------
__device__ __forceinline__ float warpReduceSum(float v) {
#pragma unroll
    for (int m = 32; m; m >>= 1) v += __shfl_xor(v, m, 64);
    return v;
}
__device__ __forceinline__ int encf(float f) {
    int i = __float_as_int(f);
    return i >= 0 ? i : (i ^ 0x7fffffff);
}
__device__ __forceinline__ float decf(int i) {
    return __int_as_float(i >= 0 ? i : (i ^ 0x7fffffff));
}
// fp32 -> bf16 (RNE) scalar
__device__ __forceinline__ short f2bs(float x) {
    unsigned u = __float_as_uint(x);
    u += 0x7fffu + ((u >> 16) & 1u);
    return (short)(u >> 16);
}
// packed pair (v_cvt_pk_bf16_f32)
__device__ __forceinline__ short2 f2bs2(float a, float b) {
    union {
        __hip_bfloat162 h;
        short2 s;
    } u;
    u.h = __float22bfloat162_rn(make_float2(a, b));
    return u.s;
}
__device__ __forceinline__ float bs2f(short s) {
    return __uint_as_float(((unsigned)(unsigned short)s) << 16);
}

__global__ void fill_i32(int* p, int v, int n) {
    int i = blockIdx.x * 256 + threadIdx.x;
    if (i < n) p[i] = v;
}

// cat cols 0..255 pre-initialized with GAT1/GCN1 biases (scatters accumulate on top)
__global__ void init_cat(float* __restrict__ cat, const float* __restrict__ b1, const float* __restrict__ b2) {
    int i = blockIdx.x * 256 + threadIdx.x;  // over N*256
    int n = i >> 8, c = i & 255;
    float b = (c < 128) ? b1[c] : b2[c - 128];
    cat[(size_t)n * 512 + c] = b;
}

// pack all 4 conv kernels into W_all[512][2048] bf16 (row=(Kidx*125+oc), col=k*256+ic)
__global__ void repack_wall(const float* __restrict__ cw0, const float* __restrict__ cw1,
                            const float* __restrict__ cw2, const float* __restrict__ cw3,
                            __hip_bfloat16* __restrict__ wall) {
    int i = blockIdx.x * 256 + threadIdx.x;
    if (i >= 512 * 2048) return;
    int r = i >> 11, c = i & 2047;
    int k = c >> 8, ic = c & 255;
    float v = 0.f;
    if (r < 500) {
        int Kidx = r / 125, oc = r - Kidx * 125;
        int K = 5 + Kidx;
        if (k < K) {
            const float* cw = Kidx == 0 ? cw0 : Kidx == 1 ? cw1 : Kidx == 2 ? cw2 : cw3;
            v = cw[((size_t)oc * 256 + ic) * K + k];
        }
    }
    wall[i] = __float2bfloat16(v);
}

// transformer weights: wqkvT[768][256] bf16, woT[256][256], bqkv[768]
__global__ void repack_xf(const float* __restrict__ Wq, const float* __restrict__ Wk, const float* __restrict__ Wv,
                          const float* __restrict__ Wo, const float* __restrict__ bq, const float* __restrict__ bk,
                          const float* __restrict__ bv, short* __restrict__ wqkvT, short* __restrict__ woT,
                          float* __restrict__ bqkv) {
    int i = blockIdx.x * 256 + threadIdx.x;
    if (i < 768 * 256) {
        int n = i >> 8, k = i & 255;
        const float* W = n < 256 ? Wq : n < 512 ? Wk : Wv;
        wqkvT[i] = f2bs(W[k * 256 + (n & 255)]);
    }
    if (i < 256 * 256) {
        int n = i >> 8, k = i & 255;
        woT[i] = f2bs(Wo[k * 256 + n]);
    }
    if (i < 768) bqkv[i] = i < 256 ? bq[i] : i < 512 ? bk[i - 256] : bv[i - 512];
}

// ---------- generic fp32 GEMM (graph convs + head) ----------
__global__ __launch_bounds__(256) void gemm64(const float* __restrict__ A, const float* __restrict__ B,
                                              const float* __restrict__ bias, float* __restrict__ C,
                                              int M, int N, int K, int lda, int ldc, int doRelu) {
    __shared__ float As[16][65];
    __shared__ float Bs[16][65];
    const int bm = blockIdx.y * 64, bn = blockIdx.x * 64;
    const int tid = threadIdx.x;
    const int tx = tid & 15, ty = tid >> 4;
    float acc[4][4] = {};
    for (int k0 = 0; k0 < K; k0 += 16) {
#pragma unroll
        for (int j = 0; j < 4; j++) {
            int i = tid + j * 256;
            int kk = i & 15, m = i >> 4;
            int gr = bm + m, gc = k0 + kk;
            As[kk][m] = (gr < M && gc < K) ? A[(size_t)gr * lda + gc] : 0.f;
        }
#pragma unroll
        for (int j = 0; j < 4; j++) {
            int i = tid + j * 256;
            int n = i & 63, kk = i >> 6;
            int gr = k0 + kk, gc = bn + n;
            Bs[kk][n] = (gr < K && gc < N) ? B[(size_t)gr * N + gc] : 0.f;
        }
        __syncthreads();
#pragma unroll
        for (int kk = 0; kk < 16; kk++) {
            float a[4], b[4];
#pragma unroll
            for (int i2 = 0; i2 < 4; i2++) a[i2] = As[kk][ty * 4 + i2];
#pragma unroll
            for (int j2 = 0; j2 < 4; j2++) b[j2] = Bs[kk][tx * 4 + j2];
#pragma unroll
            for (int i2 = 0; i2 < 4; i2++)
#pragma unroll
                for (int j2 = 0; j2 < 4; j2++) acc[i2][j2] = fmaf(a[i2], b[j2], acc[i2][j2]);
        }
        __syncthreads();
    }
#pragma unroll
    for (int i2 = 0; i2 < 4; i2++) {
        int r = bm + ty * 4 + i2;
        if (r >= M) continue;
#pragma unroll
        for (int j2 = 0; j2 < 4; j2++) {
            int c = bn + tx * 4 + j2;
            if (c >= N) continue;
            float v = acc[i2][j2];
            if (bias) v += bias[c];
            if (doRelu) v = fmaxf(v, 0.f);
            C[(size_t)r * ldc + c] = v;
        }
    }
}

// ---------- GAT alphas ----------
__global__ __launch_bounds__(256) void alpha_kernel(const float* __restrict__ h, const float* __restrict__ asrc,
                                                    const float* __restrict__ adst, float* __restrict__ als,
                                                    float* __restrict__ ald) {
    int gw = (blockIdx.x * 256 + threadIdx.x) >> 6;
    int lane = threadIdx.x & 63;
    if (gw >= N_NODES) return;
    const float* row = h + (size_t)gw * FEAT;
    float v0 = row[lane], v1 = row[lane + 64];
    float ps = v0 * asrc[lane] + v1 * asrc[lane + 64];
    float pd = v0 * adst[lane] + v1 * adst[lane + 64];
    ps = warpReduceSum(ps);
    pd = warpReduceSum(pd);
    if (lane == 0) {
        als[gw] = ps;
        ald[gw] = pd;
    }
}

// ---------- edge passes ----------
__device__ __forceinline__ void edge_decode(int i, const int* __restrict__ ei, int& s, int& d) {
    if (i < N_EDGES) {
        s = ei[i];
        d = ei[N_EDGES + i];
    } else {
        s = d = i - N_EDGES;
    }
}

__global__ void edge_p1(const int* __restrict__ ei, const float* __restrict__ als, const float* __restrict__ ald,
                        float* __restrict__ elog, int* __restrict__ menc, float* dega) {
    int i = blockIdx.x * 256 + threadIdx.x;
    if (i >= ET_EDGES) return;
    int s, d;
    edge_decode(i, ei, s, d);
    float e = als[s] + ald[d];
    e = (e >= 0.f) ? e : 0.2f * e;
    elog[i] = e;
    atomicMax(&menc[d], encf(e));
    if (dega) unsafeAtomicAdd(&dega[d], 1.f);
}

__global__ void edge_p2(const int* __restrict__ ei, float* __restrict__ elog, const int* __restrict__ menc,
                        float* __restrict__ den) {
    int i = blockIdx.x * 256 + threadIdx.x;
    if (i >= ET_EDGES) return;
    int s, d;
    edge_decode(i, ei, s, d);
    float ex = __expf(elog[i] - decf(menc[d]));
    elog[i] = ex;
    unsafeAtomicAdd(&den[d], ex);
}

__global__ void edge_p2b(const int* __restrict__ ei, float* __restrict__ elog, const float* __restrict__ den) {
    int i = blockIdx.x * 256 + threadIdx.x;
    if (i >= ET_EDGES) return;
    int s, d;
    edge_decode(i, ei, s, d);
    elog[i] = elog[i] / den[d];
}

__global__ void dinv_kernel(float* deg) {
    int i = blockIdx.x * 256 + threadIdx.x;
    if (i < N_NODES) deg[i] = rsqrtf(fmaxf(deg[i], 1.f));
}

__global__ void edge_scatter(const int* __restrict__ ei, const float* __restrict__ coef, const float* __restrict__ h,
                             float* __restrict__ out, int ldo) {
    int i = blockIdx.x * 256 + threadIdx.x;
    if (i >= ET_EDGES * FEAT) return;
    int e = i >> 7, f = i & 127;
    int s, d;
    edge_decode(e, ei, s, d);
    unsafeAtomicAdd(&out[(size_t)d * ldo + f], coef[e] * h[(size_t)s * FEAT + f]);
}

__global__ void gcn_scatter(const int* __restrict__ ei, const float* __restrict__ dinv, const float* __restrict__ h,
                            float* __restrict__ out, int ldo) {
    int i = blockIdx.x * 256 + threadIdx.x;
    if (i >= ET_EDGES * FEAT) return;
    int e = i >> 7, f = i & 127;
    int s, d;
    edge_decode(e, ei, s, d);
    float coef = dinv[s] * dinv[d];
    unsafeAtomicAdd(&out[(size_t)d * ldo + f], coef * h[(size_t)s * FEAT + f]);
}

__global__ void root_gather(const float* __restrict__ g2, const int* __restrict__ rooti, const float* __restrict__ gb,
                            float* __restrict__ fin) {
    int i = blockIdx.x * 256 + threadIdx.x;
    if (i >= N_ROOTS * FEAT) return;
    int r = i >> 7, c = i & 127;
    fin[(size_t)r * 1128 + c] = g2[(size_t)rooti[r] * FEAT + c] + gb[c];
}

__global__ void fc2_kernel(const float* __restrict__ fch, const float* __restrict__ W, const float* __restrict__ b,
                           float* __restrict__ out) {
    int i = blockIdx.x * 256 + threadIdx.x;
    if (i >= N_ROOTS * 3) return;
    int r = i / 3, c = i - r * 3;
    float acc = b[c];
    for (int k = 0; k < 300; k++) acc = fmaf(fch[(size_t)r * 300 + k], W[k * 3 + c], acc);
    out[i] = acc;
}

// ================= MFMA transformer v3: V in registers, 2 LDS regions, 4 blocks/CU =================
#define QA_STRIDE 264  // 132 dwords == 4 mod 32 -> 2-way on frag reads (free)
#define KR_STRIDE 264

template <int MODE>
__global__ __launch_bounds__(256, 4) void xformer_kernel(
    const float* __restrict__ emb, const int* __restrict__ text2, const short* __restrict__ wqkvT,
    const float* __restrict__ bqkv, const short* __restrict__ woT, const float* __restrict__ bo,
    const float* __restrict__ lng, const float* __restrict__ lnb, const int* __restrict__ rooti,
    const int* __restrict__ rpi, float* __restrict__ cat, unsigned short* __restrict__ tbuf) {
    __shared__ short qa[32 * QA_STRIDE];    // Q (scaled), then attn-out, then fp32 LN scratch
    __shared__ short kreg[32 * KR_STRIDE];  // K, then y (post O-proj)
    // total LDS 33792 B -> 4 blocks/CU

    const int tid = threadIdx.x;
    const int wave = tid >> 6, lane = tid & 63;
    const int quad = lane >> 4, l16 = lane & 15;

    int gnode[2];
#pragma unroll
    for (int m = 0; m < 2; m++) {
        int slot = blockIdx.x * 2 + m;
        gnode[m] = (MODE == 0) ? slot : ((slot < N_ROOTS) ? rooti[slot] : rpi[slot - N_ROOTS]);
    }
    const int tokA0 = text2[gnode[0] * SEQ + l16];
    const int tokA1 = text2[gnode[1] * SEQ + l16];

    // ---- Preload A fragments (both nodes, 8 k-chunks) ----
    short8 Areg[2][8];
#pragma unroll
    for (int k0 = 0; k0 < 8; k0++) {
        const float* pa0 = emb + (size_t)tokA0 * 256 + k0 * 32 + quad * 8;
        const float* pa1 = emb + (size_t)tokA1 * 256 + k0 * 32 + quad * 8;
        float4 a0l = ((const float4*)pa0)[0], a0h = ((const float4*)pa0)[1];
        float4 a1l = ((const float4*)pa1)[0], a1h = ((const float4*)pa1)[1];
        short2 c0 = f2bs2(a0l.x, a0l.y), c1 = f2bs2(a0l.z, a0l.w), c2 = f2bs2(a0h.x, a0h.y), c3 = f2bs2(a0h.z, a0h.w);
        Areg[0][k0] = (short8){c0.x, c0.y, c1.x, c1.y, c2.x, c2.y, c3.x, c3.y};
        c0 = f2bs2(a1l.x, a1l.y);
        c1 = f2bs2(a1l.z, a1l.w);
        c2 = f2bs2(a1h.x, a1h.y);
        c3 = f2bs2(a1h.z, a1h.w);
        Areg[1][k0] = (short8){c0.x, c0.y, c1.x, c1.y, c2.x, c2.y, c3.x, c3.y};
    }

    // V C-frags kept in registers (wave-local): vacc[i][m] for tile g=32+wave*4+i, node m
    f32x4 vacc[4][2];

    // ---- Phase 1: QKV, 3 passes (q scaled 1/4 -> qa | k -> kreg | v -> registers) ----
#pragma unroll
    for (int grp = 0; grp < 3; grp++) {
        f32x4 acc[4][2];
#pragma unroll
        for (int i = 0; i < 4; i++) {
            acc[i][0] = (f32x4){0.f, 0.f, 0.f, 0.f};
            acc[i][1] = (f32x4){0.f, 0.f, 0.f, 0.f};
        }
#pragma unroll
        for (int k0 = 0; k0 < 8; k0++) {
#pragma unroll
            for (int i = 0; i < 4; i++) {
                const int g = grp * 16 + wave * 4 + i;
                short8 B = *(const short8*)(wqkvT + (size_t)(g * 16 + l16) * 256 + k0 * 32 + quad * 8);
                acc[i][0] = __builtin_amdgcn_mfma_f32_16x16x32_bf16(Areg[0][k0], B, acc[i][0], 0, 0, 0);
                acc[i][1] = __builtin_amdgcn_mfma_f32_16x16x32_bf16(Areg[1][k0], B, acc[i][1], 0, 0, 0);
            }
        }
#pragma unroll
        for (int i = 0; i < 4; i++) {
            const int g = grp * 16 + wave * 4 + i;
            const int col = g * 16 + l16;  // 0..767
            const float b = bqkv[col];
            if (grp == 2) {
                // keep V in registers (+bias)
#pragma unroll
                for (int m = 0; m < 2; m++) {
                    vacc[i][m][0] = acc[i][m][0] + b;
                    vacc[i][m][1] = acc[i][m][1] + b;
                    vacc[i][m][2] = acc[i][m][2] + b;
                    vacc[i][m][3] = acc[i][m][3] + b;
                }
            } else {
#pragma unroll
                for (int m = 0; m < 2; m++) {
                    const int rbase = m * 16 + quad * 4;
                    float v0 = acc[i][m][0] + b, v1 = acc[i][m][1] + b;
                    float v2 = acc[i][m][2] + b, v3 = acc[i][m][3] + b;
                    if (grp == 0) {  // fold 1/sqrt(dh)=0.25 into Q
                        v0 *= 0.25f;
                        v1 *= 0.25f;
                        v2 *= 0.25f;
                        v3 *= 0.25f;
                    }
                    short2 p01 = f2bs2(v0, v1), p23 = f2bs2(v2, v3);
                    short* dst = (grp == 0) ? (qa + (rbase)*QA_STRIDE + col) : (kreg + (rbase)*KR_STRIDE + (col - 256));
                    const int str = (grp == 0) ? QA_STRIDE : KR_STRIDE;
                    dst[0 * str] = p01.x;
                    dst[1 * str] = p01.y;
                    dst[2 * str] = p23.x;
                    dst[3 * str] = p23.y;
                }
            }
        }
    }
    // q/k/v for heads wave*4..+3 are wave-local: no barrier before attention.

    // ---- Phase 2: MFMA attention. S^T = K·Q^T; softmax per column; PV with A=V^T (shuffled regs) ----
#pragma unroll
    for (int p = 0; p < 2; p++) {
#pragma unroll
        for (int i = 0; i < 4; i++) {
            const int h = wave * 4 + i;
            const int arow = p * 16 + l16;
            const int q8 = (quad & 1) * 8;
            short8 Af = *(const short8*)(kreg + arow * KR_STRIDE + h * 16 + q8);
            short8 Bf = *(const short8*)(qa + arow * QA_STRIDE + h * 16 + q8);
            if (quad >= 2) {
                Af = (short8){0, 0, 0, 0, 0, 0, 0, 0};
                Bf = (short8){0, 0, 0, 0, 0, 0, 0, 0};
            }
            f32x4 S = __builtin_amdgcn_mfma_f32_16x16x32_bf16(Af, Bf, (f32x4){0.f, 0.f, 0.f, 0.f}, 0, 0, 0);
            // S^T[key=quad*4+r][q=l16]; softmax over keys per column q
            float mx = fmaxf(fmaxf(S[0], S[1]), fmaxf(S[2], S[3]));
            mx = fmaxf(mx, __shfl_xor(mx, 16));
            mx = fmaxf(mx, __shfl_xor(mx, 32));
            float e0 = __expf(S[0] - mx), e1 = __expf(S[1] - mx);
            float e2 = __expf(S[2] - mx), e3 = __expf(S[3] - mx);
            float sm = (e0 + e1) + (e2 + e3);
            sm += __shfl_xor(sm, 16);
            sm += __shfl_xor(sm, 32);
            const float inv = 1.f / sm;
            float pr[4] = {e0 * inv, e1 * inv, e2 * inv, e3 * inv};
            // PV B-operand: B[k=key=quad*8+j][n=q=l16] = P^T[key][q] via shuffles (verified pattern)
            float bp[8];
#pragma unroll
            for (int j = 0; j < 8; j++) {
                const int srcq = (2 * quad + (j >> 2)) & 3;
                float v = __shfl(pr[j & 3], l16 + 16 * srcq);
                bp[j] = (quad < 2) ? v : 0.f;
            }
            short2 b01 = f2bs2(bp[0], bp[1]), b23 = f2bs2(bp[2], bp[3]);
            short2 b45 = f2bs2(bp[4], bp[5]), b67 = f2bs2(bp[6], bp[7]);
            short8 BP = (short8){b01.x, b01.y, b23.x, b23.y, b45.x, b45.y, b67.x, b67.y};
            // PV A-operand: A[m=d_local=l16][k=key=quad*8+j] = V[node p][key][h*16+l16]
            // from vacc[i][p]: value at src lane 16*((q8+j)>>2)+l16, reg (j&3); zero for quad>=2
            float av[8];
#pragma unroll
            for (int j = 0; j < 8; j++) {
                const int srcq = ((quad & 1) * 2 + (j >> 2));
                float v = __shfl(vacc[i][p][j & 3], l16 + 16 * srcq);
                av[j] = (quad < 2) ? v : 0.f;
            }
            short2 a01 = f2bs2(av[0], av[1]), a23 = f2bs2(av[2], av[3]);
            short2 a45 = f2bs2(av[4], av[5]), a67 = f2bs2(av[6], av[7]);
            short8 Av = (short8){a01.x, a01.y, a23.x, a23.y, a45.x, a45.y, a67.x, a67.y};
            f32x4 O = __builtin_amdgcn_mfma_f32_16x16x32_bf16(Av, BP, (f32x4){0.f, 0.f, 0.f, 0.f}, 0, 0, 0);
            // O^T[d=quad*4+r][q=l16] -> attn-out at qa[row=p*16+l16][col=h*16+quad*4+r] (b64)
            short2 o01 = f2bs2(O[0], O[1]), o23 = f2bs2(O[2], O[3]);
            *(short4v*)(qa + arow * QA_STRIDE + h * 16 + quad * 4) = (short4v){o01.x, o01.y, o23.x, o23.y};
        }
    }
    __syncthreads();  // attn-out crosses waves for O-proj A-frags

    // ---- Phase 3: O-proj (+bo) -> y into kreg cols 0..255 (K dead) ----
    {
        short8 Afr[2][8];
#pragma unroll
        for (int m = 0; m < 2; m++)
#pragma unroll
            for (int k0 = 0; k0 < 8; k0++)
                Afr[m][k0] = *(const short8*)(qa + (m * 16 + l16) * QA_STRIDE + k0 * 32 + quad * 8);
#pragma unroll
        for (int i = 0; i < 4; i++) {
            const int g = wave * 4 + i;
            f32x4 oa0 = (f32x4){0.f, 0.f, 0.f, 0.f}, oa1 = (f32x4){0.f, 0.f, 0.f, 0.f};
#pragma unroll
            for (int k0 = 0; k0 < 8; k0++) {
                short8 B = *(const short8*)(woT + (size_t)(g * 16 + l16) * 256 + k0 * 32 + quad * 8);
                oa0 = __builtin_amdgcn_mfma_f32_16x16x32_bf16(Afr[0][k0], B, oa0, 0, 0, 0);
                oa1 = __builtin_amdgcn_mfma_f32_16x16x32_bf16(Afr[1][k0], B, oa1, 0, 0, 0);
            }
            const int col = g * 16 + l16;
            const float bocol = bo[col];
            short2 a01 = f2bs2(oa0[0] + bocol, oa0[1] + bocol), a23 = f2bs2(oa0[2] + bocol, oa0[3] + bocol);
            short2 c01 = f2bs2(oa1[0] + bocol, oa1[1] + bocol), c23 = f2bs2(oa1[2] + bocol, oa1[3] + bocol);
            kreg[(quad * 4 + 0) * KR_STRIDE + col] = a01.x;
            kreg[(quad * 4 + 1) * KR_STRIDE + col] = a01.y;
            kreg[(quad * 4 + 2) * KR_STRIDE + col] = a23.x;
            kreg[(quad * 4 + 3) * KR_STRIDE + col] = a23.y;
            kreg[(16 + quad * 4 + 0) * KR_STRIDE + col] = c01.x;
            kreg[(16 + quad * 4 + 1) * KR_STRIDE + col] = c01.y;
            kreg[(16 + quad * 4 + 2) * KR_STRIDE + col] = c23.x;
            kreg[(16 + quad * 4 + 3) * KR_STRIDE + col] = c23.y;
        }
    }
    __syncthreads();

    // ---- Phase 4: residual + LayerNorm (pass A: partials + writeback y+res; pass B: normalize) ----
    float* qs = (float*)qa;  // qa dead
    {
        const int row = tid >> 3, seg = tid & 7;
        const int m = row >> 4, r = row & 15;
        const int tokr = text2[gnode[m] * SEQ + r];
        const float* ep = emb + (size_t)tokr * 256 + seg * 32;
        float sum = 0.f, sq = 0.f;
#pragma unroll
        for (int j = 0; j < 4; j++) {
            short8 y8 = *(const short8*)(kreg + row * KR_STRIDE + seg * 32 + j * 8);
            float4 ea = ((const float4*)(ep + j * 8))[0];
            float4 eb = ((const float4*)(ep + j * 8))[1];
            float ev[8] = {ea.x, ea.y, ea.z, ea.w, eb.x, eb.y, eb.z, eb.w};
            float yv[8];
#pragma unroll
            for (int e = 0; e < 8; e++) {
                yv[e] = bs2f(y8[e]) + ev[e];
                sum += yv[e];
                sq = fmaf(yv[e], yv[e], sq);
            }
            short2 w0 = f2bs2(yv[0], yv[1]), w1 = f2bs2(yv[2], yv[3]);
            short2 w2 = f2bs2(yv[4], yv[5]), w3 = f2bs2(yv[6], yv[7]);
            *(short4v*)(kreg + row * KR_STRIDE + seg * 32 + j * 8) = (short4v){w0.x, w0.y, w1.x, w1.y};
            *(short4v*)(kreg + row * KR_STRIDE + seg * 32 + j * 8 + 4) = (short4v){w2.x, w2.y, w3.x, w3.y};
        }
        qs[tid] = sum;
        qs[256 + tid] = sq;
    }
    __syncthreads();
    if (tid < 32) {
        float s = 0.f, q2 = 0.f;
#pragma unroll
        for (int j = 0; j < 8; j++) {
            s += qs[tid * 8 + j];
            q2 += qs[256 + tid * 8 + j];
        }
        float mu = s * (1.f / 256.f);
        float var = q2 * (1.f / 256.f) - mu * mu;
        qs[512 + tid * 2] = mu;
        qs[512 + tid * 2 + 1] = rsqrtf(var + 1e-5f);
    }
    __syncthreads();
    {
        const int c = tid;
        const float g = lng[c], bb = lnb[c];
        float csum[2] = {0.f, 0.f};
#pragma unroll
        for (int m = 0; m < 2; m++) {
#pragma unroll
            for (int r = 0; r < 16; r++) {
                const int row = m * 16 + r;
                const float yv = bs2f(kreg[row * KR_STRIDE + c]);  // y+residual already
                const float mu = qs[512 + row * 2], rstd = qs[512 + row * 2 + 1];
                const float o = (yv - mu) * rstd * g + bb;
                if (MODE == 0) {
                    csum[m] += o;
                } else {
                    tbuf[((size_t)(blockIdx.x * 2 + m) * 24 + r) * 256 + c] = (unsigned short)f2bs(o);
                }
            }
        }
        if (MODE == 0) {
            cat[(size_t)gnode[0] * 512 + 256 + c] = csum[0] * (1.f / 16.f);
            cat[(size_t)gnode[1] * 512 + 256 + c] = csum[1] * (1.f / 16.f);
        } else {
            for (int z = tid; z < 2 * 8 * 256; z += 256) {
                const int m = z >> 11, rem = z & 2047;
                tbuf[((size_t)(blockIdx.x * 2 + m) * 24 + 16 + (rem >> 8)) * 256 + (rem & 255)] = 0;
            }
        }
    }
}

// conv GEMM (proven): C[24576,512] = im2col(tbuf) @ W_all^T
__global__ __launch_bounds__(256) void conv_gemm(const short* __restrict__ tb, const short* __restrict__ wall,
                                                 float* __restrict__ C) {
    __shared__ short As[128 * 40];
    __shared__ short Bs[128 * 40];
    const int bid = blockIdx.x;
    const int m0 = (bid >> 2) * 128;
    const int n0 = (bid & 3) * 128;
    const int tid = threadIdx.x;
    const int lane = tid & 63;
    const int wave = tid >> 6;
    const int wm = (wave >> 1) * 64, wn = (wave & 1) * 64;
    const int quad = lane >> 4, l16 = lane & 15;

    const int r0 = tid >> 2, kc = (tid & 3) * 8;
    const int r1 = r0 + 64;
    const int am0 = m0 + r0, am1 = m0 + r1;
    const int s0 = am0 / 12, p0_ = am0 - s0 * 12;
    const int s1 = am1 / 12, p1_ = am1 - s1 * 12;
    const size_t ga0 = (size_t)(s0 * 24 + p0_) * 256 + kc;
    const size_t ga1 = (size_t)(s1 * 24 + p1_) * 256 + kc;
    const size_t gb0 = (size_t)(n0 + r0) * 2048 + kc;
    const size_t gb1 = (size_t)(n0 + r1) * 2048 + kc;
    short* sa0 = As + r0 * 40 + kc;
    short* sa1 = As + r1 * 40 + kc;
    short* sb0 = Bs + r0 * 40 + kc;
    short* sb1 = Bs + r1 * 40 + kc;

    f32x4 acc[4][4];
#pragma unroll
    for (int i = 0; i < 4; i++)
#pragma unroll
        for (int j = 0; j < 4; j++) acc[i][j] = (f32x4){0.f, 0.f, 0.f, 0.f};

    for (int k0 = 0; k0 < 2048; k0 += 32) {
        short8 a0 = *(const short8*)(tb + ga0 + k0);
        short8 a1 = *(const short8*)(tb + ga1 + k0);
        short8 b0 = *(const short8*)(wall + gb0 + k0);
        short8 b1 = *(const short8*)(wall + gb1 + k0);
        *(short8*)sa0 = a0;
        *(short8*)sa1 = a1;
        *(short8*)sb0 = b0;
        *(short8*)sb1 = b1;
        __syncthreads();
        short8 af[4], bfr[4];
#pragma unroll
        for (int i = 0; i < 4; i++) af[i] = *(const short8*)(As + (wm + i * 16 + l16) * 40 + quad * 8);
#pragma unroll
        for (int j = 0; j < 4; j++) bfr[j] = *(const short8*)(Bs + (wn + j * 16 + l16) * 40 + quad * 8);
#pragma unroll
        for (int i = 0; i < 4; i++)
#pragma unroll
            for (int j = 0; j < 4; j++)
                acc[i][j] = __builtin_amdgcn_mfma_f32_16x16x32_bf16(af[i], bfr[j], acc[i][j], 0, 0, 0);
        __syncthreads();
    }
#pragma unroll
    for (int i = 0; i < 4; i++) {
#pragma unroll
        for (int j = 0; j < 4; j++) {
            const int col = n0 + wn + j * 16 + l16;
            const size_t base = (size_t)(m0 + wm + i * 16 + quad * 4) * 512 + col;
#pragma unroll
            for (int r = 0; r < 4; r++) C[base + (size_t)r * 512] = acc[i][j][r];
        }
    }
}

__global__ void conv_maxpool(const float* __restrict__ C, const float* __restrict__ cb0, const float* __restrict__ cb1,
                             const float* __restrict__ cb2, const float* __restrict__ cb3, float* __restrict__ fin) {
    int i = blockIdx.x * 256 + threadIdx.x;
    if (i >= 2048 * 500) return;
    int slot = i / 500, q = i - slot * 500;
    int Kidx = q / 125, oc = q - Kidx * 125;
    int L = 12 - Kidx;
    const float* base = C + (size_t)(slot * 12) * 512 + q;
    float m = base[0];
    for (int p = 1; p < L; p++) m = fmaxf(m, base[(size_t)p * 512]);
    float b = (Kidx == 0 ? cb0 : Kidx == 1 ? cb1 : Kidx == 2 ? cb2 : cb3)[oc];
    float v = fmaxf(m + b, 0.f);
    int idx = slot < N_ROOTS ? slot : slot - N_ROOTS;
    int colbase = slot < N_ROOTS ? 128 : 628;
    fin[(size_t)idx * 1128 + colbase + q] = v;
}

// ---------- host launch ----------
extern "C" void kernel_launch(void* const* d_in, const int* in_sizes, int n_in, void* d_out, int out_size, void* d_ws,
                              size_t ws_size, hipStream_t stream) {
    const float* x2 = (const float*)d_in[0];
    const float* emb = (const float*)d_in[1];
    const float* Wq = (const float*)d_in[2];
    const float* Wk = (const float*)d_in[3];
    const float* Wv = (const float*)d_in[4];
    const float* Wo = (const float*)d_in[5];
    const float* bq = (const float*)d_in[6];
    const float* bk = (const float*)d_in[7];
    const float* bv = (const float*)d_in[8];
    const float* bo = (const float*)d_in[9];
    const float* lng = (const float*)d_in[10];
    const float* lnb = (const float*)d_in[11];
    const float* gat1_W = (const float*)d_in[12];
    const float* gat1_as = (const float*)d_in[13];
    const float* gat1_ad = (const float*)d_in[14];
    const float* gat1_b = (const float*)d_in[15];
    const float* gcn1_W = (const float*)d_in[16];
    const float* gcn1_b = (const float*)d_in[17];
    const float* gat2_W = (const float*)d_in[18];
    const float* gat2_as = (const float*)d_in[19];
    const float* gat2_ad = (const float*)d_in[20];
    const float* gat2_b = (const float*)d_in[21];
    // d_in[22]/[23] gcn2: dead code in reference forward
    const float* cw0 = (const float*)d_in[24];
    const float* cb0 = (const float*)d_in[25];
    const float* cw1 = (const float*)d_in[26];
    const float* cb1 = (const float*)d_in[27];
    const float* cw2 = (const float*)d_in[28];
    const float* cb2 = (const float*)d_in[29];
    const float* cw3 = (const float*)d_in[30];
    const float* cb3 = (const float*)d_in[31];
    const float* fc1_W = (const float*)d_in[32];
    const float* fc1_b = (const float*)d_in[33];
    const float* fc2_W = (const float*)d_in[34];
    const float* fc2_b = (const float*)d_in[35];
    const int* text2 = (const int*)d_in[36];
    const int* ei = (const int*)d_in[37];
    const int* rooti = (const int*)d_in[38];
    const int* rpi = (const int*)d_in[39];

    float* ws = (float*)d_ws;
    size_t off = 0;
    auto alloc = [&](size_t n) {
        float* p = ws + off;
        off += n;
        return p;
    };
    // zero block first (one small memset): g2o | den1 | den2 | deg
    float* g2o = alloc((size_t)N_NODES * FEAT);
    float* den1 = alloc(N_NODES);
    float* den2 = alloc(N_NODES);
    float* deg = alloc(N_NODES);
    size_t zero_floats = off;
    float* cat = alloc((size_t)N_NODES * 512);  // init_cat covers cols 0..255; xformer fills 256..511
    float* h1 = alloc((size_t)N_NODES * FEAT);  // h1+h2 reused as tbuf after scatters
    float* h2 = alloc((size_t)N_NODES * FEAT);
    float* hg2 = alloc((size_t)N_NODES * FEAT);
    float* als1 = alloc(N_NODES);
    float* ald1 = alloc(N_NODES);
    float* als2 = alloc(N_NODES);
    float* ald2 = alloc(N_NODES);
    int* m1 = (int*)alloc(N_NODES);
    int* m2 = (int*)alloc(N_NODES);
    float* el1 = alloc(ET_EDGES);
    float* el2 = alloc(ET_EDGES);
    float* fin = alloc((size_t)N_ROOTS * 1128);
    float* fch = alloc((size_t)N_ROOTS * 300);
    float* wallf = alloc(512 * 2048 / 2);
    float* wqkvTf = alloc(768 * 256 / 2);
    float* woTf = alloc(256 * 256 / 2);
    float* bqkv = alloc(768);
    (void)ws_size;
    (void)in_sizes;
    (void)n_in;
    (void)out_size;

    unsigned short* tbuf = (unsigned short*)h1;  // 2048*24*256 bf16 fits in h1+h2
    __hip_bfloat16* wall = (__hip_bfloat16*)wallf;
    short* wqkvT = (short*)wqkvTf;
    short* woT = (short*)woTf;
    float* Cbuf = cat;

    hipMemsetAsync(g2o, 0, zero_floats * sizeof(float), stream);
    init_cat<<<cdiv((long long)N_NODES * 256, 256), 256, 0, stream>>>(cat, gat1_b, gcn1_b);
    fill_i32<<<cdiv(2 * N_NODES, 256), 256, 0, stream>>>(m1, (int)0x80000000, 2 * N_NODES);
    repack_wall<<<cdiv(512 * 2048, 256), 256, 0, stream>>>(cw0, cw1, cw2, cw3, wall);
    repack_xf<<<cdiv(768 * 256, 256), 256, 0, stream>>>(Wq, Wk, Wv, Wo, bq, bk, bv, wqkvT, woT, bqkv);

    // GAT1 / GCN1 node transforms
    gemm64<<<dim3(2, 512), 256, 0, stream>>>(x2, gat1_W, nullptr, h1, N_NODES, FEAT, FEAT, FEAT, FEAT, 0);
    gemm64<<<dim3(2, 512), 256, 0, stream>>>(x2, gcn1_W, nullptr, h2, N_NODES, FEAT, FEAT, FEAT, FEAT, 0);
    alpha_kernel<<<cdiv((long long)N_NODES * 64, 256), 256, 0, stream>>>(h1, gat1_as, gat1_ad, als1, ald1);
    edge_p1<<<cdiv(ET_EDGES, 256), 256, 0, stream>>>(ei, als1, ald1, el1, m1, deg);
    edge_p2<<<cdiv(ET_EDGES, 256), 256, 0, stream>>>(ei, el1, m1, den1);
    edge_p2b<<<cdiv(ET_EDGES, 256), 256, 0, stream>>>(ei, el1, den1);
    dinv_kernel<<<cdiv(N_NODES, 256), 256, 0, stream>>>(deg);
    const int sc_blocks = cdiv((long long)ET_EDGES * FEAT, 256);
    edge_scatter<<<sc_blocks, 256, 0, stream>>>(ei, el1, h1, cat + 0, 512);
    gcn_scatter<<<sc_blocks, 256, 0, stream>>>(ei, deg, h2, cat + 128, 512);
    // transformer (MFMA): all nodes -> t_avg into cat[:,256:512]
    xformer_kernel<0><<<N_NODES / 2, 256, 0, stream>>>(emb, text2, wqkvT, bqkv, woT, bo, lng, lnb, rooti, rpi, cat,
                                                       nullptr);
    // transformer (MFMA): conv slots -> tbuf (h1/h2 dead after scatters)
    xformer_kernel<1><<<2 * N_ROOTS / 2, 256, 0, stream>>>(emb, text2, wqkvT, bqkv, woT, bo, lng, lnb, rooti, rpi,
                                                           nullptr, tbuf);
    // GAT2
    gemm64<<<dim3(2, 512), 256, 0, stream>>>(cat, gat2_W, nullptr, hg2, N_NODES, FEAT, 512, 512, FEAT, 0);
    alpha_kernel<<<cdiv((long long)N_NODES * 64, 256), 256, 0, stream>>>(hg2, gat2_as, gat2_ad, als2, ald2);
    edge_p1<<<cdiv(ET_EDGES, 256), 256, 0, stream>>>(ei, als2, ald2, el2, m2, nullptr);
    edge_p2<<<cdiv(ET_EDGES, 256), 256, 0, stream>>>(ei, el2, m2, den2);
    edge_p2b<<<cdiv(ET_EDGES, 256), 256, 0, stream>>>(ei, el2, den2);
    edge_scatter<<<sc_blocks, 256, 0, stream>>>(ei, el2, hg2, g2o, FEAT);
    // conv branch
    conv_gemm<<<192 * 4, 256, 0, stream>>>((const short*)tbuf, (const short*)wall, Cbuf);
    root_gather<<<cdiv(N_ROOTS * FEAT, 256), 256, 0, stream>>>(g2o, rooti, gat2_b, fin);
    conv_maxpool<<<cdiv(2048 * 500, 256), 256, 0, stream>>>(Cbuf, cb0, cb1, cb2, cb3, fin);
    // head
    gemm64<<<dim3(cdiv(300, 64), cdiv(N_ROOTS, 64)), 256, 0, stream>>>(fin, fc1_W, fc1_b, fch, N_ROOTS, 300, 1128,
                                                                       1128, 300, 1);
    fc2_kernel<<<cdiv(N_ROOTS * 3, 256), 256, 0, stream>>>(fch, fc2_W, fc2_b, (float*)d_out);
}

// Round 7
// 2183.549 us; speedup vs baseline: 7.6600x; 1.0657x over previous
//
#include <hip/hip_runtime.h>
#include <hip/hip_bf16.h>
#include <cstdint>
#include <cstddef>

#define N_NODES 32768
#define N_EDGES 131072
#define ET_EDGES (N_EDGES + N_NODES)
#define N_ROOTS 1024
#define EMB_D 256
#define FEAT 128
#define SEQ 16
#define OUT_CH 125

static inline int cdiv(long long a, long long b) { return (int)((a + b - 1) / b); }

typedef short short8 __attribute__((ext_vector_type(8)));
typedef short short4v __attribute__((ext_vector_type(4)));
typedef float f32x4 __attribute__((ext_vector_type(4)));

// ---------- small utils ----------
__device__ __forceinline__ float warpReduceSum(float v) {
#pragma unroll
    for (int m = 32; m; m >>= 1) v += __shfl_xor(v, m, 64);
    return v;
}
__device__ __forceinline__ int encf(float f) {
    int i = __float_as_int(f);
    return i >= 0 ? i : (i ^ 0x7fffffff);
}
__device__ __forceinline__ float decf(int i) {
    return __int_as_float(i >= 0 ? i : (i ^ 0x7fffffff));
}
// fp32 -> bf16 (RNE) scalar
__device__ __forceinline__ short f2bs(float x) {
    unsigned u = __float_as_uint(x);
    u += 0x7fffu + ((u >> 16) & 1u);
    return (short)(u >> 16);
}
// packed pair (v_cvt_pk_bf16_f32)
__device__ __forceinline__ short2 f2bs2(float a, float b) {
    union {
        __hip_bfloat162 h;
        short2 s;
    } u;
    u.h = __float22bfloat162_rn(make_float2(a, b));
    return u.s;
}
__device__ __forceinline__ float bs2f(short s) {
    return __uint_as_float(((unsigned)(unsigned short)s) << 16);
}

__global__ void fill_i32(int* p, int v, int n) {
    int i = blockIdx.x * 256 + threadIdx.x;
    if (i < n) p[i] = v;
}

// cat cols 0..255 pre-initialized with GAT1/GCN1 biases (scatters accumulate on top)
__global__ void init_cat(float* __restrict__ cat, const float* __restrict__ b1, const float* __restrict__ b2) {
    int i = blockIdx.x * 256 + threadIdx.x;  // over N*256
    int n = i >> 8, c = i & 255;
    float b = (c < 128) ? b1[c] : b2[c - 128];
    cat[(size_t)n * 512 + c] = b;
}

// pack all 4 conv kernels into W_all[512][2048] bf16 (row=(Kidx*125+oc), col=k*256+ic)
__global__ void repack_wall(const float* __restrict__ cw0, const float* __restrict__ cw1,
                            const float* __restrict__ cw2, const float* __restrict__ cw3,
                            __hip_bfloat16* __restrict__ wall) {
    int i = blockIdx.x * 256 + threadIdx.x;
    if (i >= 512 * 2048) return;
    int r = i >> 11, c = i & 2047;
    int k = c >> 8, ic = c & 255;
    float v = 0.f;
    if (r < 500) {
        int Kidx = r / 125, oc = r - Kidx * 125;
        int K = 5 + Kidx;
        if (k < K) {
            const float* cw = Kidx == 0 ? cw0 : Kidx == 1 ? cw1 : Kidx == 2 ? cw2 : cw3;
            v = cw[((size_t)oc * 256 + ic) * K + k];
        }
    }
    wall[i] = __float2bfloat16(v);
}

// transformer weights: wqkvT[768][256] bf16, woT[256][256], bqkv[768]
__global__ void repack_xf(const float* __restrict__ Wq, const float* __restrict__ Wk, const float* __restrict__ Wv,
                          const float* __restrict__ Wo, const float* __restrict__ bq, const float* __restrict__ bk,
                          const float* __restrict__ bv, short* __restrict__ wqkvT, short* __restrict__ woT,
                          float* __restrict__ bqkv) {
    int i = blockIdx.x * 256 + threadIdx.x;
    if (i < 768 * 256) {
        int n = i >> 8, k = i & 255;
        const float* W = n < 256 ? Wq : n < 512 ? Wk : Wv;
        wqkvT[i] = f2bs(W[k * 256 + (n & 255)]);
    }
    if (i < 256 * 256) {
        int n = i >> 8, k = i & 255;
        woT[i] = f2bs(Wo[k * 256 + n]);
    }
    if (i < 768) bqkv[i] = i < 256 ? bq[i] : i < 512 ? bk[i - 256] : bv[i - 512];
}

// generic W[K][N] fp32 -> Wt[N][K] bf16
__global__ void repack_wT(const float* __restrict__ W, short* __restrict__ out, int K, int N) {
    int i = blockIdx.x * 256 + threadIdx.x;
    if (i >= K * N) return;
    int n = i / K, k = i - n * K;
    out[i] = f2bs(W[(size_t)k * N + n]);
}

// ---------- MFMA GEMM: C[M,128] = A[M,K]fp32 @ Wt[128,K]bf16^T ; M mult of 128, K mult of 32 ----------
__global__ __launch_bounds__(256) void mfma_gemm_n128(const float* __restrict__ A, const short* __restrict__ Wt,
                                                      float* __restrict__ C, int K) {
    __shared__ short As[128 * 40];
    __shared__ short Bs[128 * 40];
    const int m0 = blockIdx.x * 128;
    const int tid = threadIdx.x;
    const int lane = tid & 63;
    const int wave = tid >> 6;
    const int wm = (wave >> 1) * 64, wn = (wave & 1) * 64;
    const int quad = lane >> 4, l16 = lane & 15;

    const int r0 = tid >> 2, kc = (tid & 3) * 8;
    const int r1 = r0 + 64;

    f32x4 acc[4][4];
#pragma unroll
    for (int i = 0; i < 4; i++)
#pragma unroll
        for (int j = 0; j < 4; j++) acc[i][j] = (f32x4){0.f, 0.f, 0.f, 0.f};

    for (int k0 = 0; k0 < K; k0 += 32) {
        // stage A (fp32 -> bf16)
#pragma unroll
        for (int rr = 0; rr < 2; rr++) {
            const int r = rr ? r1 : r0;
            const float* pa = A + (size_t)(m0 + r) * K + k0 + kc;
            float4 a0 = ((const float4*)pa)[0], a1 = ((const float4*)pa)[1];
            short2 c0 = f2bs2(a0.x, a0.y), c1 = f2bs2(a0.z, a0.w), c2 = f2bs2(a1.x, a1.y), c3 = f2bs2(a1.z, a1.w);
            *(short8*)(As + r * 40 + kc) = (short8){c0.x, c0.y, c1.x, c1.y, c2.x, c2.y, c3.x, c3.y};
        }
        // stage B (bf16 rows of Wt)
        *(short8*)(Bs + r0 * 40 + kc) = *(const short8*)(Wt + (size_t)r0 * K + k0 + kc);
        *(short8*)(Bs + r1 * 40 + kc) = *(const short8*)(Wt + (size_t)r1 * K + k0 + kc);
        __syncthreads();
        short8 af[4], bfr[4];
#pragma unroll
        for (int i = 0; i < 4; i++) af[i] = *(const short8*)(As + (wm + i * 16 + l16) * 40 + quad * 8);
#pragma unroll
        for (int j = 0; j < 4; j++) bfr[j] = *(const short8*)(Bs + (wn + j * 16 + l16) * 40 + quad * 8);
#pragma unroll
        for (int i = 0; i < 4; i++)
#pragma unroll
            for (int j = 0; j < 4; j++)
                acc[i][j] = __builtin_amdgcn_mfma_f32_16x16x32_bf16(af[i], bfr[j], acc[i][j], 0, 0, 0);
        __syncthreads();
    }
#pragma unroll
    for (int i = 0; i < 4; i++) {
#pragma unroll
        for (int j = 0; j < 4; j++) {
            const int col = wn + j * 16 + l16;
            const size_t base = (size_t)(m0 + wm + i * 16 + quad * 4) * 128 + col;
#pragma unroll
            for (int r = 0; r < 4; r++) C[base + (size_t)r * 128] = acc[i][j][r];
        }
    }
}

// ---------- generic fp32 GEMM (head fc1 only) ----------
__global__ __launch_bounds__(256) void gemm64(const float* __restrict__ A, const float* __restrict__ B,
                                              const float* __restrict__ bias, float* __restrict__ C,
                                              int M, int N, int K, int lda, int ldc, int doRelu) {
    __shared__ float As[16][65];
    __shared__ float Bs[16][65];
    const int bm = blockIdx.y * 64, bn = blockIdx.x * 64;
    const int tid = threadIdx.x;
    const int tx = tid & 15, ty = tid >> 4;
    float acc[4][4] = {};
    for (int k0 = 0; k0 < K; k0 += 16) {
#pragma unroll
        for (int j = 0; j < 4; j++) {
            int i = tid + j * 256;
            int kk = i & 15, m = i >> 4;
            int gr = bm + m, gc = k0 + kk;
            As[kk][m] = (gr < M && gc < K) ? A[(size_t)gr * lda + gc] : 0.f;
        }
#pragma unroll
        for (int j = 0; j < 4; j++) {
            int i = tid + j * 256;
            int n = i & 63, kk = i >> 6;
            int gr = k0 + kk, gc = bn + n;
            Bs[kk][n] = (gr < K && gc < N) ? B[(size_t)gr * N + gc] : 0.f;
        }
        __syncthreads();
#pragma unroll
        for (int kk = 0; kk < 16; kk++) {
            float a[4], b[4];
#pragma unroll
            for (int i2 = 0; i2 < 4; i2++) a[i2] = As[kk][ty * 4 + i2];
#pragma unroll
            for (int j2 = 0; j2 < 4; j2++) b[j2] = Bs[kk][tx * 4 + j2];
#pragma unroll
            for (int i2 = 0; i2 < 4; i2++)
#pragma unroll
                for (int j2 = 0; j2 < 4; j2++) acc[i2][j2] = fmaf(a[i2], b[j2], acc[i2][j2]);
        }
        __syncthreads();
    }
#pragma unroll
    for (int i2 = 0; i2 < 4; i2++) {
        int r = bm + ty * 4 + i2;
        if (r >= M) continue;
#pragma unroll
        for (int j2 = 0; j2 < 4; j2++) {
            int c = bn + tx * 4 + j2;
            if (c >= N) continue;
            float v = acc[i2][j2];
            if (bias) v += bias[c];
            if (doRelu) v = fmaxf(v, 0.f);
            C[(size_t)r * ldc + c] = v;
        }
    }
}

// ---------- GAT alphas ----------
__global__ __launch_bounds__(256) void alpha_kernel(const float* __restrict__ h, const float* __restrict__ asrc,
                                                    const float* __restrict__ adst, float* __restrict__ als,
                                                    float* __restrict__ ald) {
    int gw = (blockIdx.x * 256 + threadIdx.x) >> 6;
    int lane = threadIdx.x & 63;
    if (gw >= N_NODES) return;
    const float* row = h + (size_t)gw * FEAT;
    float v0 = row[lane], v1 = row[lane + 64];
    float ps = v0 * asrc[lane] + v1 * asrc[lane + 64];
    float pd = v0 * adst[lane] + v1 * adst[lane + 64];
    ps = warpReduceSum(ps);
    pd = warpReduceSum(pd);
    if (lane == 0) {
        als[gw] = ps;
        ald[gw] = pd;
    }
}

// ---------- edge passes ----------
__device__ __forceinline__ void edge_decode(int i, const int* __restrict__ ei, int& s, int& d) {
    if (i < N_EDGES) {
        s = ei[i];
        d = ei[N_EDGES + i];
    } else {
        s = d = i - N_EDGES;
    }
}

__global__ void edge_p1(const int* __restrict__ ei, const float* __restrict__ als, const float* __restrict__ ald,
                        float* __restrict__ elog, int* __restrict__ menc, float* dega) {
    int i = blockIdx.x * 256 + threadIdx.x;
    if (i >= ET_EDGES) return;
    int s, d;
    edge_decode(i, ei, s, d);
    float e = als[s] + ald[d];
    e = (e >= 0.f) ? e : 0.2f * e;
    elog[i] = e;
    atomicMax(&menc[d], encf(e));
    if (dega) unsafeAtomicAdd(&dega[d], 1.f);
}

__global__ void edge_p2(const int* __restrict__ ei, float* __restrict__ elog, const int* __restrict__ menc,
                        float* __restrict__ den) {
    int i = blockIdx.x * 256 + threadIdx.x;
    if (i >= ET_EDGES) return;
    int s, d;
    edge_decode(i, ei, s, d);
    float ex = __expf(elog[i] - decf(menc[d]));
    elog[i] = ex;
    unsafeAtomicAdd(&den[d], ex);
}

__global__ void edge_p2b(const int* __restrict__ ei, float* __restrict__ elog, const float* __restrict__ den) {
    int i = blockIdx.x * 256 + threadIdx.x;
    if (i >= ET_EDGES) return;
    int s, d;
    edge_decode(i, ei, s, d);
    elog[i] = elog[i] / den[d];
}

__global__ void dinv_kernel(float* deg) {
    int i = blockIdx.x * 256 + threadIdx.x;
    if (i < N_NODES) deg[i] = rsqrtf(fmaxf(deg[i], 1.f));
}

__global__ void edge_scatter(const int* __restrict__ ei, const float* __restrict__ coef, const float* __restrict__ h,
                             float* __restrict__ out, int ldo) {
    int i = blockIdx.x * 256 + threadIdx.x;
    if (i >= ET_EDGES * FEAT) return;
    int e = i >> 7, f = i & 127;
    int s, d;
    edge_decode(e, ei, s, d);
    unsafeAtomicAdd(&out[(size_t)d * ldo + f], coef[e] * h[(size_t)s * FEAT + f]);
}

__global__ void gcn_scatter(const int* __restrict__ ei, const float* __restrict__ dinv, const float* __restrict__ h,
                            float* __restrict__ out, int ldo) {
    int i = blockIdx.x * 256 + threadIdx.x;
    if (i >= ET_EDGES * FEAT) return;
    int e = i >> 7, f = i & 127;
    int s, d;
    edge_decode(e, ei, s, d);
    float coef = dinv[s] * dinv[d];
    unsafeAtomicAdd(&out[(size_t)d * ldo + f], coef * h[(size_t)s * FEAT + f]);
}

__global__ void root_gather(const float* __restrict__ g2, const int* __restrict__ rooti, const float* __restrict__ gb,
                            float* __restrict__ fin) {
    int i = blockIdx.x * 256 + threadIdx.x;
    if (i >= N_ROOTS * FEAT) return;
    int r = i >> 7, c = i & 127;
    fin[(size_t)r * 1128 + c] = g2[(size_t)rooti[r] * FEAT + c] + gb[c];
}

__global__ void fc2_kernel(const float* __restrict__ fch, const float* __restrict__ W, const float* __restrict__ b,
                           float* __restrict__ out) {
    int i = blockIdx.x * 256 + threadIdx.x;
    if (i >= N_ROOTS * 3) return;
    int r = i / 3, c = i - r * 3;
    float acc = b[c];
    for (int k = 0; k < 300; k++) acc = fmaf(fch[(size_t)r * 300 + k], W[k * 3 + c], acc);
    out[i] = acc;
}

// ================= MFMA transformer v4: LDS-routed P and V (no bpermute storm) =================
#define QA_STRIDE 264  // 132 dwords == 4 mod 32 -> 2-way on frag reads (free)
#define KR_STRIDE 264

// vT overlay layout inside kreg: addr(shorts) = d*32 + swizzled key (XOR on 8-blocks)
__device__ __forceinline__ int vt_addr(int d, int key) {
    return d * 32 + (((key & 24) ^ (((d ^ (d >> 2)) & 3) << 3)) | (key & 7));
}

template <int MODE>
__global__ __launch_bounds__(256, 4) void xformer_kernel(
    const float* __restrict__ emb, const int* __restrict__ text2, const short* __restrict__ wqkvT,
    const float* __restrict__ bqkv, const short* __restrict__ woT, const float* __restrict__ bo,
    const float* __restrict__ lng, const float* __restrict__ lnb, const int* __restrict__ rooti,
    const int* __restrict__ rpi, float* __restrict__ cat, unsigned short* __restrict__ tbuf) {
    __shared__ short qa[32 * QA_STRIDE];    // Q -> P-scratch -> attn-out -> fp32 LN scratch
    __shared__ short kreg[32 * KR_STRIDE];  // K -> vT overlay -> y (post O-proj)
    // total LDS 33792 B -> 4 blocks/CU

    const int tid = threadIdx.x;
    const int wave = tid >> 6, lane = tid & 63;
    const int quad = lane >> 4, l16 = lane & 15;

    int gnode[2];
#pragma unroll
    for (int m = 0; m < 2; m++) {
        int slot = blockIdx.x * 2 + m;
        gnode[m] = (MODE == 0) ? slot : ((slot < N_ROOTS) ? rooti[slot] : rpi[slot - N_ROOTS]);
    }
    const int tokA0 = text2[gnode[0] * SEQ + l16];
    const int tokA1 = text2[gnode[1] * SEQ + l16];

    // ---- Preload A fragments (both nodes, 8 k-chunks) ----
    short8 Areg[2][8];
#pragma unroll
    for (int k0 = 0; k0 < 8; k0++) {
        const float* pa0 = emb + (size_t)tokA0 * 256 + k0 * 32 + quad * 8;
        const float* pa1 = emb + (size_t)tokA1 * 256 + k0 * 32 + quad * 8;
        float4 a0l = ((const float4*)pa0)[0], a0h = ((const float4*)pa0)[1];
        float4 a1l = ((const float4*)pa1)[0], a1h = ((const float4*)pa1)[1];
        short2 c0 = f2bs2(a0l.x, a0l.y), c1 = f2bs2(a0l.z, a0l.w), c2 = f2bs2(a0h.x, a0h.y), c3 = f2bs2(a0h.z, a0h.w);
        Areg[0][k0] = (short8){c0.x, c0.y, c1.x, c1.y, c2.x, c2.y, c3.x, c3.y};
        c0 = f2bs2(a1l.x, a1l.y);
        c1 = f2bs2(a1l.z, a1l.w);
        c2 = f2bs2(a1h.x, a1h.y);
        c3 = f2bs2(a1h.z, a1h.w);
        Areg[1][k0] = (short8){c0.x, c0.y, c1.x, c1.y, c2.x, c2.y, c3.x, c3.y};
    }

    // V C-frags kept in registers until K is dead: vacc[i][m] for tile g=32+wave*4+i, node m
    f32x4 vacc[4][2];

    // ---- Phase 1: QKV, 3 passes (q scaled 1/4 -> qa | k -> kreg | v -> registers) ----
#pragma unroll
    for (int grp = 0; grp < 3; grp++) {
        f32x4 acc[4][2];
#pragma unroll
        for (int i = 0; i < 4; i++) {
            acc[i][0] = (f32x4){0.f, 0.f, 0.f, 0.f};
            acc[i][1] = (f32x4){0.f, 0.f, 0.f, 0.f};
        }
#pragma unroll
        for (int k0 = 0; k0 < 8; k0++) {
#pragma unroll
            for (int i = 0; i < 4; i++) {
                const int g = grp * 16 + wave * 4 + i;
                short8 B = *(const short8*)(wqkvT + (size_t)(g * 16 + l16) * 256 + k0 * 32 + quad * 8);
                acc[i][0] = __builtin_amdgcn_mfma_f32_16x16x32_bf16(Areg[0][k0], B, acc[i][0], 0, 0, 0);
                acc[i][1] = __builtin_amdgcn_mfma_f32_16x16x32_bf16(Areg[1][k0], B, acc[i][1], 0, 0, 0);
            }
        }
#pragma unroll
        for (int i = 0; i < 4; i++) {
            const int g = grp * 16 + wave * 4 + i;
            const int col = g * 16 + l16;  // 0..767
            const float b = bqkv[col];
            if (grp == 2) {
#pragma unroll
                for (int m = 0; m < 2; m++) {
                    vacc[i][m][0] = acc[i][m][0] + b;
                    vacc[i][m][1] = acc[i][m][1] + b;
                    vacc[i][m][2] = acc[i][m][2] + b;
                    vacc[i][m][3] = acc[i][m][3] + b;
                }
            } else {
#pragma unroll
                for (int m = 0; m < 2; m++) {
                    const int rbase = m * 16 + quad * 4;
                    float v0 = acc[i][m][0] + b, v1 = acc[i][m][1] + b;
                    float v2 = acc[i][m][2] + b, v3 = acc[i][m][3] + b;
                    if (grp == 0) {
                        v0 *= 0.25f;
                        v1 *= 0.25f;
                        v2 *= 0.25f;
                        v3 *= 0.25f;
                    }
                    short2 p01 = f2bs2(v0, v1), p23 = f2bs2(v2, v3);
                    short* dst = (grp == 0) ? (qa + rbase * QA_STRIDE + col) : (kreg + rbase * KR_STRIDE + (col - 256));
                    const int str = (grp == 0) ? QA_STRIDE : KR_STRIDE;
                    dst[0 * str] = p01.x;
                    dst[1 * str] = p01.y;
                    dst[2 * str] = p23.x;
                    dst[3 * str] = p23.y;
                }
            }
        }
    }
    // q/k for heads wave*4..+3 are wave-local: no barrier before S.

    // ---- Phase 2a: S = K·Q^T per (node, head); softmax per column; P -> qa scratch ----
#pragma unroll
    for (int p = 0; p < 2; p++) {
#pragma unroll
        for (int i = 0; i < 4; i++) {
            const int h = wave * 4 + i;
            const int arow = p * 16 + l16;
            const int q8 = (quad & 1) * 8;
            short8 Af = *(const short8*)(kreg + arow * KR_STRIDE + h * 16 + q8);
            short8 Bf = *(const short8*)(qa + arow * QA_STRIDE + h * 16 + q8);
            if (quad >= 2) {
                Af = (short8){0, 0, 0, 0, 0, 0, 0, 0};
                Bf = (short8){0, 0, 0, 0, 0, 0, 0, 0};
            }
            f32x4 S = __builtin_amdgcn_mfma_f32_16x16x32_bf16(Af, Bf, (f32x4){0.f, 0.f, 0.f, 0.f}, 0, 0, 0);
            // S^T[key=quad*4+r][q=l16]; softmax over keys per column q
            float mx = fmaxf(fmaxf(S[0], S[1]), fmaxf(S[2], S[3]));
            mx = fmaxf(mx, __shfl_xor(mx, 16));
            mx = fmaxf(mx, __shfl_xor(mx, 32));
            float e0 = __expf(S[0] - mx), e1 = __expf(S[1] - mx);
            float e2 = __expf(S[2] - mx), e3 = __expf(S[3] - mx);
            float sm = (e0 + e1) + (e2 + e3);
            sm += __shfl_xor(sm, 16);
            sm += __shfl_xor(sm, 32);
            const float inv = 1.f / sm;
            // P-scratch: Pb[q=l16][key=quad*4..+3] into the (future O) slot of qa (b64)
            short2 p01 = f2bs2(e0 * inv, e1 * inv), p23 = f2bs2(e2 * inv, e3 * inv);
            *(short4v*)(qa + arow * QA_STRIDE + h * 16 + quad * 4) = (short4v){p01.x, p01.y, p23.x, p23.y};
        }
    }
    __syncthreads();  // all waves done with K -> kreg region reusable as vT

    // ---- Phase 2b: write V^T into vT overlay (wave-local rows d = wave*64..+63) ----
#pragma unroll
    for (int i = 0; i < 4; i++) {
        const int d = (wave * 4 + i) * 16 + l16;
#pragma unroll
        for (int m = 0; m < 2; m++) {
            const int rbase = m * 16 + quad * 4;
            short2 p01 = f2bs2(vacc[i][m][0], vacc[i][m][1]), p23 = f2bs2(vacc[i][m][2], vacc[i][m][3]);
            *(short4v*)(kreg + vt_addr(d, rbase)) = (short4v){p01.x, p01.y, p23.x, p23.y};
        }
    }

    // ---- Phase 2c: O^T = V^T · P  (A from vT, B from P-scratch); O overwrites P-scratch ----
#pragma unroll
    for (int p = 0; p < 2; p++) {
#pragma unroll
        for (int i = 0; i < 4; i++) {
            const int h = wave * 4 + i;
            const int arow = p * 16 + l16;
            const int q8 = (quad & 1) * 8;
            short8 BP = *(const short8*)(qa + arow * QA_STRIDE + h * 16 + q8);
            short8 Av = *(const short8*)(kreg + vt_addr(h * 16 + l16, p * 16 + q8));
            if (quad >= 2) {
                BP = (short8){0, 0, 0, 0, 0, 0, 0, 0};
                Av = (short8){0, 0, 0, 0, 0, 0, 0, 0};
            }
            f32x4 O = __builtin_amdgcn_mfma_f32_16x16x32_bf16(Av, BP, (f32x4){0.f, 0.f, 0.f, 0.f}, 0, 0, 0);
            short2 o01 = f2bs2(O[0], O[1]), o23 = f2bs2(O[2], O[3]);
            *(short4v*)(qa + arow * QA_STRIDE + h * 16 + quad * 4) = (short4v){o01.x, o01.y, o23.x, o23.y};
        }
    }
    __syncthreads();  // attn-out crosses waves for O-proj A-frags

    // ---- Phase 3: O-proj (+bo) -> y into kreg cols 0..255 ----
    {
        short8 Afr[2][8];
#pragma unroll
        for (int m = 0; m < 2; m++)
#pragma unroll
            for (int k0 = 0; k0 < 8; k0++)
                Afr[m][k0] = *(const short8*)(qa + (m * 16 + l16) * QA_STRIDE + k0 * 32 + quad * 8);
#pragma unroll
        for (int i = 0; i < 4; i++) {
            const int g = wave * 4 + i;
            f32x4 oa0 = (f32x4){0.f, 0.f, 0.f, 0.f}, oa1 = (f32x4){0.f, 0.f, 0.f, 0.f};
#pragma unroll
            for (int k0 = 0; k0 < 8; k0++) {
                short8 B = *(const short8*)(woT + (size_t)(g * 16 + l16) * 256 + k0 * 32 + quad * 8);
                oa0 = __builtin_amdgcn_mfma_f32_16x16x32_bf16(Afr[0][k0], B, oa0, 0, 0, 0);
                oa1 = __builtin_amdgcn_mfma_f32_16x16x32_bf16(Afr[1][k0], B, oa1, 0, 0, 0);
            }
            const int col = g * 16 + l16;
            const float bocol = bo[col];
            short2 a01 = f2bs2(oa0[0] + bocol, oa0[1] + bocol), a23 = f2bs2(oa0[2] + bocol, oa0[3] + bocol);
            short2 c01 = f2bs2(oa1[0] + bocol, oa1[1] + bocol), c23 = f2bs2(oa1[2] + bocol, oa1[3] + bocol);
            kreg[(quad * 4 + 0) * KR_STRIDE + col] = a01.x;
            kreg[(quad * 4 + 1) * KR_STRIDE + col] = a01.y;
            kreg[(quad * 4 + 2) * KR_STRIDE + col] = a23.x;
            kreg[(quad * 4 + 3) * KR_STRIDE + col] = a23.y;
            kreg[(16 + quad * 4 + 0) * KR_STRIDE + col] = c01.x;
            kreg[(16 + quad * 4 + 1) * KR_STRIDE + col] = c01.y;
            kreg[(16 + quad * 4 + 2) * KR_STRIDE + col] = c23.x;
            kreg[(16 + quad * 4 + 3) * KR_STRIDE + col] = c23.y;
        }
    }
    __syncthreads();

    // ---- Phase 4: residual + LayerNorm ----
    float* qs = (float*)qa;  // qa dead
    {
        const int row = tid >> 3, seg = tid & 7;
        const int m = row >> 4, r = row & 15;
        const int tokr = text2[gnode[m] * SEQ + r];
        const float* ep = emb + (size_t)tokr * 256 + seg * 32;
        float sum = 0.f, sq = 0.f;
#pragma unroll
        for (int j = 0; j < 4; j++) {
            short8 y8 = *(const short8*)(kreg + row * KR_STRIDE + seg * 32 + j * 8);
            float4 ea = ((const float4*)(ep + j * 8))[0];
            float4 eb = ((const float4*)(ep + j * 8))[1];
            float ev[8] = {ea.x, ea.y, ea.z, ea.w, eb.x, eb.y, eb.z, eb.w};
            float yv[8];
#pragma unroll
            for (int e = 0; e < 8; e++) {
                yv[e] = bs2f(y8[e]) + ev[e];
                sum += yv[e];
                sq = fmaf(yv[e], yv[e], sq);
            }
            short2 w0 = f2bs2(yv[0], yv[1]), w1 = f2bs2(yv[2], yv[3]);
            short2 w2 = f2bs2(yv[4], yv[5]), w3 = f2bs2(yv[6], yv[7]);
            *(short4v*)(kreg + row * KR_STRIDE + seg * 32 + j * 8) = (short4v){w0.x, w0.y, w1.x, w1.y};
            *(short4v*)(kreg + row * KR_STRIDE + seg * 32 + j * 8 + 4) = (short4v){w2.x, w2.y, w3.x, w3.y};
        }
        qs[tid] = sum;
        qs[256 + tid] = sq;
    }
    __syncthreads();
    if (tid < 32) {
        float s = 0.f, q2 = 0.f;
#pragma unroll
        for (int j = 0; j < 8; j++) {
            s += qs[tid * 8 + j];
            q2 += qs[256 + tid * 8 + j];
        }
        float mu = s * (1.f / 256.f);
        float var = q2 * (1.f / 256.f) - mu * mu;
        qs[512 + tid * 2] = mu;
        qs[512 + tid * 2 + 1] = rsqrtf(var + 1e-5f);
    }
    __syncthreads();
    {
        const int c = tid;
        const float g = lng[c], bb = lnb[c];
        float csum[2] = {0.f, 0.f};
#pragma unroll
        for (int m = 0; m < 2; m++) {
#pragma unroll
            for (int r = 0; r < 16; r++) {
                const int row = m * 16 + r;
                const float yv = bs2f(kreg[row * KR_STRIDE + c]);
                const float mu = qs[512 + row * 2], rstd = qs[512 + row * 2 + 1];
                const float o = (yv - mu) * rstd * g + bb;
                if (MODE == 0) {
                    csum[m] += o;
                } else {
                    tbuf[((size_t)(blockIdx.x * 2 + m) * 24 + r) * 256 + c] = (unsigned short)f2bs(o);
                }
            }
        }
        if (MODE == 0) {
            cat[(size_t)gnode[0] * 512 + 256 + c] = csum[0] * (1.f / 16.f);
            cat[(size_t)gnode[1] * 512 + 256 + c] = csum[1] * (1.f / 16.f);
        } else {
            for (int z = tid; z < 2 * 8 * 256; z += 256) {
                const int m = z >> 11, rem = z & 2047;
                tbuf[((size_t)(blockIdx.x * 2 + m) * 24 + 16 + (rem >> 8)) * 256 + (rem & 255)] = 0;
            }
        }
    }
}

// conv GEMM (proven): C[24576,512] = im2col(tbuf) @ W_all^T
__global__ __launch_bounds__(256) void conv_gemm(const short* __restrict__ tb, const short* __restrict__ wall,
                                                 float* __restrict__ C) {
    __shared__ short As[128 * 40];
    __shared__ short Bs[128 * 40];
    const int bid = blockIdx.x;
    const int m0 = (bid >> 2) * 128;
    const int n0 = (bid & 3) * 128;
    const int tid = threadIdx.x;
    const int lane = tid & 63;
    const int wave = tid >> 6;
    const int wm = (wave >> 1) * 64, wn = (wave & 1) * 64;
    const int quad = lane >> 4, l16 = lane & 15;

    const int r0 = tid >> 2, kc = (tid & 3) * 8;
    const int r1 = r0 + 64;
    const int am0 = m0 + r0, am1 = m0 + r1;
    const int s0 = am0 / 12, p0_ = am0 - s0 * 12;
    const int s1 = am1 / 12, p1_ = am1 - s1 * 12;
    const size_t ga0 = (size_t)(s0 * 24 + p0_) * 256 + kc;
    const size_t ga1 = (size_t)(s1 * 24 + p1_) * 256 + kc;
    const size_t gb0 = (size_t)(n0 + r0) * 2048 + kc;
    const size_t gb1 = (size_t)(n0 + r1) * 2048 + kc;
    short* sa0 = As + r0 * 40 + kc;
    short* sa1 = As + r1 * 40 + kc;
    short* sb0 = Bs + r0 * 40 + kc;
    short* sb1 = Bs + r1 * 40 + kc;

    f32x4 acc[4][4];
#pragma unroll
    for (int i = 0; i < 4; i++)
#pragma unroll
        for (int j = 0; j < 4; j++) acc[i][j] = (f32x4){0.f, 0.f, 0.f, 0.f};

    for (int k0 = 0; k0 < 2048; k0 += 32) {
        short8 a0 = *(const short8*)(tb + ga0 + k0);
        short8 a1 = *(const short8*)(tb + ga1 + k0);
        short8 b0 = *(const short8*)(wall + gb0 + k0);
        short8 b1 = *(const short8*)(wall + gb1 + k0);
        *(short8*)sa0 = a0;
        *(short8*)sa1 = a1;
        *(short8*)sb0 = b0;
        *(short8*)sb1 = b1;
        __syncthreads();
        short8 af[4], bfr[4];
#pragma unroll
        for (int i = 0; i < 4; i++) af[i] = *(const short8*)(As + (wm + i * 16 + l16) * 40 + quad * 8);
#pragma unroll
        for (int j = 0; j < 4; j++) bfr[j] = *(const short8*)(Bs + (wn + j * 16 + l16) * 40 + quad * 8);
#pragma unroll
        for (int i = 0; i < 4; i++)
#pragma unroll
            for (int j = 0; j < 4; j++)
                acc[i][j] = __builtin_amdgcn_mfma_f32_16x16x32_bf16(af[i], bfr[j], acc[i][j], 0, 0, 0);
        __syncthreads();
    }
#pragma unroll
    for (int i = 0; i < 4; i++) {
#pragma unroll
        for (int j = 0; j < 4; j++) {
            const int col = n0 + wn + j * 16 + l16;
            const size_t base = (size_t)(m0 + wm + i * 16 + quad * 4) * 512 + col;
#pragma unroll
            for (int r = 0; r < 4; r++) C[base + (size_t)r * 512] = acc[i][j][r];
        }
    }
}

__global__ void conv_maxpool(const float* __restrict__ C, const float* __restrict__ cb0, const float* __restrict__ cb1,
                             const float* __restrict__ cb2, const float* __restrict__ cb3, float* __restrict__ fin) {
    int i = blockIdx.x * 256 + threadIdx.x;
    if (i >= 2048 * 500) return;
    int slot = i / 500, q = i - slot * 500;
    int Kidx = q / 125, oc = q - Kidx * 125;
    int L = 12 - Kidx;
    const float* base = C + (size_t)(slot * 12) * 512 + q;
    float m = base[0];
    for (int p = 1; p < L; p++) m = fmaxf(m, base[(size_t)p * 512]);
    float b = (Kidx == 0 ? cb0 : Kidx == 1 ? cb1 : Kidx == 2 ? cb2 : cb3)[oc];
    float v = fmaxf(m + b, 0.f);
    int idx = slot < N_ROOTS ? slot : slot - N_ROOTS;
    int colbase = slot < N_ROOTS ? 128 : 628;
    fin[(size_t)idx * 1128 + colbase + q] = v;
}

// ---------- host launch ----------
extern "C" void kernel_launch(void* const* d_in, const int* in_sizes, int n_in, void* d_out, int out_size, void* d_ws,
                              size_t ws_size, hipStream_t stream) {
    const float* x2 = (const float*)d_in[0];
    const float* emb = (const float*)d_in[1];
    const float* Wq = (const float*)d_in[2];
    const float* Wk = (const float*)d_in[3];
    const float* Wv = (const float*)d_in[4];
    const float* Wo = (const float*)d_in[5];
    const float* bq = (const float*)d_in[6];
    const float* bk = (const float*)d_in[7];
    const float* bv = (const float*)d_in[8];
    const float* bo = (const float*)d_in[9];
    const float* lng = (const float*)d_in[10];
    const float* lnb = (const float*)d_in[11];
    const float* gat1_W = (const float*)d_in[12];
    const float* gat1_as = (const float*)d_in[13];
    const float* gat1_ad = (const float*)d_in[14];
    const float* gat1_b = (const float*)d_in[15];
    const float* gcn1_W = (const float*)d_in[16];
    const float* gcn1_b = (const float*)d_in[17];
    const float* gat2_W = (const float*)d_in[18];
    const float* gat2_as = (const float*)d_in[19];
    const float* gat2_ad = (const float*)d_in[20];
    const float* gat2_b = (const float*)d_in[21];
    // d_in[22]/[23] gcn2: dead code in reference forward
    const float* cw0 = (const float*)d_in[24];
    const float* cb0 = (const float*)d_in[25];
    const float* cw1 = (const float*)d_in[26];
    const float* cb1 = (const float*)d_in[27];
    const float* cw2 = (const float*)d_in[28];
    const float* cb2 = (const float*)d_in[29];
    const float* cw3 = (const float*)d_in[30];
    const float* cb3 = (const float*)d_in[31];
    const float* fc1_W = (const float*)d_in[32];
    const float* fc1_b = (const float*)d_in[33];
    const float* fc2_W = (const float*)d_in[34];
    const float* fc2_b = (const float*)d_in[35];
    const int* text2 = (const int*)d_in[36];
    const int* ei = (const int*)d_in[37];
    const int* rooti = (const int*)d_in[38];
    const int* rpi = (const int*)d_in[39];

    float* ws = (float*)d_ws;
    size_t off = 0;
    auto alloc = [&](size_t n) {
        float* p = ws + off;
        off += n;
        return p;
    };
    // zero block first (one small memset): g2o | den1 | den2 | deg
    float* g2o = alloc((size_t)N_NODES * FEAT);
    float* den1 = alloc(N_NODES);
    float* den2 = alloc(N_NODES);
    float* deg = alloc(N_NODES);
    size_t zero_floats = off;
    float* cat = alloc((size_t)N_NODES * 512);  // init_cat covers cols 0..255; xformer fills 256..511
    float* h1 = alloc((size_t)N_NODES * FEAT);  // h1+h2 reused as tbuf after scatters
    float* h2 = alloc((size_t)N_NODES * FEAT);
    float* hg2 = alloc((size_t)N_NODES * FEAT);
    float* als1 = alloc(N_NODES);
    float* ald1 = alloc(N_NODES);
    float* als2 = alloc(N_NODES);
    float* ald2 = alloc(N_NODES);
    int* m1 = (int*)alloc(N_NODES);
    int* m2 = (int*)alloc(N_NODES);
    float* el1 = alloc(ET_EDGES);
    float* el2 = alloc(ET_EDGES);
    float* fin = alloc((size_t)N_ROOTS * 1128);
    float* fch = alloc((size_t)N_ROOTS * 300);
    float* wallf = alloc(512 * 2048 / 2);
    float* wqkvTf = alloc(768 * 256 / 2);
    float* woTf = alloc(256 * 256 / 2);
    float* bqkv = alloc(768);
    float* wg1Tf = alloc(128 * 128 / 2);
    float* wc1Tf = alloc(128 * 128 / 2);
    float* wg2Tf = alloc(128 * 512 / 2);
    (void)ws_size;
    (void)in_sizes;
    (void)n_in;
    (void)out_size;

    unsigned short* tbuf = (unsigned short*)h1;  // 2048*24*256 bf16 fits in h1+h2
    __hip_bfloat16* wall = (__hip_bfloat16*)wallf;
    short* wqkvT = (short*)wqkvTf;
    short* woT = (short*)woTf;
    short* wg1T = (short*)wg1Tf;
    short* wc1T = (short*)wc1Tf;
    short* wg2T = (short*)wg2Tf;
    float* Cbuf = cat;

    hipMemsetAsync(g2o, 0, zero_floats * sizeof(float), stream);
    init_cat<<<cdiv((long long)N_NODES * 256, 256), 256, 0, stream>>>(cat, gat1_b, gcn1_b);
    fill_i32<<<cdiv(2 * N_NODES, 256), 256, 0, stream>>>(m1, (int)0x80000000, 2 * N_NODES);
    repack_wall<<<cdiv(512 * 2048, 256), 256, 0, stream>>>(cw0, cw1, cw2, cw3, wall);
    repack_xf<<<cdiv(768 * 256, 256), 256, 0, stream>>>(Wq, Wk, Wv, Wo, bq, bk, bv, wqkvT, woT, bqkv);
    repack_wT<<<cdiv(128 * 128, 256), 256, 0, stream>>>(gat1_W, wg1T, 128, 128);
    repack_wT<<<cdiv(128 * 128, 256), 256, 0, stream>>>(gcn1_W, wc1T, 128, 128);
    repack_wT<<<cdiv(512 * 128, 256), 256, 0, stream>>>(gat2_W, wg2T, 512, 128);

    // GAT1 / GCN1 node transforms (MFMA)
    mfma_gemm_n128<<<N_NODES / 128, 256, 0, stream>>>(x2, wg1T, h1, 128);
    mfma_gemm_n128<<<N_NODES / 128, 256, 0, stream>>>(x2, wc1T, h2, 128);
    alpha_kernel<<<cdiv((long long)N_NODES * 64, 256), 256, 0, stream>>>(h1, gat1_as, gat1_ad, als1, ald1);
    edge_p1<<<cdiv(ET_EDGES, 256), 256, 0, stream>>>(ei, als1, ald1, el1, m1, deg);
    edge_p2<<<cdiv(ET_EDGES, 256), 256, 0, stream>>>(ei, el1, m1, den1);
    edge_p2b<<<cdiv(ET_EDGES, 256), 256, 0, stream>>>(ei, el1, den1);
    dinv_kernel<<<cdiv(N_NODES, 256), 256, 0, stream>>>(deg);
    const int sc_blocks = cdiv((long long)ET_EDGES * FEAT, 256);
    edge_scatter<<<sc_blocks, 256, 0, stream>>>(ei, el1, h1, cat + 0, 512);
    gcn_scatter<<<sc_blocks, 256, 0, stream>>>(ei, deg, h2, cat + 128, 512);
    // transformer (MFMA): all nodes -> t_avg into cat[:,256:512]
    xformer_kernel<0><<<N_NODES / 2, 256, 0, stream>>>(emb, text2, wqkvT, bqkv, woT, bo, lng, lnb, rooti, rpi, cat,
                                                       nullptr);
    // transformer (MFMA): conv slots -> tbuf (h1/h2 dead after scatters)
    xformer_kernel<1><<<2 * N_ROOTS / 2, 256, 0, stream>>>(emb, text2, wqkvT, bqkv, woT, bo, lng, lnb, rooti, rpi,
                                                           nullptr, tbuf);
    // GAT2 (MFMA, K=512; cat rows are exactly K-contiguous)
    mfma_gemm_n128<<<N_NODES / 128, 256, 0, stream>>>(cat, wg2T, hg2, 512);
    alpha_kernel<<<cdiv((long long)N_NODES * 64, 256), 256, 0, stream>>>(hg2, gat2_as, gat2_ad, als2, ald2);
    edge_p1<<<cdiv(ET_EDGES, 256), 256, 0, stream>>>(ei, als2, ald2, el2, m2, nullptr);
    edge_p2<<<cdiv(ET_EDGES, 256), 256, 0, stream>>>(ei, el2, m2, den2);
    edge_p2b<<<cdiv(ET_EDGES, 256), 256, 0, stream>>>(ei, el2, den2);
    edge_scatter<<<sc_blocks, 256, 0, stream>>>(ei, el2, hg2, g2o, FEAT);
    // conv branch
    conv_gemm<<<192 * 4, 256, 0, stream>>>((const short*)tbuf, (const short*)wall, Cbuf);
    root_gather<<<cdiv(N_ROOTS * FEAT, 256), 256, 0, stream>>>(g2o, rooti, gat2_b, fin);
    conv_maxpool<<<cdiv(2048 * 500, 256), 256, 0, stream>>>(Cbuf, cb0, cb1, cb2, cb3, fin);
    // head
    gemm64<<<dim3(cdiv(300, 64), cdiv(N_ROOTS, 64)), 256, 0, stream>>>(fin, fc1_W, fc1_b, fch, N_ROOTS, 300, 1128,
                                                                       1128, 300, 1);
    fc2_kernel<<<cdiv(N_ROOTS * 3, 256), 256, 0, stream>>>(fch, fc2_W, fc2_b, (float*)d_out);
}

// Round 8
// 2100.182 us; speedup vs baseline: 7.9641x; 1.0397x over previous
//
#include <hip/hip_runtime.h>
#include <hip/hip_bf16.h>
#include <cstdint>
#include <cstddef>

#define N_NODES 32768
#define N_EDGES 131072
#define ET_EDGES (N_EDGES + N_NODES)
#define N_ROOTS 1024
#define EMB_D 256
#define FEAT 128
#define SEQ 16
#define OUT_CH 125

static inline int cdiv(long long a, long long b) { return (int)((a + b - 1) / b); }

typedef short short8 __attribute__((ext_vector_type(8)));
typedef short short4v __attribute__((ext_vector_type(4)));
typedef float f32x4 __attribute__((ext_vector_type(4)));

// ---------- small utils ----------
__device__ __forceinline__ float warpReduceSum(float v) {
#pragma unroll
    for (int m = 32; m; m >>= 1) v += __shfl_xor(v, m, 64);
    return v;
}
__device__ __forceinline__ int encf(float f) {
    int i = __float_as_int(f);
    return i >= 0 ? i : (i ^ 0x7fffffff);
}
__device__ __forceinline__ float decf(int i) {
    return __int_as_float(i >= 0 ? i : (i ^ 0x7fffffff));
}
// fp32 -> bf16 (RNE) scalar
__device__ __forceinline__ short f2bs(float x) {
    unsigned u = __float_as_uint(x);
    u += 0x7fffu + ((u >> 16) & 1u);
    return (short)(u >> 16);
}
// packed pair (v_cvt_pk_bf16_f32)
__device__ __forceinline__ short2 f2bs2(float a, float b) {
    union {
        __hip_bfloat162 h;
        short2 s;
    } u;
    u.h = __float22bfloat162_rn(make_float2(a, b));
    return u.s;
}
__device__ __forceinline__ float bs2f(short s) {
    return __uint_as_float(((unsigned)(unsigned short)s) << 16);
}

__global__ void fill_i32(int* p, int v, int n) {
    int i = blockIdx.x * 256 + threadIdx.x;
    if (i < n) p[i] = v;
}

// cat cols 0..255 pre-initialized with GAT1/GCN1 biases (scatters accumulate on top)
__global__ void init_cat(float* __restrict__ cat, const float* __restrict__ b1, const float* __restrict__ b2) {
    int i = blockIdx.x * 256 + threadIdx.x;  // over N*256
    int n = i >> 8, c = i & 255;
    float b = (c < 128) ? b1[c] : b2[c - 128];
    cat[(size_t)n * 512 + c] = b;
}

// pack all 4 conv kernels into W_all[512][2048] bf16 (row=(Kidx*125+oc), col=k*256+ic)
__global__ void repack_wall(const float* __restrict__ cw0, const float* __restrict__ cw1,
                            const float* __restrict__ cw2, const float* __restrict__ cw3,
                            __hip_bfloat16* __restrict__ wall) {
    int i = blockIdx.x * 256 + threadIdx.x;
    if (i >= 512 * 2048) return;
    int r = i >> 11, c = i & 2047;
    int k = c >> 8, ic = c & 255;
    float v = 0.f;
    if (r < 500) {
        int Kidx = r / 125, oc = r - Kidx * 125;
        int K = 5 + Kidx;
        if (k < K) {
            const float* cw = Kidx == 0 ? cw0 : Kidx == 1 ? cw1 : Kidx == 2 ? cw2 : cw3;
            v = cw[((size_t)oc * 256 + ic) * K + k];
        }
    }
    wall[i] = __float2bfloat16(v);
}

// transformer weights: wqkvT[768][256] bf16, woT[256][256], bqkv[768]
__global__ void repack_xf(const float* __restrict__ Wq, const float* __restrict__ Wk, const float* __restrict__ Wv,
                          const float* __restrict__ Wo, const float* __restrict__ bq, const float* __restrict__ bk,
                          const float* __restrict__ bv, short* __restrict__ wqkvT, short* __restrict__ woT,
                          float* __restrict__ bqkv) {
    int i = blockIdx.x * 256 + threadIdx.x;
    if (i < 768 * 256) {
        int n = i >> 8, k = i & 255;
        const float* W = n < 256 ? Wq : n < 512 ? Wk : Wv;
        wqkvT[i] = f2bs(W[k * 256 + (n & 255)]);
    }
    if (i < 256 * 256) {
        int n = i >> 8, k = i & 255;
        woT[i] = f2bs(Wo[k * 256 + n]);
    }
    if (i < 768) bqkv[i] = i < 256 ? bq[i] : i < 512 ? bk[i - 256] : bv[i - 512];
}

// generic W[K][N] fp32 -> Wt[N][K] bf16
__global__ void repack_wT(const float* __restrict__ W, short* __restrict__ out, int K, int N) {
    int i = blockIdx.x * 256 + threadIdx.x;
    if (i >= K * N) return;
    int n = i / K, k = i - n * K;
    out[i] = f2bs(W[(size_t)k * N + n]);
}

// ---------- MFMA GEMM: C[M,128] = A[M,K]fp32 @ Wt[128,K]bf16^T ; M mult of 128, K mult of 32 ----------
__global__ __launch_bounds__(256) void mfma_gemm_n128(const float* __restrict__ A, const short* __restrict__ Wt,
                                                      float* __restrict__ C, int K) {
    __shared__ short As[128 * 40];
    __shared__ short Bs[128 * 40];
    const int m0 = blockIdx.x * 128;
    const int tid = threadIdx.x;
    const int lane = tid & 63;
    const int wave = tid >> 6;
    const int wm = (wave >> 1) * 64, wn = (wave & 1) * 64;
    const int quad = lane >> 4, l16 = lane & 15;

    const int r0 = tid >> 2, kc = (tid & 3) * 8;
    const int r1 = r0 + 64;

    f32x4 acc[4][4];
#pragma unroll
    for (int i = 0; i < 4; i++)
#pragma unroll
        for (int j = 0; j < 4; j++) acc[i][j] = (f32x4){0.f, 0.f, 0.f, 0.f};

    for (int k0 = 0; k0 < K; k0 += 32) {
#pragma unroll
        for (int rr = 0; rr < 2; rr++) {
            const int r = rr ? r1 : r0;
            const float* pa = A + (size_t)(m0 + r) * K + k0 + kc;
            float4 a0 = ((const float4*)pa)[0], a1 = ((const float4*)pa)[1];
            short2 c0 = f2bs2(a0.x, a0.y), c1 = f2bs2(a0.z, a0.w), c2 = f2bs2(a1.x, a1.y), c3 = f2bs2(a1.z, a1.w);
            *(short8*)(As + r * 40 + kc) = (short8){c0.x, c0.y, c1.x, c1.y, c2.x, c2.y, c3.x, c3.y};
        }
        *(short8*)(Bs + r0 * 40 + kc) = *(const short8*)(Wt + (size_t)r0 * K + k0 + kc);
        *(short8*)(Bs + r1 * 40 + kc) = *(const short8*)(Wt + (size_t)r1 * K + k0 + kc);
        __syncthreads();
        short8 af[4], bfr[4];
#pragma unroll
        for (int i = 0; i < 4; i++) af[i] = *(const short8*)(As + (wm + i * 16 + l16) * 40 + quad * 8);
#pragma unroll
        for (int j = 0; j < 4; j++) bfr[j] = *(const short8*)(Bs + (wn + j * 16 + l16) * 40 + quad * 8);
#pragma unroll
        for (int i = 0; i < 4; i++)
#pragma unroll
            for (int j = 0; j < 4; j++)
                acc[i][j] = __builtin_amdgcn_mfma_f32_16x16x32_bf16(af[i], bfr[j], acc[i][j], 0, 0, 0);
        __syncthreads();
    }
#pragma unroll
    for (int i = 0; i < 4; i++) {
#pragma unroll
        for (int j = 0; j < 4; j++) {
            const int col = wn + j * 16 + l16;
            const size_t base = (size_t)(m0 + wm + i * 16 + quad * 4) * 128 + col;
#pragma unroll
            for (int r = 0; r < 4; r++) C[base + (size_t)r * 128] = acc[i][j][r];
        }
    }
}

// ---------- generic fp32 GEMM (head fc1 only) ----------
__global__ __launch_bounds__(256) void gemm64(const float* __restrict__ A, const float* __restrict__ B,
                                              const float* __restrict__ bias, float* __restrict__ C,
                                              int M, int N, int K, int lda, int ldc, int doRelu) {
    __shared__ float As[16][65];
    __shared__ float Bs[16][65];
    const int bm = blockIdx.y * 64, bn = blockIdx.x * 64;
    const int tid = threadIdx.x;
    const int tx = tid & 15, ty = tid >> 4;
    float acc[4][4] = {};
    for (int k0 = 0; k0 < K; k0 += 16) {
#pragma unroll
        for (int j = 0; j < 4; j++) {
            int i = tid + j * 256;
            int kk = i & 15, m = i >> 4;
            int gr = bm + m, gc = k0 + kk;
            As[kk][m] = (gr < M && gc < K) ? A[(size_t)gr * lda + gc] : 0.f;
        }
#pragma unroll
        for (int j = 0; j < 4; j++) {
            int i = tid + j * 256;
            int n = i & 63, kk = i >> 6;
            int gr = k0 + kk, gc = bn + n;
            Bs[kk][n] = (gr < K && gc < N) ? B[(size_t)gr * N + gc] : 0.f;
        }
        __syncthreads();
#pragma unroll
        for (int kk = 0; kk < 16; kk++) {
            float a[4], b[4];
#pragma unroll
            for (int i2 = 0; i2 < 4; i2++) a[i2] = As[kk][ty * 4 + i2];
#pragma unroll
            for (int j2 = 0; j2 < 4; j2++) b[j2] = Bs[kk][tx * 4 + j2];
#pragma unroll
            for (int i2 = 0; i2 < 4; i2++)
#pragma unroll
                for (int j2 = 0; j2 < 4; j2++) acc[i2][j2] = fmaf(a[i2], b[j2], acc[i2][j2]);
        }
        __syncthreads();
    }
#pragma unroll
    for (int i2 = 0; i2 < 4; i2++) {
        int r = bm + ty * 4 + i2;
        if (r >= M) continue;
#pragma unroll
        for (int j2 = 0; j2 < 4; j2++) {
            int c = bn + tx * 4 + j2;
            if (c >= N) continue;
            float v = acc[i2][j2];
            if (bias) v += bias[c];
            if (doRelu) v = fmaxf(v, 0.f);
            C[(size_t)r * ldc + c] = v;
        }
    }
}

// ---------- GAT alphas ----------
__global__ __launch_bounds__(256) void alpha_kernel(const float* __restrict__ h, const float* __restrict__ asrc,
                                                    const float* __restrict__ adst, float* __restrict__ als,
                                                    float* __restrict__ ald) {
    int gw = (blockIdx.x * 256 + threadIdx.x) >> 6;
    int lane = threadIdx.x & 63;
    if (gw >= N_NODES) return;
    const float* row = h + (size_t)gw * FEAT;
    float v0 = row[lane], v1 = row[lane + 64];
    float ps = v0 * asrc[lane] + v1 * asrc[lane + 64];
    float pd = v0 * adst[lane] + v1 * adst[lane + 64];
    ps = warpReduceSum(ps);
    pd = warpReduceSum(pd);
    if (lane == 0) {
        als[gw] = ps;
        ald[gw] = pd;
    }
}

// ---------- edge passes ----------
__device__ __forceinline__ void edge_decode(int i, const int* __restrict__ ei, int& s, int& d) {
    if (i < N_EDGES) {
        s = ei[i];
        d = ei[N_EDGES + i];
    } else {
        s = d = i - N_EDGES;
    }
}

__global__ void edge_p1(const int* __restrict__ ei, const float* __restrict__ als, const float* __restrict__ ald,
                        float* __restrict__ elog, int* __restrict__ menc, float* dega) {
    int i = blockIdx.x * 256 + threadIdx.x;
    if (i >= ET_EDGES) return;
    int s, d;
    edge_decode(i, ei, s, d);
    float e = als[s] + ald[d];
    e = (e >= 0.f) ? e : 0.2f * e;
    elog[i] = e;
    atomicMax(&menc[d], encf(e));
    if (dega) unsafeAtomicAdd(&dega[d], 1.f);
}

__global__ void edge_p2(const int* __restrict__ ei, float* __restrict__ elog, const int* __restrict__ menc,
                        float* __restrict__ den) {
    int i = blockIdx.x * 256 + threadIdx.x;
    if (i >= ET_EDGES) return;
    int s, d;
    edge_decode(i, ei, s, d);
    float ex = __expf(elog[i] - decf(menc[d]));
    elog[i] = ex;
    unsafeAtomicAdd(&den[d], ex);
}

__global__ void edge_p2b(const int* __restrict__ ei, float* __restrict__ elog, const float* __restrict__ den) {
    int i = blockIdx.x * 256 + threadIdx.x;
    if (i >= ET_EDGES) return;
    int s, d;
    edge_decode(i, ei, s, d);
    elog[i] = elog[i] / den[d];
}

__global__ void dinv_kernel(float* deg) {
    int i = blockIdx.x * 256 + threadIdx.x;
    if (i < N_NODES) deg[i] = rsqrtf(fmaxf(deg[i], 1.f));
}

__global__ void edge_scatter(const int* __restrict__ ei, const float* __restrict__ coef, const float* __restrict__ h,
                             float* __restrict__ out, int ldo) {
    int i = blockIdx.x * 256 + threadIdx.x;
    if (i >= ET_EDGES * FEAT) return;
    int e = i >> 7, f = i & 127;
    int s, d;
    edge_decode(e, ei, s, d);
    unsafeAtomicAdd(&out[(size_t)d * ldo + f], coef[e] * h[(size_t)s * FEAT + f]);
}

__global__ void gcn_scatter(const int* __restrict__ ei, const float* __restrict__ dinv, const float* __restrict__ h,
                            float* __restrict__ out, int ldo) {
    int i = blockIdx.x * 256 + threadIdx.x;
    if (i >= ET_EDGES * FEAT) return;
    int e = i >> 7, f = i & 127;
    int s, d;
    edge_decode(e, ei, s, d);
    float coef = dinv[s] * dinv[d];
    unsafeAtomicAdd(&out[(size_t)d * ldo + f], coef * h[(size_t)s * FEAT + f]);
}

__global__ void root_gather(const float* __restrict__ g2, const int* __restrict__ rooti, const float* __restrict__ gb,
                            float* __restrict__ fin) {
    int i = blockIdx.x * 256 + threadIdx.x;
    if (i >= N_ROOTS * FEAT) return;
    int r = i >> 7, c = i & 127;
    fin[(size_t)r * 1128 + c] = g2[(size_t)rooti[r] * FEAT + c] + gb[c];
}

__global__ void fc2_kernel(const float* __restrict__ fch, const float* __restrict__ W, const float* __restrict__ b,
                           float* __restrict__ out) {
    int i = blockIdx.x * 256 + threadIdx.x;
    if (i >= N_ROOTS * 3) return;
    int r = i / 3, c = i - r * 3;
    float acc = b[c];
    for (int k = 0; k < 300; k++) acc = fmaf(fch[(size_t)r * 300 + k], W[k * 3 + c], acc);
    out[i] = acc;
}

// ================= MFMA transformer v5: LDS A-tile + 2-deep B prefetch =================
#define QA_STRIDE 264
#define KR_STRIDE 264

// vT overlay layout inside kreg: addr(shorts) = d*32 + swizzled key (XOR on 8-blocks)
__device__ __forceinline__ int vt_addr(int d, int key) {
    return d * 32 + (((key & 24) ^ (((d ^ (d >> 2)) & 3) << 3)) | (key & 7));
}

template <int MODE>
__global__ __launch_bounds__(256, 4) void xformer_kernel(
    const float* __restrict__ emb, const int* __restrict__ text2, const short* __restrict__ wqkvT,
    const float* __restrict__ bqkv, const short* __restrict__ woT, const float* __restrict__ bo,
    const float* __restrict__ lng, const float* __restrict__ lnb, const int* __restrict__ rooti,
    const int* __restrict__ rpi, float* __restrict__ cat, unsigned short* __restrict__ tbuf) {
    __shared__ short qa[32 * QA_STRIDE];    // Q -> P-scratch -> attn-out -> fp32 LN scratch
    __shared__ short kreg[32 * KR_STRIDE];  // A-tile -> K -> vT overlay -> y
    // total LDS 33792 B -> 4 blocks/CU

    const int tid = threadIdx.x;
    const int wave = tid >> 6, lane = tid & 63;
    const int quad = lane >> 4, l16 = lane & 15;

    int gnode[2];
#pragma unroll
    for (int m = 0; m < 2; m++) {
        int slot = blockIdx.x * 2 + m;
        gnode[m] = (MODE == 0) ? slot : ((slot < N_ROOTS) ? rooti[slot] : rpi[slot - N_ROOTS]);
    }

    // ---- Stage A-tile (2 nodes x 16 rows x 256 cols, bf16) into kreg; one gather pass ----
    {
        const int row = tid >> 3, seg = tid & 7;  // row 0..31, seg 0..7 (32 cols each)
        const int m = row >> 4, r = row & 15;
        const int tok = text2[gnode[m] * SEQ + r];
        const float* ep = emb + (size_t)tok * 256 + seg * 32;
#pragma unroll
        for (int j = 0; j < 4; j++) {
            float4 ea = ((const float4*)(ep + j * 8))[0];
            float4 eb = ((const float4*)(ep + j * 8))[1];
            short2 w0 = f2bs2(ea.x, ea.y), w1 = f2bs2(ea.z, ea.w);
            short2 w2 = f2bs2(eb.x, eb.y), w3 = f2bs2(eb.z, eb.w);
            *(short8*)(kreg + row * KR_STRIDE + seg * 32 + j * 8) =
                (short8){w0.x, w0.y, w1.x, w1.y, w2.x, w2.y, w3.x, w3.y};
        }
    }
    __syncthreads();

    // GEMM pass: acc[i][m] += A(LDS) @ B(weights), B 2-deep prefetch. wrow0 = row of tile i=0.
    auto run_gemm = [&](const short* __restrict__ W, int wrow0, const short* __restrict__ Albase,
                        f32x4(&acc)[4][2]) {
#pragma unroll
        for (int i = 0; i < 4; i++) {
            acc[i][0] = (f32x4){0.f, 0.f, 0.f, 0.f};
            acc[i][1] = (f32x4){0.f, 0.f, 0.f, 0.f};
        }
        const short* wb = W + (size_t)(wrow0 + l16) * 256 + quad * 8;
        short8 Bcur[4], Bnxt[4];
#pragma unroll
        for (int i = 0; i < 4; i++) Bcur[i] = *(const short8*)(wb + (size_t)i * 16 * 256);
#pragma unroll
        for (int k0 = 0; k0 < 8; k0++) {
            if (k0 < 7) {
#pragma unroll
                for (int i = 0; i < 4; i++)
                    Bnxt[i] = *(const short8*)(wb + (size_t)i * 16 * 256 + (k0 + 1) * 32);
            }
            short8 A0 = *(const short8*)(Albase + l16 * KR_STRIDE + k0 * 32 + quad * 8);
            short8 A1 = *(const short8*)(Albase + (16 + l16) * KR_STRIDE + k0 * 32 + quad * 8);
#pragma unroll
            for (int i = 0; i < 4; i++) {
                acc[i][0] = __builtin_amdgcn_mfma_f32_16x16x32_bf16(A0, Bcur[i], acc[i][0], 0, 0, 0);
                acc[i][1] = __builtin_amdgcn_mfma_f32_16x16x32_bf16(A1, Bcur[i], acc[i][1], 0, 0, 0);
            }
#pragma unroll
            for (int i = 0; i < 4; i++) Bcur[i] = Bnxt[i];
        }
    };

    f32x4 vacc[4][2];
    // ---- Phase 1: Q (grp0) -> qa; V (grp2) -> regs; K (grp1) last -> kreg after barrier ----
    {
        f32x4 acc[4][2];
        run_gemm(wqkvT, (0 * 16 + wave * 4) * 16, kreg, acc);  // Q
#pragma unroll
        for (int i = 0; i < 4; i++) {
            const int col = (wave * 4 + i) * 16 + l16;
            const float b = bqkv[col];
#pragma unroll
            for (int m = 0; m < 2; m++) {
                const int rbase = m * 16 + quad * 4;
                short2 p01 = f2bs2((acc[i][m][0] + b) * 0.25f, (acc[i][m][1] + b) * 0.25f);
                short2 p23 = f2bs2((acc[i][m][2] + b) * 0.25f, (acc[i][m][3] + b) * 0.25f);
                qa[(rbase + 0) * QA_STRIDE + col] = p01.x;
                qa[(rbase + 1) * QA_STRIDE + col] = p01.y;
                qa[(rbase + 2) * QA_STRIDE + col] = p23.x;
                qa[(rbase + 3) * QA_STRIDE + col] = p23.y;
            }
        }
        run_gemm(wqkvT, (2 * 16 + wave * 4) * 16, kreg, vacc);  // V
#pragma unroll
        for (int i = 0; i < 4; i++) {
            const float b = bqkv[(2 * 16 + wave * 4 + i) * 16 + l16];
#pragma unroll
            for (int m = 0; m < 2; m++)
#pragma unroll
                for (int r = 0; r < 4; r++) vacc[i][m][r] += b;
        }
        f32x4 kacc[4][2];
        run_gemm(wqkvT, (1 * 16 + wave * 4) * 16, kreg, kacc);  // K (A-tile read complete after this)
        __syncthreads();                                        // all waves done reading A-tile
#pragma unroll
        for (int i = 0; i < 4; i++) {
            const int colg = (1 * 16 + wave * 4 + i) * 16 + l16;
            const float b = bqkv[colg];
            const int cl = colg - 256;
#pragma unroll
            for (int m = 0; m < 2; m++) {
                const int rbase = m * 16 + quad * 4;
                short2 p01 = f2bs2(kacc[i][m][0] + b, kacc[i][m][1] + b);
                short2 p23 = f2bs2(kacc[i][m][2] + b, kacc[i][m][3] + b);
                kreg[(rbase + 0) * KR_STRIDE + cl] = p01.x;
                kreg[(rbase + 1) * KR_STRIDE + cl] = p01.y;
                kreg[(rbase + 2) * KR_STRIDE + cl] = p23.x;
                kreg[(rbase + 3) * KR_STRIDE + cl] = p23.y;
            }
        }
    }
    // q/k for heads wave*4..+3 are wave-local: no barrier before S.

    // ---- Phase 2a: S = K·Q^T per (node, head); softmax per column; P -> qa scratch ----
#pragma unroll
    for (int p = 0; p < 2; p++) {
#pragma unroll
        for (int i = 0; i < 4; i++) {
            const int h = wave * 4 + i;
            const int arow = p * 16 + l16;
            const int q8 = (quad & 1) * 8;
            short8 Af = *(const short8*)(kreg + arow * KR_STRIDE + h * 16 + q8);
            short8 Bf = *(const short8*)(qa + arow * QA_STRIDE + h * 16 + q8);
            if (quad >= 2) {
                Af = (short8){0, 0, 0, 0, 0, 0, 0, 0};
                Bf = (short8){0, 0, 0, 0, 0, 0, 0, 0};
            }
            f32x4 S = __builtin_amdgcn_mfma_f32_16x16x32_bf16(Af, Bf, (f32x4){0.f, 0.f, 0.f, 0.f}, 0, 0, 0);
            float mx = fmaxf(fmaxf(S[0], S[1]), fmaxf(S[2], S[3]));
            mx = fmaxf(mx, __shfl_xor(mx, 16));
            mx = fmaxf(mx, __shfl_xor(mx, 32));
            float e0 = __expf(S[0] - mx), e1 = __expf(S[1] - mx);
            float e2 = __expf(S[2] - mx), e3 = __expf(S[3] - mx);
            float sm = (e0 + e1) + (e2 + e3);
            sm += __shfl_xor(sm, 16);
            sm += __shfl_xor(sm, 32);
            const float inv = 1.f / sm;
            short2 p01 = f2bs2(e0 * inv, e1 * inv), p23 = f2bs2(e2 * inv, e3 * inv);
            *(short4v*)(qa + arow * QA_STRIDE + h * 16 + quad * 4) = (short4v){p01.x, p01.y, p23.x, p23.y};
        }
    }
    __syncthreads();  // all waves done with K -> kreg region reusable as vT

    // ---- Phase 2b: write V^T into vT overlay (wave-local rows d = wave*64..+63) ----
#pragma unroll
    for (int i = 0; i < 4; i++) {
        const int d = (wave * 4 + i) * 16 + l16;
#pragma unroll
        for (int m = 0; m < 2; m++) {
            const int rbase = m * 16 + quad * 4;
            short2 p01 = f2bs2(vacc[i][m][0], vacc[i][m][1]), p23 = f2bs2(vacc[i][m][2], vacc[i][m][3]);
            *(short4v*)(kreg + vt_addr(d, rbase)) = (short4v){p01.x, p01.y, p23.x, p23.y};
        }
    }

    // ---- Phase 2c: O^T = V^T · P ; O overwrites P-scratch ----
#pragma unroll
    for (int p = 0; p < 2; p++) {
#pragma unroll
        for (int i = 0; i < 4; i++) {
            const int h = wave * 4 + i;
            const int arow = p * 16 + l16;
            const int q8 = (quad & 1) * 8;
            short8 BP = *(const short8*)(qa + arow * QA_STRIDE + h * 16 + q8);
            short8 Av = *(const short8*)(kreg + vt_addr(h * 16 + l16, p * 16 + q8));
            if (quad >= 2) {
                BP = (short8){0, 0, 0, 0, 0, 0, 0, 0};
                Av = (short8){0, 0, 0, 0, 0, 0, 0, 0};
            }
            f32x4 O = __builtin_amdgcn_mfma_f32_16x16x32_bf16(Av, BP, (f32x4){0.f, 0.f, 0.f, 0.f}, 0, 0, 0);
            short2 o01 = f2bs2(O[0], O[1]), o23 = f2bs2(O[2], O[3]);
            *(short4v*)(qa + arow * QA_STRIDE + h * 16 + quad * 4) = (short4v){o01.x, o01.y, o23.x, o23.y};
        }
    }
    __syncthreads();  // attn-out crosses waves for O-proj A-frags

    // ---- Phase 3: O-proj (+bo) -> y into kreg (vT dead) ----
    {
        f32x4 oacc[4][2];
        run_gemm(woT, (wave * 4) * 16, qa, oacc);
#pragma unroll
        for (int i = 0; i < 4; i++) {
            const int col = (wave * 4 + i) * 16 + l16;
            const float bocol = bo[col];
#pragma unroll
            for (int m = 0; m < 2; m++) {
                const int rbase = m * 16 + quad * 4;
                short2 a01 = f2bs2(oacc[i][m][0] + bocol, oacc[i][m][1] + bocol);
                short2 a23 = f2bs2(oacc[i][m][2] + bocol, oacc[i][m][3] + bocol);
                kreg[(rbase + 0) * KR_STRIDE + col] = a01.x;
                kreg[(rbase + 1) * KR_STRIDE + col] = a01.y;
                kreg[(rbase + 2) * KR_STRIDE + col] = a23.x;
                kreg[(rbase + 3) * KR_STRIDE + col] = a23.y;
            }
        }
    }
    __syncthreads();

    // ---- Phase 4: residual + LayerNorm ----
    float* qs = (float*)qa;  // qa dead
    {
        const int row = tid >> 3, seg = tid & 7;
        const int m = row >> 4, r = row & 15;
        const int tokr = text2[gnode[m] * SEQ + r];
        const float* ep = emb + (size_t)tokr * 256 + seg * 32;
        float sum = 0.f, sq = 0.f;
#pragma unroll
        for (int j = 0; j < 4; j++) {
            short8 y8 = *(const short8*)(kreg + row * KR_STRIDE + seg * 32 + j * 8);
            float4 ea = ((const float4*)(ep + j * 8))[0];
            float4 eb = ((const float4*)(ep + j * 8))[1];
            float ev[8] = {ea.x, ea.y, ea.z, ea.w, eb.x, eb.y, eb.z, eb.w};
            float yv[8];
#pragma unroll
            for (int e = 0; e < 8; e++) {
                yv[e] = bs2f(y8[e]) + ev[e];
                sum += yv[e];
                sq = fmaf(yv[e], yv[e], sq);
            }
            short2 w0 = f2bs2(yv[0], yv[1]), w1 = f2bs2(yv[2], yv[3]);
            short2 w2 = f2bs2(yv[4], yv[5]), w3 = f2bs2(yv[6], yv[7]);
            *(short4v*)(kreg + row * KR_STRIDE + seg * 32 + j * 8) = (short4v){w0.x, w0.y, w1.x, w1.y};
            *(short4v*)(kreg + row * KR_STRIDE + seg * 32 + j * 8 + 4) = (short4v){w2.x, w2.y, w3.x, w3.y};
        }
        qs[tid] = sum;
        qs[256 + tid] = sq;
    }
    __syncthreads();
    if (tid < 32) {
        float s = 0.f, q2 = 0.f;
#pragma unroll
        for (int j = 0; j < 8; j++) {
            s += qs[tid * 8 + j];
            q2 += qs[256 + tid * 8 + j];
        }
        float mu = s * (1.f / 256.f);
        float var = q2 * (1.f / 256.f) - mu * mu;
        qs[512 + tid * 2] = mu;
        qs[512 + tid * 2 + 1] = rsqrtf(var + 1e-5f);
    }
    __syncthreads();
    {
        const int c = tid;
        const float g = lng[c], bb = lnb[c];
        float csum[2] = {0.f, 0.f};
#pragma unroll
        for (int m = 0; m < 2; m++) {
#pragma unroll
            for (int r = 0; r < 16; r++) {
                const int row = m * 16 + r;
                const float yv = bs2f(kreg[row * KR_STRIDE + c]);
                const float mu = qs[512 + row * 2], rstd = qs[512 + row * 2 + 1];
                const float o = (yv - mu) * rstd * g + bb;
                if (MODE == 0) {
                    csum[m] += o;
                } else {
                    tbuf[((size_t)(blockIdx.x * 2 + m) * 24 + r) * 256 + c] = (unsigned short)f2bs(o);
                }
            }
        }
        if (MODE == 0) {
            cat[(size_t)gnode[0] * 512 + 256 + c] = csum[0] * (1.f / 16.f);
            cat[(size_t)gnode[1] * 512 + 256 + c] = csum[1] * (1.f / 16.f);
        } else {
            for (int z = tid; z < 2 * 8 * 256; z += 256) {
                const int m = z >> 11, rem = z & 2047;
                tbuf[((size_t)(blockIdx.x * 2 + m) * 24 + 16 + (rem >> 8)) * 256 + (rem & 255)] = 0;
            }
        }
    }
}

// conv GEMM (proven): C[24576,512] = im2col(tbuf) @ W_all^T
__global__ __launch_bounds__(256) void conv_gemm(const short* __restrict__ tb, const short* __restrict__ wall,
                                                 float* __restrict__ C) {
    __shared__ short As[128 * 40];
    __shared__ short Bs[128 * 40];
    const int bid = blockIdx.x;
    const int m0 = (bid >> 2) * 128;
    const int n0 = (bid & 3) * 128;
    const int tid = threadIdx.x;
    const int lane = tid & 63;
    const int wave = tid >> 6;
    const int wm = (wave >> 1) * 64, wn = (wave & 1) * 64;
    const int quad = lane >> 4, l16 = lane & 15;

    const int r0 = tid >> 2, kc = (tid & 3) * 8;
    const int r1 = r0 + 64;
    const int am0 = m0 + r0, am1 = m0 + r1;
    const int s0 = am0 / 12, p0_ = am0 - s0 * 12;
    const int s1 = am1 / 12, p1_ = am1 - s1 * 12;
    const size_t ga0 = (size_t)(s0 * 24 + p0_) * 256 + kc;
    const size_t ga1 = (size_t)(s1 * 24 + p1_) * 256 + kc;
    const size_t gb0 = (size_t)(n0 + r0) * 2048 + kc;
    const size_t gb1 = (size_t)(n0 + r1) * 2048 + kc;
    short* sa0 = As + r0 * 40 + kc;
    short* sa1 = As + r1 * 40 + kc;
    short* sb0 = Bs + r0 * 40 + kc;
    short* sb1 = Bs + r1 * 40 + kc;

    f32x4 acc[4][4];
#pragma unroll
    for (int i = 0; i < 4; i++)
#pragma unroll
        for (int j = 0; j < 4; j++) acc[i][j] = (f32x4){0.f, 0.f, 0.f, 0.f};

    for (int k0 = 0; k0 < 2048; k0 += 32) {
        short8 a0 = *(const short8*)(tb + ga0 + k0);
        short8 a1 = *(const short8*)(tb + ga1 + k0);
        short8 b0 = *(const short8*)(wall + gb0 + k0);
        short8 b1 = *(const short8*)(wall + gb1 + k0);
        *(short8*)sa0 = a0;
        *(short8*)sa1 = a1;
        *(short8*)sb0 = b0;
        *(short8*)sb1 = b1;
        __syncthreads();
        short8 af[4], bfr[4];
#pragma unroll
        for (int i = 0; i < 4; i++) af[i] = *(const short8*)(As + (wm + i * 16 + l16) * 40 + quad * 8);
#pragma unroll
        for (int j = 0; j < 4; j++) bfr[j] = *(const short8*)(Bs + (wn + j * 16 + l16) * 40 + quad * 8);
#pragma unroll
        for (int i = 0; i < 4; i++)
#pragma unroll
            for (int j = 0; j < 4; j++)
                acc[i][j] = __builtin_amdgcn_mfma_f32_16x16x32_bf16(af[i], bfr[j], acc[i][j], 0, 0, 0);
        __syncthreads();
    }
#pragma unroll
    for (int i = 0; i < 4; i++) {
#pragma unroll
        for (int j = 0; j < 4; j++) {
            const int col = n0 + wn + j * 16 + l16;
            const size_t base = (size_t)(m0 + wm + i * 16 + quad * 4) * 512 + col;
#pragma unroll
            for (int r = 0; r < 4; r++) C[base + (size_t)r * 512] = acc[i][j][r];
        }
    }
}

__global__ void conv_maxpool(const float* __restrict__ C, const float* __restrict__ cb0, const float* __restrict__ cb1,
                             const float* __restrict__ cb2, const float* __restrict__ cb3, float* __restrict__ fin) {
    int i = blockIdx.x * 256 + threadIdx.x;
    if (i >= 2048 * 500) return;
    int slot = i / 500, q = i - slot * 500;
    int Kidx = q / 125, oc = q - Kidx * 125;
    int L = 12 - Kidx;
    const float* base = C + (size_t)(slot * 12) * 512 + q;
    float m = base[0];
    for (int p = 1; p < L; p++) m = fmaxf(m, base[(size_t)p * 512]);
    float b = (Kidx == 0 ? cb0 : Kidx == 1 ? cb1 : Kidx == 2 ? cb2 : cb3)[oc];
    float v = fmaxf(m + b, 0.f);
    int idx = slot < N_ROOTS ? slot : slot - N_ROOTS;
    int colbase = slot < N_ROOTS ? 128 : 628;
    fin[(size_t)idx * 1128 + colbase + q] = v;
}

// ---------- host launch ----------
extern "C" void kernel_launch(void* const* d_in, const int* in_sizes, int n_in, void* d_out, int out_size, void* d_ws,
                              size_t ws_size, hipStream_t stream) {
    const float* x2 = (const float*)d_in[0];
    const float* emb = (const float*)d_in[1];
    const float* Wq = (const float*)d_in[2];
    const float* Wk = (const float*)d_in[3];
    const float* Wv = (const float*)d_in[4];
    const float* Wo = (const float*)d_in[5];
    const float* bq = (const float*)d_in[6];
    const float* bk = (const float*)d_in[7];
    const float* bv = (const float*)d_in[8];
    const float* bo = (const float*)d_in[9];
    const float* lng = (const float*)d_in[10];
    const float* lnb = (const float*)d_in[11];
    const float* gat1_W = (const float*)d_in[12];
    const float* gat1_as = (const float*)d_in[13];
    const float* gat1_ad = (const float*)d_in[14];
    const float* gat1_b = (const float*)d_in[15];
    const float* gcn1_W = (const float*)d_in[16];
    const float* gcn1_b = (const float*)d_in[17];
    const float* gat2_W = (const float*)d_in[18];
    const float* gat2_as = (const float*)d_in[19];
    const float* gat2_ad = (const float*)d_in[20];
    const float* gat2_b = (const float*)d_in[21];
    // d_in[22]/[23] gcn2: dead code in reference forward
    const float* cw0 = (const float*)d_in[24];
    const float* cb0 = (const float*)d_in[25];
    const float* cw1 = (const float*)d_in[26];
    const float* cb1 = (const float*)d_in[27];
    const float* cw2 = (const float*)d_in[28];
    const float* cb2 = (const float*)d_in[29];
    const float* cw3 = (const float*)d_in[30];
    const float* cb3 = (const float*)d_in[31];
    const float* fc1_W = (const float*)d_in[32];
    const float* fc1_b = (const float*)d_in[33];
    const float* fc2_W = (const float*)d_in[34];
    const float* fc2_b = (const float*)d_in[35];
    const int* text2 = (const int*)d_in[36];
    const int* ei = (const int*)d_in[37];
    const int* rooti = (const int*)d_in[38];
    const int* rpi = (const int*)d_in[39];

    float* ws = (float*)d_ws;
    size_t off = 0;
    auto alloc = [&](size_t n) {
        float* p = ws + off;
        off += n;
        return p;
    };
    // zero block first (one small memset): g2o | den1 | den2 | deg
    float* g2o = alloc((size_t)N_NODES * FEAT);
    float* den1 = alloc(N_NODES);
    float* den2 = alloc(N_NODES);
    float* deg = alloc(N_NODES);
    size_t zero_floats = off;
    float* cat = alloc((size_t)N_NODES * 512);  // init_cat covers cols 0..255; xformer fills 256..511
    float* h1 = alloc((size_t)N_NODES * FEAT);  // h1+h2 reused as tbuf after scatters
    float* h2 = alloc((size_t)N_NODES * FEAT);
    float* hg2 = alloc((size_t)N_NODES * FEAT);
    float* als1 = alloc(N_NODES);
    float* ald1 = alloc(N_NODES);
    float* als2 = alloc(N_NODES);
    float* ald2 = alloc(N_NODES);
    int* m1 = (int*)alloc(N_NODES);
    int* m2 = (int*)alloc(N_NODES);
    float* el1 = alloc(ET_EDGES);
    float* el2 = alloc(ET_EDGES);
    float* fin = alloc((size_t)N_ROOTS * 1128);
    float* fch = alloc((size_t)N_ROOTS * 300);
    float* wallf = alloc(512 * 2048 / 2);
    float* wqkvTf = alloc(768 * 256 / 2);
    float* woTf = alloc(256 * 256 / 2);
    float* bqkv = alloc(768);
    float* wg1Tf = alloc(128 * 128 / 2);
    float* wc1Tf = alloc(128 * 128 / 2);
    float* wg2Tf = alloc(128 * 512 / 2);
    (void)ws_size;
    (void)in_sizes;
    (void)n_in;
    (void)out_size;

    unsigned short* tbuf = (unsigned short*)h1;  // 2048*24*256 bf16 fits in h1+h2
    __hip_bfloat16* wall = (__hip_bfloat16*)wallf;
    short* wqkvT = (short*)wqkvTf;
    short* woT = (short*)woTf;
    short* wg1T = (short*)wg1Tf;
    short* wc1T = (short*)wc1Tf;
    short* wg2T = (short*)wg2Tf;
    float* Cbuf = cat;

    hipMemsetAsync(g2o, 0, zero_floats * sizeof(float), stream);
    init_cat<<<cdiv((long long)N_NODES * 256, 256), 256, 0, stream>>>(cat, gat1_b, gcn1_b);
    fill_i32<<<cdiv(2 * N_NODES, 256), 256, 0, stream>>>(m1, (int)0x80000000, 2 * N_NODES);
    repack_wall<<<cdiv(512 * 2048, 256), 256, 0, stream>>>(cw0, cw1, cw2, cw3, wall);
    repack_xf<<<cdiv(768 * 256, 256), 256, 0, stream>>>(Wq, Wk, Wv, Wo, bq, bk, bv, wqkvT, woT, bqkv);
    repack_wT<<<cdiv(128 * 128, 256), 256, 0, stream>>>(gat1_W, wg1T, 128, 128);
    repack_wT<<<cdiv(128 * 128, 256), 256, 0, stream>>>(gcn1_W, wc1T, 128, 128);
    repack_wT<<<cdiv(512 * 128, 256), 256, 0, stream>>>(gat2_W, wg2T, 512, 128);

    // GAT1 / GCN1 node transforms (MFMA)
    mfma_gemm_n128<<<N_NODES / 128, 256, 0, stream>>>(x2, wg1T, h1, 128);
    mfma_gemm_n128<<<N_NODES / 128, 256, 0, stream>>>(x2, wc1T, h2, 128);
    alpha_kernel<<<cdiv((long long)N_NODES * 64, 256), 256, 0, stream>>>(h1, gat1_as, gat1_ad, als1, ald1);
    edge_p1<<<cdiv(ET_EDGES, 256), 256, 0, stream>>>(ei, als1, ald1, el1, m1, deg);
    edge_p2<<<cdiv(ET_EDGES, 256), 256, 0, stream>>>(ei, el1, m1, den1);
    edge_p2b<<<cdiv(ET_EDGES, 256), 256, 0, stream>>>(ei, el1, den1);
    dinv_kernel<<<cdiv(N_NODES, 256), 256, 0, stream>>>(deg);
    const int sc_blocks = cdiv((long long)ET_EDGES * FEAT, 256);
    edge_scatter<<<sc_blocks, 256, 0, stream>>>(ei, el1, h1, cat + 0, 512);
    gcn_scatter<<<sc_blocks, 256, 0, stream>>>(ei, deg, h2, cat + 128, 512);
    // transformer (MFMA): all nodes -> t_avg into cat[:,256:512]
    xformer_kernel<0><<<N_NODES / 2, 256, 0, stream>>>(emb, text2, wqkvT, bqkv, woT, bo, lng, lnb, rooti, rpi, cat,
                                                       nullptr);
    // transformer (MFMA): conv slots -> tbuf (h1/h2 dead after scatters)
    xformer_kernel<1><<<2 * N_ROOTS / 2, 256, 0, stream>>>(emb, text2, wqkvT, bqkv, woT, bo, lng, lnb, rooti, rpi,
                                                           nullptr, tbuf);
    // GAT2 (MFMA, K=512; cat rows are exactly K-contiguous)
    mfma_gemm_n128<<<N_NODES / 128, 256, 0, stream>>>(cat, wg2T, hg2, 512);
    alpha_kernel<<<cdiv((long long)N_NODES * 64, 256), 256, 0, stream>>>(hg2, gat2_as, gat2_ad, als2, ald2);
    edge_p1<<<cdiv(ET_EDGES, 256), 256, 0, stream>>>(ei, als2, ald2, el2, m2, nullptr);
    edge_p2<<<cdiv(ET_EDGES, 256), 256, 0, stream>>>(ei, el2, m2, den2);
    edge_p2b<<<cdiv(ET_EDGES, 256), 256, 0, stream>>>(ei, el2, den2);
    edge_scatter<<<sc_blocks, 256, 0, stream>>>(ei, el2, hg2, g2o, FEAT);
    // conv branch
    conv_gemm<<<192 * 4, 256, 0, stream>>>((const short*)tbuf, (const short*)wall, Cbuf);
    root_gather<<<cdiv(N_ROOTS * FEAT, 256), 256, 0, stream>>>(g2o, rooti, gat2_b, fin);
    conv_maxpool<<<cdiv(2048 * 500, 256), 256, 0, stream>>>(Cbuf, cb0, cb1, cb2, cb3, fin);
    // head
    gemm64<<<dim3(cdiv(300, 64), cdiv(N_ROOTS, 64)), 256, 0, stream>>>(fin, fc1_W, fc1_b, fch, N_ROOTS, 300, 1128,
                                                                       1128, 300, 1);
    fc2_kernel<<<cdiv(N_ROOTS * 3, 256), 256, 0, stream>>>(fch, fc2_W, fc2_b, (float*)d_out);
}